// Round 8
// baseline (2856.041 us; speedup 1.0000x reference)
//
#include <hip/hip_runtime.h>
#include <hip/hip_bf16.h>

typedef __hip_bfloat16 bf16;
using v8s   = __attribute__((ext_vector_type(8))) short;
using f32x4 = __attribute__((ext_vector_type(4))) float;

#define DI __device__ __forceinline__

DI float gelu_f(float x) { return 0.5f * x * (1.f + erff(x * 0.70710678118654752f)); }

DI void g2lds16(const bf16* g, bf16* l) {
  __builtin_amdgcn_global_load_lds((const __attribute__((address_space(1))) void*)g,
                                   (__attribute__((address_space(3))) void*)l, 16, 0, 0);
}

// ---------------- block reduction helpers (256 threads, 4 waves) ----------------
DI float block_sum(float v, float* red, int tid) {
#pragma unroll
  for (int o = 32; o > 0; o >>= 1) v += __shfl_down(v, o);
  __syncthreads();
  if ((tid & 63) == 0) red[tid >> 6] = v;
  __syncthreads();
  return red[0] + red[1] + red[2] + red[3];
}
DI float block_max(float v, float* red, int tid) {
#pragma unroll
  for (int o = 32; o > 0; o >>= 1) v = fmaxf(v, __shfl_down(v, o));
  __syncthreads();
  if ((tid & 63) == 0) red[tid >> 6] = v;
  __syncthreads();
  return fmaxf(fmaxf(red[0], red[1]), fmaxf(red[2], red[3]));
}

// ---------------- weight prep ----------------
__global__ __launch_bounds__(256)
void tconv(const float* __restrict__ in, bf16* __restrict__ out,
           int R, int C, long inStrideZ, long outStrideL, long outStrideH, int zmod) {
  __shared__ float tile[32][33];
  int z = blockIdx.z;
  int lz = z / zmod, hz = z - lz * zmod;
  in  += (long)z * inStrideZ;
  out += (long)lz * outStrideL + (long)hz * outStrideH;
  int cb = blockIdx.x * 32, rb = blockIdx.y * 32;
  int tx = threadIdx.x & 31, ty = threadIdx.x >> 5;  // 32x8
#pragma unroll
  for (int i = 0; i < 32; i += 8)
    tile[ty + i][tx] = in[(long)(rb + ty + i) * C + cb + tx];
  __syncthreads();
#pragma unroll
  for (int i = 0; i < 32; i += 8)
    out[(long)(cb + ty + i) * R + rb + tx] = __float2bfloat16(tile[tx][ty + i]);
}

__global__ __launch_bounds__(256)
void prep_cw(const float* __restrict__ wsrc, bf16* __restrict__ o, int IC, int KT) {
  int idx = blockIdx.x * 256 + threadIdx.x;
  int oc = idx / KT, kp = idx - oc * KT;
  float v = 0.f;
  if (kp < IC * 3) {
    int kk = kp / IC, ic = kp - kk * IC;
    v = wsrc[(oc * IC + ic) * 3 + kk];
  }
  o[idx] = __float2bfloat16(v);
}

__global__ __launch_bounds__(256)
void prep_bias(const float* __restrict__ bq, const float* __restrict__ bk,
               const float* __restrict__ bv, float* __restrict__ o) {
  int idx = blockIdx.x * 256 + threadIdx.x;  // 6*2304
  int l = idx / 2304, n = idx - l * 2304;
  int which = n / 768, r = n - which * 768;
  const float* src = which == 0 ? bq : (which == 1 ? bk : bv);
  o[idx] = src[l * 768 + r];
}

// pad-repack head layer-2 weights: hw2 [3072][527] -> hw2p [3072][640] (zero pad)
__global__ __launch_bounds__(256)
void prep_hw2(const float* __restrict__ hw2, const float* __restrict__ hb2,
              float* __restrict__ hw2p, float* __restrict__ hb2p) {
  int idx = blockIdx.x * 256 + threadIdx.x;  // 3072*640
  int e = idx / 640, c = idx - e * 640;
  hw2p[idx] = c < 527 ? hw2[(long)e * 527 + c] : 0.f;
  if (idx < 640) hb2p[idx] = idx < 527 ? hb2[idx] : 0.f;
}

// ---------------- im2col ----------------
__global__ __launch_bounds__(256)
void im2col1(const float* __restrict__ x, bf16* __restrict__ out) {
  int idx = blockIdx.x * 256 + threadIdx.x;  // 8192*256
  int m = idx >> 8, kp = idx & 255;
  float v = 0.f;
  if (kp < 240) {
    int kk = kp / 80, ic = kp - kk * 80;
    int t = (m & 2047) + kk - 1;
    int b = m >> 11;
    if ((unsigned)t < 2048u) v = x[((long)(b * 80 + ic) << 11) + t];
  }
  out[idx] = __float2bfloat16(v);
}

__global__ __launch_bounds__(256)
void im2col2(const bf16* __restrict__ y, bf16* __restrict__ out) {
  int idx = blockIdx.x * 256 + threadIdx.x;  // 4096*2304
  int m = idx / 2304, kp = idx - m * 2304;
  int kk = kp / 768, ic = kp - kk * 768;
  int t = 2 * (m & 1023) + kk - 1;
  bf16 v = __float2bfloat16(0.f);
  if ((unsigned)t < 2048u) v = y[((long)(m >> 10) * 2048 + t) * 768 + ic];
  out[idx] = v;
}

// ---------------- GEMM: C[m][n] = sum_k A[m][k]*B[n][k]  (both bf16, K%64==0) ----------------
// 2-phase double-buffered K-loop, WAVES = WM*WN waves (64*WAVES threads).
enum { EPI_GELU_BF16, EPI_CONV2, EPI_QKV, EPI_BIAS_F32, EPI_RELU_BF16 };

struct GP {
  const bf16* A; const bf16* B; const float* bias;
  bf16* Ob; float* Of; const float* aux;
  int M, N, K; long sA, sB, sC; int zoff;
};

template<int BM, int BN, int WM, int WN, int EPI>
__global__ __launch_bounds__(WM * WN * 64)
void gemm_bt(GP p) {
  constexpr int WAVES = WM * WN;
  constexpr int FM = BM / WM / 16, FN = BN / WN / 16;
  __shared__ __align__(16) bf16 As0[BM * 64], Bs0[BN * 64];
  __shared__ __align__(16) bf16 As1[BM * 64], Bs1[BN * 64];
  const int tid = threadIdx.x;
  const int lane = tid & 63, wid = tid >> 6;
  const int wr = wid / WN, wc = wid - wr * WN;
  const int row0 = wr * (BM / WM), col0 = wc * (BN / WN);
  const int lr = lane & 15, lk = (lane >> 4) * 8;
  const int lrow = lane >> 3, lcol = (lane & 7) * 8;
  const int z = blockIdx.z;
  const bf16* Ab = p.A + (long)z * p.sA + (long)blockIdx.x * BM * p.K;
  const bf16* Bb = p.B + (long)z * p.sB + (long)blockIdx.y * BN * p.K;
  f32x4 acc[FM][FN] = {};

  auto stage = [&](bf16* As, bf16* Bs, int kt) {
#pragma unroll
    for (int i = 0; i < BM / 8 / WAVES; ++i) {
      const int c = wid + i * WAVES;  // chunk of 8 rows (1KB)
      g2lds16(&Ab[(long)(c * 8 + lrow) * p.K + kt + lcol], &As[c << 9]);
    }
#pragma unroll
    for (int i = 0; i < BN / 8 / WAVES; ++i) {
      const int c = wid + i * WAVES;
      g2lds16(&Bb[(long)(c * 8 + lrow) * p.K + kt + lcol], &Bs[c << 9]);
    }
  };

  auto compute = [&](const bf16* As, const bf16* Bs) {
#pragma unroll
    for (int ks = 0; ks < 2; ++ks) {
      v8s af[FM], bf_[FN];
#pragma unroll
      for (int mi = 0; mi < FM; ++mi)
        af[mi] = *(const v8s*)&As[(row0 + mi * 16 + lr) * 64 + ks * 32 + lk];
#pragma unroll
      for (int ni = 0; ni < FN; ++ni)
        bf_[ni] = *(const v8s*)&Bs[(col0 + ni * 16 + lr) * 64 + ks * 32 + lk];
      __builtin_amdgcn_s_setprio(1);
#pragma unroll
      for (int mi = 0; mi < FM; ++mi)
#pragma unroll
        for (int ni = 0; ni < FN; ++ni)
          acc[mi][ni] = __builtin_amdgcn_mfma_f32_16x16x32_bf16(af[mi], bf_[ni], acc[mi][ni], 0, 0, 0);
      __builtin_amdgcn_s_setprio(0);
    }
  };

  stage(As0, Bs0, 0);
  __syncthreads();
  int kt = 0;
  while (true) {
    if (kt + 64 < p.K) stage(As1, Bs1, kt + 64);
    compute(As0, Bs0);
    __syncthreads();
    kt += 64;
    if (kt >= p.K) break;
    if (kt + 64 < p.K) stage(As0, Bs0, kt + 64);
    compute(As1, Bs1);
    __syncthreads();
    kt += 64;
    if (kt >= p.K) break;
  }

  // epilogue; D: row=(lane>>4)*4+r, col=lane&15
#pragma unroll
  for (int mi = 0; mi < FM; ++mi) {
#pragma unroll
    for (int ni = 0; ni < FN; ++ni) {
#pragma unroll
      for (int r = 0; r < 4; ++r) {
        float v = acc[mi][ni][r];
        const int m = blockIdx.x * BM + row0 + mi * 16 + (lane >> 4) * 4 + r;
        const int n = blockIdx.y * BN + col0 + ni * 16 + lr;
        if constexpr (EPI == EPI_GELU_BF16) {
          p.Ob[(long)m * p.N + n] = __float2bfloat16(gelu_f(v + p.bias[n]));
        } else if constexpr (EPI == EPI_CONV2) {
          float t = gelu_f(v + p.bias[n]) + p.aux[(long)(m & 1023) * 768 + n];
          p.Of[(long)m * 768 + n] = t;
          p.Ob[(long)m * 768 + n] = __float2bfloat16(t);
        } else if constexpr (EPI == EPI_QKV) {
          float t = v + p.bias[n];
          int which = n / 768, nn = n - which * 768;
          int h = nn >> 6, d = nn & 63;
          long bh = (long)(m >> 10) * 12 + h;
          if (which < 2)
            p.Ob[(long)which * 3145728 + (bh << 16) + ((long)(m & 1023) << 6) + d] = __float2bfloat16(t);
          else
            p.Ob[6291456L + (bh << 16) + ((long)d << 10) + (m & 1023)] = __float2bfloat16(t);
        } else if constexpr (EPI == EPI_BIAS_F32) {
          p.Of[(long)m * p.N + n] = v + p.bias[n];
        } else if constexpr (EPI == EPI_RELU_BF16) {
          p.Ob[(long)m * p.N + n] = __float2bfloat16(fmaxf(v + p.bias[n], 0.f));
        }
      }
    }
  }
}

// ---------------- fused flash attention ----------------
// 1D grid of 384: qt = blk/48, bh = blk%48 (XCD-aligned: same-head blocks 48
// apart -> same XCD L2). 256 threads = 4 waves x 32 q-rows. K/V dbuf in LDS.
// K/V LDS XOR-swizzled (rule 21): linear gload_lds dest + pre-swizzled global
// source col + matching XOR on ds_read col -> kills the 16-way bank conflict
// of 128B-stride row-major tiles.
__global__ __launch_bounds__(256)
void attn_flash(const bf16* __restrict__ qkv, bf16* __restrict__ cc) {
  __shared__ __align__(16) bf16 Ks[2][64 * 64], Vs[2][64 * 64];
  __shared__ __align__(16) bf16 Pl[4][32 * 76];
  const int tid = threadIdx.x, lane = tid & 63, wid = tid >> 6;
  const int lr = lane & 15, lg = lane >> 4;
  const int blk = blockIdx.x;
  const int qt = blk / 48, bh = blk - qt * 48;
  const int b = bh / 12, h = bh - b * 12;
  const long qb = (long)bh << 16;
  const bf16* Qg = qkv + qb;
  const bf16* Kg = qkv + 3145728 + qb;
  const bf16* Vg = qkv + 6291456 + qb;
  const int q0 = qt * 128 + wid * 32;
  const int lrow8 = lane >> 3;
  const int scol = (((lane & 7) ^ (lane >> 3)) & 7) * 8;  // pre-swizzled source col
  const int rswz = (lr & 7) * 8;                          // read-side XOR

  v8s aq[2][2];
#pragma unroll
  for (int mi = 0; mi < 2; ++mi)
#pragma unroll
    for (int ks = 0; ks < 2; ++ks)
      aq[mi][ks] = *(const v8s*)&Qg[(long)(q0 + mi * 16 + lr) * 64 + ks * 32 + lg * 8];

  float mrow[2][4], lrow_[2][4];
  f32x4 acc[2][4] = {};
#pragma unroll
  for (int mi = 0; mi < 2; ++mi)
#pragma unroll
    for (int r = 0; r < 4; ++r) { mrow[mi][r] = -1e30f; lrow_[mi][r] = 0.f; }
  bf16* myP = &Pl[wid][0];

  auto stageKV = [&](int buf, int kt) {
#pragma unroll
    for (int i = 0; i < 2; ++i) {
      int c = wid + i * 4;
      g2lds16(&Kg[(long)(kt + c * 8 + lrow8) * 64 + scol], &Ks[buf][c << 9]);
      g2lds16(&Vg[((long)(c * 8 + lrow8) << 10) + kt + scol], &Vs[buf][c << 9]);
    }
  };

  stageKV(0, 0);
  __syncthreads();  // buf0 staged (vmcnt drained at barrier)

  for (int it = 0; it < 16; ++it) {
    const int cur = it & 1;
    if (it + 1 < 16) stageKV(cur ^ 1, (it + 1) * 64);
    const bf16* Kc = &Ks[cur][0];
    const bf16* Vc = &Vs[cur][0];

    // S = Q K^T
    f32x4 s[2][4] = {};
#pragma unroll
    for (int ks = 0; ks < 2; ++ks) {
      v8s bk[4];
#pragma unroll
      for (int ni = 0; ni < 4; ++ni)
        bk[ni] = *(const v8s*)&Kc[(ni * 16 + lr) * 64 + ((ks * 32 + lg * 8) ^ rswz)];
      __builtin_amdgcn_s_setprio(1);
#pragma unroll
      for (int mi = 0; mi < 2; ++mi)
#pragma unroll
        for (int ni = 0; ni < 4; ++ni)
          s[mi][ni] = __builtin_amdgcn_mfma_f32_16x16x32_bf16(aq[mi][ks], bk[ni], s[mi][ni], 0, 0, 0);
      __builtin_amdgcn_s_setprio(0);
    }

    // online softmax; write P (bf16) to per-wave LDS
#pragma unroll
    for (int mi = 0; mi < 2; ++mi) {
#pragma unroll
      for (int r = 0; r < 4; ++r) {
        float tm = fmaxf(fmaxf(s[mi][0][r], s[mi][1][r]), fmaxf(s[mi][2][r], s[mi][3][r]));
#pragma unroll
        for (int o = 1; o < 16; o <<= 1) tm = fmaxf(tm, __shfl_xor(tm, o));
        float mn = fmaxf(mrow[mi][r], tm);
        float al = __expf(mrow[mi][r] - mn);
        mrow[mi][r] = mn;
        float ps = 0.f;
        const int prow = (mi * 16 + lg * 4 + r) * 76;
#pragma unroll
        for (int ni = 0; ni < 4; ++ni) {
          float pv = __expf(s[mi][ni][r] - mn);
          myP[prow + ni * 16 + lr] = __float2bfloat16(pv);
          ps += pv;
        }
#pragma unroll
        for (int o = 1; o < 16; o <<= 1) ps += __shfl_xor(ps, o);
        lrow_[mi][r] = lrow_[mi][r] * al + ps;
#pragma unroll
        for (int ni = 0; ni < 4; ++ni) acc[mi][ni][r] *= al;
      }
    }

    // O += P * V  (V d-major -> contiguous B-frags)
#pragma unroll
    for (int ks = 0; ks < 2; ++ks) {
      v8s pa[2], bv[4];
#pragma unroll
      for (int mi = 0; mi < 2; ++mi)
        pa[mi] = *(const v8s*)&myP[(mi * 16 + lr) * 76 + ks * 32 + lg * 8];
#pragma unroll
      for (int ni = 0; ni < 4; ++ni)
        bv[ni] = *(const v8s*)&Vc[(ni * 16 + lr) * 64 + ((ks * 32 + lg * 8) ^ rswz)];
      __builtin_amdgcn_s_setprio(1);
#pragma unroll
      for (int mi = 0; mi < 2; ++mi)
#pragma unroll
        for (int ni = 0; ni < 4; ++ni)
          acc[mi][ni] = __builtin_amdgcn_mfma_f32_16x16x32_bf16(pa[mi], bv[ni], acc[mi][ni], 0, 0, 0);
      __builtin_amdgcn_s_setprio(0);
    }
    __syncthreads();  // all waves done with cur; next buffer fully staged
  }

  // epilogue: normalize and write concat layout [b*1024+t][h*64+d]
#pragma unroll
  for (int mi = 0; mi < 2; ++mi)
#pragma unroll
    for (int ni = 0; ni < 4; ++ni)
#pragma unroll
      for (int r = 0; r < 4; ++r) {
        int row = q0 + mi * 16 + lg * 4 + r;
        cc[((long)(b << 10) + row) * 768 + h * 64 + ni * 16 + lr] =
            __float2bfloat16(acc[mi][ni][r] / lrow_[mi][r]);
      }
}

// ---------------- residual + LayerNorm (row=768) ----------------
__global__ __launch_bounds__(256)
void ln_resid(const float* __restrict__ xin, const float* __restrict__ add,
              const float* __restrict__ g, const float* __restrict__ bb,
              float* __restrict__ xo, bf16* __restrict__ xbo) {
  __shared__ float red[4];
  long row = blockIdx.x;
  const float* xr = xin + row * 768;
  const float* ar = add + row * 768;
  int tid = threadIdx.x;
  float v0 = xr[tid] + ar[tid];
  float v1 = xr[tid + 256] + ar[tid + 256];
  float v2 = xr[tid + 512] + ar[tid + 512];
  float mean = block_sum(v0 + v1 + v2, red, tid) * (1.f / 768.f);
  v0 -= mean; v1 -= mean; v2 -= mean;
  float var = block_sum(v0 * v0 + v1 * v1 + v2 * v2, red, tid) * (1.f / 768.f);
  float rs = rsqrtf(var + 1e-5f);
  float o0 = v0 * rs * g[tid]       + bb[tid];
  float o1 = v1 * rs * g[tid + 256] + bb[tid + 256];
  float o2 = v2 * rs * g[tid + 512] + bb[tid + 512];
  float* xro = xo + row * 768;
  bf16*  xbr = xbo + row * 768;
  xro[tid] = o0; xro[tid + 256] = o1; xro[tid + 512] = o2;
  xbr[tid] = __float2bfloat16(o0);
  xbr[tid + 256] = __float2bfloat16(o1);
  xbr[tid + 512] = __float2bfloat16(o2);
}

// ---------------- classifier head ----------------
__global__ __launch_bounds__(256)
void head_cls(const float* __restrict__ x,
              const float* __restrict__ lnpg, const float* __restrict__ lnpb,
              const float* __restrict__ hlng, const float* __restrict__ hlnb,
              float* __restrict__ cls) {
  __shared__ float red[4];
  int b = blockIdx.x, tid = threadIdx.x;
  const float* xr = x + (long)b * 1024 * 768;  // row t=0
  float v0 = xr[tid], v1 = xr[tid + 256], v2 = xr[tid + 512];
  float s = block_sum(v0 + v1 + v2, red, tid) * (1.f / 768.f);
  v0 -= s; v1 -= s; v2 -= s;
  float q = block_sum(v0 * v0 + v1 * v1 + v2 * v2, red, tid) * (1.f / 768.f);
  float r = rsqrtf(q + 1e-5f);
  v0 = v0 * r * lnpg[tid]       + lnpb[tid];
  v1 = v1 * r * lnpg[tid + 256] + lnpb[tid + 256];
  v2 = v2 * r * lnpg[tid + 512] + lnpb[tid + 512];
  s = block_sum(v0 + v1 + v2, red, tid) * (1.f / 768.f);
  v0 -= s; v1 -= s; v2 -= s;
  q = block_sum(v0 * v0 + v1 * v1 + v2 * v2, red, tid) * (1.f / 768.f);
  r = rsqrtf(q + 1e-5f);
  cls[b * 768 + tid]       = v0 * r * hlng[tid]       + hlnb[tid];
  cls[b * 768 + tid + 256] = v1 * r * hlng[tid + 256] + hlnb[tid + 256];
  cls[b * 768 + tid + 512] = v2 * r * hlng[tid + 512] + hlnb[tid + 512];
}

// split-K GEMV stage A
__global__ __launch_bounds__(256)
void mlp_part(const float* __restrict__ in, const float* __restrict__ wmat,
              float* __restrict__ part, int IN, int OUTP, int ET) {
  __shared__ float cin[4][96];
  __shared__ float red[8][32][16];
  int tid = threadIdx.x;
  int tx = tid & 31, ty = tid >> 5;
  int e0 = blockIdx.y * ET;
  for (int i = tid; i < 4 * ET; i += 256) {
    int b = i / ET, el = i - b * ET;
    cin[b][el] = in[b * IN + e0 + el];
  }
  __syncthreads();
  f32x4 acc[4] = {};
  const float* wp = wmat + (long)e0 * OUTP + (blockIdx.x * 32 + tx) * 4;
  const int iters = ET >> 3;
  for (int i = 0; i < iters; ++i) {
    int el = ty + i * 8;
    f32x4 w = *(const f32x4*)(wp + (long)el * OUTP);
#pragma unroll
    for (int b = 0; b < 4; ++b) acc[b] += cin[b][el] * w;
  }
#pragma unroll
  for (int b = 0; b < 4; ++b) *(f32x4*)&red[ty][tx][b * 4] = acc[b];
  __syncthreads();
  if (tid < 128) {
    int rx = tid & 31, b = tid >> 5;
    f32x4 s = {};
#pragma unroll
    for (int t = 0; t < 8; ++t) s += *(const f32x4*)&red[t][rx][b * 4];
    *(f32x4*)&part[((long)blockIdx.y * 4 + b) * OUTP + (blockIdx.x * 32 + rx) * 4] = s;
  }
}

__global__ __launch_bounds__(256)
void mlp_reduce(const float* __restrict__ part, const float* __restrict__ bias,
                float* __restrict__ out, int OUTP, int S, int relu) {
  int idx = blockIdx.x * 256 + threadIdx.x;
  int b = idx / OUTP, j = idx - b * OUTP;
  float s = bias[j];
  for (int t = 0; t < S; ++t) s += part[((long)t * 4 + b) * OUTP + j];
  out[idx] = relu ? fmaxf(s, 0.f) : s;
}

// C=527 logits in [4][640] padded rows
__global__ __launch_bounds__(256)
void head_softmax(const float* __restrict__ lg, float* __restrict__ out) {
  __shared__ float red[4];
  int b = blockIdx.x, tid = threadIdx.x;
  const float* r = lg + (long)b * 640;
  float v0 = r[tid];
  float v1 = tid + 256 < 527 ? r[tid + 256] : -1e30f;
  float v2 = tid + 512 < 527 ? r[tid + 512] : -1e30f;
  float mx = block_max(fmaxf(v0, fmaxf(v1, v2)), red, tid);
  float e0 = __expf(v0 - mx);
  float e1 = tid + 256 < 527 ? __expf(v1 - mx) : 0.f;
  float e2 = tid + 512 < 527 ? __expf(v2 - mx) : 0.f;
  float sm = block_sum(e0 + e1 + e2, red, tid);
  float inv = 1.f / sm;
  out[(long)b * 527 + tid] = e0 * inv;
  if (tid + 256 < 527) out[(long)b * 527 + tid + 256] = e1 * inv;
  if (tid + 512 < 527) out[(long)b * 527 + tid + 512] = e2 * inv;
}

// ---------------- launcher ----------------
extern "C" void kernel_launch(void* const* d_in, const int* in_sizes, int n_in,
                              void* d_out, int out_size, void* d_ws, size_t ws_size,
                              hipStream_t stream) {
  const float* x_in    = (const float*)d_in[0];
  const float* conv1_w = (const float*)d_in[1];
  const float* conv1_b = (const float*)d_in[2];
  const float* conv2_w = (const float*)d_in[3];
  const float* conv2_b = (const float*)d_in[4];
  const float* pos_emb = (const float*)d_in[5];
  const float* ln1_g   = (const float*)d_in[6];
  const float* ln1_b   = (const float*)d_in[7];
  const float* wq      = (const float*)d_in[8];
  const float* bq      = (const float*)d_in[9];
  const float* wk      = (const float*)d_in[10];
  const float* bk      = (const float*)d_in[11];
  const float* wv      = (const float*)d_in[12];
  const float* bv      = (const float*)d_in[13];
  const float* wo      = (const float*)d_in[14];
  const float* bo      = (const float*)d_in[15];
  const float* w1      = (const float*)d_in[16];
  const float* b1      = (const float*)d_in[17];
  const float* w2      = (const float*)d_in[18];
  const float* b2      = (const float*)d_in[19];
  const float* ln2_g   = (const float*)d_in[20];
  const float* ln2_b   = (const float*)d_in[21];
  const float* lnp_g   = (const float*)d_in[22];
  const float* lnp_b   = (const float*)d_in[23];
  const float* hln_g   = (const float*)d_in[24];
  const float* hln_b   = (const float*)d_in[25];
  const float* hw1     = (const float*)d_in[26];
  const float* hb1     = (const float*)d_in[27];
  const float* hw2     = (const float*)d_in[28];
  const float* hb2     = (const float*)d_in[29];

  // workspace layout
  char* w = (char*)d_ws;
  bf16*  wqkvT = (bf16*)(w);                      // 6*2304*768 bf16
  bf16*  woT   = (bf16*)(w + 21233664);           // 6*768*768
  bf16*  w1T   = (bf16*)(w + 28311552);           // 6*3072*768
  bf16*  w2T   = (bf16*)(w + 56623104);           // 6*768*3072
  bf16*  wc1T  = (bf16*)(w + 84934656);           // 768*256
  bf16*  wc2T  = (bf16*)(w + 85327872);           // 768*2304
  float* bqkv  = (float*)(w + 88866816);          // 6*2304 f32
  float* Xf    = (float*)(w + 88922112);          // 4096*768 f32
  bf16*  Xb    = (bf16*)(w + 101505024);          // 4096*768
  bf16*  qkv   = (bf16*)(w + 107796480);          // 3*4096*768 (q t-major, k t-major, v d-major)
  bf16*  CC    = (bf16*)(w + 126670848);          // 4096*768
  float* ATTN  = (float*)(w + 132962304);         // 4096*768 f32
  char*  BIG   = w + 145545216;                   // 50,331,648 shared region
  bf16*  A1  = (bf16*)(BIG);                      // 8192*256   (conv phase)
  bf16*  Y1G = (bf16*)(BIG + 4194304);            // 8192*768   (conv phase)
  bf16*  A2  = (bf16*)(BIG + 16777216);           // 4096*2304  (conv phase)
  bf16*  Hh  = (bf16*)(BIG);                      // 4096*3072  (ffn phase)
  float* FFN = (float*)(BIG + 25165824);          // 4096*768 f32 (ffn phase)
  // head phase (aliases, used only after last FFN)
  float* CLS  = (float*)(BIG);                    // 4*768
  float* HID  = (float*)(BIG + 16384);            // 4*3072
  float* LGT  = (float*)(BIG + 81920);            // 4*640
  float* PT1  = (float*)(BIG + 131072);           // 16*4*3072
  float* PT2  = (float*)(BIG + 1048576);          // 32*4*640
  float* HB2P = (float*)(BIG + 1572864);          // 640
  float* HW2P = (float*)(BIG + 1605632);          // 3072*640

  // ---- weight prep ----
  tconv<<<dim3(2, 24, 72), 256, 0, stream>>>(wq, wqkvT,            768, 64,   49152L, 1769472L, 49152L, 12);
  tconv<<<dim3(2, 24, 72), 256, 0, stream>>>(wk, wqkvT + 589824,   768, 64,   49152L, 1769472L, 49152L, 12);
  tconv<<<dim3(2, 24, 72), 256, 0, stream>>>(wv, wqkvT + 1179648,  768, 64,   49152L, 1769472L, 49152L, 12);
  tconv<<<dim3(24, 24, 6), 256, 0, stream>>>(wo, woT,              768, 768,  589824L, 589824L, 0L, 1);
  tconv<<<dim3(96, 24, 6), 256, 0, stream>>>(w1, w1T,              768, 3072, 2359296L, 2359296L, 0L, 1);
  tconv<<<dim3(24, 96, 6), 256, 0, stream>>>(w2, w2T,              3072, 768, 2359296L, 2359296L, 0L, 1);
  prep_cw<<<768,  256, 0, stream>>>(conv1_w, wc1T, 80, 256);
  prep_cw<<<6912, 256, 0, stream>>>(conv2_w, wc2T, 768, 2304);
  prep_bias<<<54, 256, 0, stream>>>(bq, bk, bv, bqkv);

  // ---- convs ----
  im2col1<<<8192, 256, 0, stream>>>(x_in, A1);
  { GP p{}; p.A = A1; p.B = wc1T; p.bias = conv1_b; p.Ob = Y1G;
    p.M = 8192; p.N = 768; p.K = 256;
    gemm_bt<128,64,2,2,EPI_GELU_BF16><<<dim3(64,12,1),256,0,stream>>>(p); }
  im2col2<<<36864, 256, 0, stream>>>(Y1G, A2);
  { GP p{}; p.A = A2; p.B = wc2T; p.bias = conv2_b; p.Of = Xf; p.Ob = Xb; p.aux = pos_emb;
    p.M = 4096; p.N = 768; p.K = 2304;
    gemm_bt<128,64,2,2,EPI_CONV2><<<dim3(32,12,1),256,0,stream>>>(p); }

  // ---- transformer layers ----
  for (int l = 0; l < 6; ++l) {
    { GP p{}; p.A = Xb; p.B = wqkvT + (long)l * 1769472; p.bias = bqkv + l * 2304;
      p.Ob = qkv; p.M = 4096; p.N = 2304; p.K = 768;
      gemm_bt<256,256,2,4,EPI_QKV><<<dim3(16,9,1),512,0,stream>>>(p); }
    attn_flash<<<384, 256, 0, stream>>>(qkv, CC);
    { GP p{}; p.A = CC; p.B = woT + (long)l * 589824; p.bias = bo + l * 768; p.Of = ATTN;
      p.M = 4096; p.N = 768; p.K = 768;
      gemm_bt<128,64,2,2,EPI_BIAS_F32><<<dim3(32,12,1),256,0,stream>>>(p); }
    ln_resid<<<4096, 256, 0, stream>>>(Xf, ATTN, ln1_g + l * 768, ln1_b + l * 768, Xf, Xb);
    { GP p{}; p.A = Xb; p.B = w1T + (long)l * 2359296; p.bias = b1 + l * 3072; p.Ob = Hh;
      p.M = 4096; p.N = 3072; p.K = 768;
      gemm_bt<256,256,2,4,EPI_RELU_BF16><<<dim3(16,12,1),512,0,stream>>>(p); }
    { GP p{}; p.A = Hh; p.B = w2T + (long)l * 2359296; p.bias = b2 + l * 768; p.Of = FFN;
      p.M = 4096; p.N = 768; p.K = 3072;
      gemm_bt<128,64,2,2,EPI_BIAS_F32><<<dim3(32,12,1),256,0,stream>>>(p); }
    ln_resid<<<4096, 256, 0, stream>>>(Xf, FFN, ln2_g + l * 768, ln2_b + l * 768, Xf, Xb);
  }

  // ---- head ----
  head_cls<<<4, 256, 0, stream>>>(Xf, lnp_g, lnp_b, hln_g, hln_b, CLS);
  prep_hw2<<<7680, 256, 0, stream>>>(hw2, hb2, HW2P, HB2P);
  mlp_part<<<dim3(24, 16), 256, 0, stream>>>(CLS, hw1, PT1, 768, 3072, 48);
  mlp_reduce<<<48, 256, 0, stream>>>(PT1, hb1, HID, 3072, 16, 1);
  mlp_part<<<dim3(5, 32), 256, 0, stream>>>(HID, HW2P, PT2, 3072, 640, 96);
  mlp_reduce<<<10, 256, 0, stream>>>(PT2, HB2P, LGT, 640, 32, 0);
  head_softmax<<<4, 256, 0, stream>>>(LGT, (float*)d_out);
}

// Round 9
// 2179.017 us; speedup vs baseline: 1.3107x; 1.3107x over previous
//
#include <hip/hip_runtime.h>
#include <hip/hip_bf16.h>

typedef __hip_bfloat16 bf16;
using v8s   = __attribute__((ext_vector_type(8))) short;
using f32x4 = __attribute__((ext_vector_type(4))) float;

#define DI __device__ __forceinline__

DI float gelu_f(float x) { return 0.5f * x * (1.f + erff(x * 0.70710678118654752f)); }

DI void g2lds16(const bf16* g, bf16* l) {
  __builtin_amdgcn_global_load_lds((const __attribute__((address_space(1))) void*)g,
                                   (__attribute__((address_space(3))) void*)l, 16, 0, 0);
}

// ---------------- block reduction helpers (256 threads, 4 waves) ----------------
DI float block_sum(float v, float* red, int tid) {
#pragma unroll
  for (int o = 32; o > 0; o >>= 1) v += __shfl_down(v, o);
  __syncthreads();
  if ((tid & 63) == 0) red[tid >> 6] = v;
  __syncthreads();
  return red[0] + red[1] + red[2] + red[3];
}
DI float block_max(float v, float* red, int tid) {
#pragma unroll
  for (int o = 32; o > 0; o >>= 1) v = fmaxf(v, __shfl_down(v, o));
  __syncthreads();
  if ((tid & 63) == 0) red[tid >> 6] = v;
  __syncthreads();
  return fmaxf(fmaxf(red[0], red[1]), fmaxf(red[2], red[3]));
}

// ---------------- weight prep ----------------
__global__ __launch_bounds__(256)
void tconv(const float* __restrict__ in, bf16* __restrict__ out,
           int R, int C, long inStrideZ, long outStrideL, long outStrideH, int zmod) {
  __shared__ float tile[32][33];
  int z = blockIdx.z;
  int lz = z / zmod, hz = z - lz * zmod;
  in  += (long)z * inStrideZ;
  out += (long)lz * outStrideL + (long)hz * outStrideH;
  int cb = blockIdx.x * 32, rb = blockIdx.y * 32;
  int tx = threadIdx.x & 31, ty = threadIdx.x >> 5;  // 32x8
#pragma unroll
  for (int i = 0; i < 32; i += 8)
    tile[ty + i][tx] = in[(long)(rb + ty + i) * C + cb + tx];
  __syncthreads();
#pragma unroll
  for (int i = 0; i < 32; i += 8)
    out[(long)(cb + ty + i) * R + rb + tx] = __float2bfloat16(tile[tx][ty + i]);
}

__global__ __launch_bounds__(256)
void prep_cw(const float* __restrict__ wsrc, bf16* __restrict__ o, int IC, int KT) {
  int idx = blockIdx.x * 256 + threadIdx.x;
  int oc = idx / KT, kp = idx - oc * KT;
  float v = 0.f;
  if (kp < IC * 3) {
    int kk = kp / IC, ic = kp - kk * IC;
    v = wsrc[(oc * IC + ic) * 3 + kk];
  }
  o[idx] = __float2bfloat16(v);
}

__global__ __launch_bounds__(256)
void prep_bias(const float* __restrict__ bq, const float* __restrict__ bk,
               const float* __restrict__ bv, float* __restrict__ o) {
  int idx = blockIdx.x * 256 + threadIdx.x;  // 6*2304
  int l = idx / 2304, n = idx - l * 2304;
  int which = n / 768, r = n - which * 768;
  const float* src = which == 0 ? bq : (which == 1 ? bk : bv);
  o[idx] = src[l * 768 + r];
}

// pad-repack head layer-2 weights: hw2 [3072][527] -> hw2p [3072][640] (zero pad)
__global__ __launch_bounds__(256)
void prep_hw2(const float* __restrict__ hw2, const float* __restrict__ hb2,
              float* __restrict__ hw2p, float* __restrict__ hb2p) {
  int idx = blockIdx.x * 256 + threadIdx.x;  // 3072*640
  int e = idx / 640, c = idx - e * 640;
  hw2p[idx] = c < 527 ? hw2[(long)e * 527 + c] : 0.f;
  if (idx < 640) hb2p[idx] = idx < 527 ? hb2[idx] : 0.f;
}

// ---------------- im2col ----------------
__global__ __launch_bounds__(256)
void im2col1(const float* __restrict__ x, bf16* __restrict__ out) {
  int idx = blockIdx.x * 256 + threadIdx.x;  // 8192*256
  int m = idx >> 8, kp = idx & 255;
  float v = 0.f;
  if (kp < 240) {
    int kk = kp / 80, ic = kp - kk * 80;
    int t = (m & 2047) + kk - 1;
    int b = m >> 11;
    if ((unsigned)t < 2048u) v = x[((long)(b * 80 + ic) << 11) + t];
  }
  out[idx] = __float2bfloat16(v);
}

__global__ __launch_bounds__(256)
void im2col2(const bf16* __restrict__ y, bf16* __restrict__ out) {
  int idx = blockIdx.x * 256 + threadIdx.x;  // 4096*2304
  int m = idx / 2304, kp = idx - m * 2304;
  int kk = kp / 768, ic = kp - kk * 768;
  int t = 2 * (m & 1023) + kk - 1;
  bf16 v = __float2bfloat16(0.f);
  if ((unsigned)t < 2048u) v = y[((long)(m >> 10) * 2048 + t) * 768 + ic];
  out[idx] = v;
}

// ---------------- GEMM: C[m][n] = sum_k A[m][k]*B[n][k]  (both bf16, K%64==0) ----------------
// 2-phase double-buffered K-loop, WAVES = WM*WN waves (64*WAVES threads).
// launch_bounds 2nd arg = 2 waves/EU -> VGPR cap 256 (prevents the round-8
// spill: 8-wave 256^2 tile needs ~210 VGPR; default cap was 128 -> scratch).
enum { EPI_GELU_BF16, EPI_CONV2, EPI_QKV, EPI_BIAS_F32, EPI_RELU_BF16 };

struct GP {
  const bf16* A; const bf16* B; const float* bias;
  bf16* Ob; float* Of; const float* aux;
  int M, N, K; long sA, sB, sC; int zoff;
};

template<int BM, int BN, int WM, int WN, int EPI>
__global__ __launch_bounds__(WM * WN * 64, 2)
void gemm_bt(GP p) {
  constexpr int WAVES = WM * WN;
  constexpr int FM = BM / WM / 16, FN = BN / WN / 16;
  __shared__ __align__(16) bf16 As0[BM * 64], Bs0[BN * 64];
  __shared__ __align__(16) bf16 As1[BM * 64], Bs1[BN * 64];
  const int tid = threadIdx.x;
  const int lane = tid & 63, wid = tid >> 6;
  const int wr = wid / WN, wc = wid - wr * WN;
  const int row0 = wr * (BM / WM), col0 = wc * (BN / WN);
  const int lr = lane & 15, lk = (lane >> 4) * 8;
  const int lrow = lane >> 3, lcol = (lane & 7) * 8;
  const int z = blockIdx.z;
  const bf16* Ab = p.A + (long)z * p.sA + (long)blockIdx.x * BM * p.K;
  const bf16* Bb = p.B + (long)z * p.sB + (long)blockIdx.y * BN * p.K;
  f32x4 acc[FM][FN] = {};

  auto stage = [&](bf16* As, bf16* Bs, int kt) {
#pragma unroll
    for (int i = 0; i < BM / 8 / WAVES; ++i) {
      const int c = wid + i * WAVES;  // chunk of 8 rows (1KB)
      g2lds16(&Ab[(long)(c * 8 + lrow) * p.K + kt + lcol], &As[c << 9]);
    }
#pragma unroll
    for (int i = 0; i < BN / 8 / WAVES; ++i) {
      const int c = wid + i * WAVES;
      g2lds16(&Bb[(long)(c * 8 + lrow) * p.K + kt + lcol], &Bs[c << 9]);
    }
  };

  auto compute = [&](const bf16* As, const bf16* Bs) {
#pragma unroll
    for (int ks = 0; ks < 2; ++ks) {
      v8s af[FM], bf_[FN];
#pragma unroll
      for (int mi = 0; mi < FM; ++mi)
        af[mi] = *(const v8s*)&As[(row0 + mi * 16 + lr) * 64 + ks * 32 + lk];
#pragma unroll
      for (int ni = 0; ni < FN; ++ni)
        bf_[ni] = *(const v8s*)&Bs[(col0 + ni * 16 + lr) * 64 + ks * 32 + lk];
      __builtin_amdgcn_s_setprio(1);
#pragma unroll
      for (int mi = 0; mi < FM; ++mi)
#pragma unroll
        for (int ni = 0; ni < FN; ++ni)
          acc[mi][ni] = __builtin_amdgcn_mfma_f32_16x16x32_bf16(af[mi], bf_[ni], acc[mi][ni], 0, 0, 0);
      __builtin_amdgcn_s_setprio(0);
    }
  };

  stage(As0, Bs0, 0);
  __syncthreads();
  int kt = 0;
  while (true) {
    if (kt + 64 < p.K) stage(As1, Bs1, kt + 64);
    compute(As0, Bs0);
    __syncthreads();
    kt += 64;
    if (kt >= p.K) break;
    if (kt + 64 < p.K) stage(As0, Bs0, kt + 64);
    compute(As1, Bs1);
    __syncthreads();
    kt += 64;
    if (kt >= p.K) break;
  }

  // epilogue; D: row=(lane>>4)*4+r, col=lane&15
#pragma unroll
  for (int mi = 0; mi < FM; ++mi) {
#pragma unroll
    for (int ni = 0; ni < FN; ++ni) {
#pragma unroll
      for (int r = 0; r < 4; ++r) {
        float v = acc[mi][ni][r];
        const int m = blockIdx.x * BM + row0 + mi * 16 + (lane >> 4) * 4 + r;
        const int n = blockIdx.y * BN + col0 + ni * 16 + lr;
        if constexpr (EPI == EPI_GELU_BF16) {
          p.Ob[(long)m * p.N + n] = __float2bfloat16(gelu_f(v + p.bias[n]));
        } else if constexpr (EPI == EPI_CONV2) {
          float t = gelu_f(v + p.bias[n]) + p.aux[(long)(m & 1023) * 768 + n];
          p.Of[(long)m * 768 + n] = t;
          p.Ob[(long)m * 768 + n] = __float2bfloat16(t);
        } else if constexpr (EPI == EPI_QKV) {
          float t = v + p.bias[n];
          int which = n / 768, nn = n - which * 768;
          int h = nn >> 6, d = nn & 63;
          long bh = (long)(m >> 10) * 12 + h;
          if (which < 2)
            p.Ob[(long)which * 3145728 + (bh << 16) + ((long)(m & 1023) << 6) + d] = __float2bfloat16(t);
          else
            p.Ob[6291456L + (bh << 16) + ((long)d << 10) + (m & 1023)] = __float2bfloat16(t);
        } else if constexpr (EPI == EPI_BIAS_F32) {
          p.Of[(long)m * p.N + n] = v + p.bias[n];
        } else if constexpr (EPI == EPI_RELU_BF16) {
          p.Ob[(long)m * p.N + n] = __float2bfloat16(fmaxf(v + p.bias[n], 0.f));
        }
      }
    }
  }
}

// ---------------- fused flash attention ----------------
// 1D grid of 384: qt = blk/48, bh = blk%48 (XCD-aligned). 4 waves x 32 q-rows.
// K/V dbuf in LDS, XOR-swizzled (rule 21): linear gload_lds dest +
// pre-swizzled global source col + matching XOR on ds_read col.
__global__ __launch_bounds__(256)
void attn_flash(const bf16* __restrict__ qkv, bf16* __restrict__ cc) {
  __shared__ __align__(16) bf16 Ks[2][64 * 64], Vs[2][64 * 64];
  __shared__ __align__(16) bf16 Pl[4][32 * 76];
  const int tid = threadIdx.x, lane = tid & 63, wid = tid >> 6;
  const int lr = lane & 15, lg = lane >> 4;
  const int blk = blockIdx.x;
  const int qt = blk / 48, bh = blk - qt * 48;
  const int b = bh / 12, h = bh - b * 12;
  const long qb = (long)bh << 16;
  const bf16* Qg = qkv + qb;
  const bf16* Kg = qkv + 3145728 + qb;
  const bf16* Vg = qkv + 6291456 + qb;
  const int q0 = qt * 128 + wid * 32;
  const int lrow8 = lane >> 3;
  const int scol = (((lane & 7) ^ (lane >> 3)) & 7) * 8;  // pre-swizzled source col
  const int rswz = (lr & 7) * 8;                          // read-side XOR

  v8s aq[2][2];
#pragma unroll
  for (int mi = 0; mi < 2; ++mi)
#pragma unroll
    for (int ks = 0; ks < 2; ++ks)
      aq[mi][ks] = *(const v8s*)&Qg[(long)(q0 + mi * 16 + lr) * 64 + ks * 32 + lg * 8];

  float mrow[2][4], lrow_[2][4];
  f32x4 acc[2][4] = {};
#pragma unroll
  for (int mi = 0; mi < 2; ++mi)
#pragma unroll
    for (int r = 0; r < 4; ++r) { mrow[mi][r] = -1e30f; lrow_[mi][r] = 0.f; }
  bf16* myP = &Pl[wid][0];

  auto stageKV = [&](int buf, int kt) {
#pragma unroll
    for (int i = 0; i < 2; ++i) {
      int c = wid + i * 4;
      g2lds16(&Kg[(long)(kt + c * 8 + lrow8) * 64 + scol], &Ks[buf][c << 9]);
      g2lds16(&Vg[((long)(c * 8 + lrow8) << 10) + kt + scol], &Vs[buf][c << 9]);
    }
  };

  stageKV(0, 0);
  __syncthreads();  // buf0 staged (vmcnt drained at barrier)

  for (int it = 0; it < 16; ++it) {
    const int cur = it & 1;
    if (it + 1 < 16) stageKV(cur ^ 1, (it + 1) * 64);
    const bf16* Kc = &Ks[cur][0];
    const bf16* Vc = &Vs[cur][0];

    // S = Q K^T
    f32x4 s[2][4] = {};
#pragma unroll
    for (int ks = 0; ks < 2; ++ks) {
      v8s bk[4];
#pragma unroll
      for (int ni = 0; ni < 4; ++ni)
        bk[ni] = *(const v8s*)&Kc[(ni * 16 + lr) * 64 + ((ks * 32 + lg * 8) ^ rswz)];
      __builtin_amdgcn_s_setprio(1);
#pragma unroll
      for (int mi = 0; mi < 2; ++mi)
#pragma unroll
        for (int ni = 0; ni < 4; ++ni)
          s[mi][ni] = __builtin_amdgcn_mfma_f32_16x16x32_bf16(aq[mi][ks], bk[ni], s[mi][ni], 0, 0, 0);
      __builtin_amdgcn_s_setprio(0);
    }

    // online softmax; write P (bf16) to per-wave LDS
#pragma unroll
    for (int mi = 0; mi < 2; ++mi) {
#pragma unroll
      for (int r = 0; r < 4; ++r) {
        float tm = fmaxf(fmaxf(s[mi][0][r], s[mi][1][r]), fmaxf(s[mi][2][r], s[mi][3][r]));
#pragma unroll
        for (int o = 1; o < 16; o <<= 1) tm = fmaxf(tm, __shfl_xor(tm, o));
        float mn = fmaxf(mrow[mi][r], tm);
        float al = __expf(mrow[mi][r] - mn);
        mrow[mi][r] = mn;
        float ps = 0.f;
        const int prow = (mi * 16 + lg * 4 + r) * 76;
#pragma unroll
        for (int ni = 0; ni < 4; ++ni) {
          float pv = __expf(s[mi][ni][r] - mn);
          myP[prow + ni * 16 + lr] = __float2bfloat16(pv);
          ps += pv;
        }
#pragma unroll
        for (int o = 1; o < 16; o <<= 1) ps += __shfl_xor(ps, o);
        lrow_[mi][r] = lrow_[mi][r] * al + ps;
#pragma unroll
        for (int ni = 0; ni < 4; ++ni) acc[mi][ni][r] *= al;
      }
    }

    // O += P * V  (V d-major -> contiguous B-frags)
#pragma unroll
    for (int ks = 0; ks < 2; ++ks) {
      v8s pa[2], bv[4];
#pragma unroll
      for (int mi = 0; mi < 2; ++mi)
        pa[mi] = *(const v8s*)&myP[(mi * 16 + lr) * 76 + ks * 32 + lg * 8];
#pragma unroll
      for (int ni = 0; ni < 4; ++ni)
        bv[ni] = *(const v8s*)&Vc[(ni * 16 + lr) * 64 + ((ks * 32 + lg * 8) ^ rswz)];
      __builtin_amdgcn_s_setprio(1);
#pragma unroll
      for (int mi = 0; mi < 2; ++mi)
#pragma unroll
        for (int ni = 0; ni < 4; ++ni)
          acc[mi][ni] = __builtin_amdgcn_mfma_f32_16x16x32_bf16(pa[mi], bv[ni], acc[mi][ni], 0, 0, 0);
      __builtin_amdgcn_s_setprio(0);
    }
    __syncthreads();  // all waves done with cur; next buffer fully staged
  }

  // epilogue: normalize and write concat layout [b*1024+t][h*64+d]
#pragma unroll
  for (int mi = 0; mi < 2; ++mi)
#pragma unroll
    for (int ni = 0; ni < 4; ++ni)
#pragma unroll
      for (int r = 0; r < 4; ++r) {
        int row = q0 + mi * 16 + lg * 4 + r;
        cc[((long)(b << 10) + row) * 768 + h * 64 + ni * 16 + lr] =
            __float2bfloat16(acc[mi][ni][r] / lrow_[mi][r]);
      }
}

// ---------------- residual + LayerNorm (row=768) ----------------
__global__ __launch_bounds__(256)
void ln_resid(const float* __restrict__ xin, const float* __restrict__ add,
              const float* __restrict__ g, const float* __restrict__ bb,
              float* __restrict__ xo, bf16* __restrict__ xbo) {
  __shared__ float red[4];
  long row = blockIdx.x;
  const float* xr = xin + row * 768;
  const float* ar = add + row * 768;
  int tid = threadIdx.x;
  float v0 = xr[tid] + ar[tid];
  float v1 = xr[tid + 256] + ar[tid + 256];
  float v2 = xr[tid + 512] + ar[tid + 512];
  float mean = block_sum(v0 + v1 + v2, red, tid) * (1.f / 768.f);
  v0 -= mean; v1 -= mean; v2 -= mean;
  float var = block_sum(v0 * v0 + v1 * v1 + v2 * v2, red, tid) * (1.f / 768.f);
  float rs = rsqrtf(var + 1e-5f);
  float o0 = v0 * rs * g[tid]       + bb[tid];
  float o1 = v1 * rs * g[tid + 256] + bb[tid + 256];
  float o2 = v2 * rs * g[tid + 512] + bb[tid + 512];
  float* xro = xo + row * 768;
  bf16*  xbr = xbo + row * 768;
  xro[tid] = o0; xro[tid + 256] = o1; xro[tid + 512] = o2;
  xbr[tid] = __float2bfloat16(o0);
  xbr[tid + 256] = __float2bfloat16(o1);
  xbr[tid + 512] = __float2bfloat16(o2);
}

// ---------------- classifier head ----------------
__global__ __launch_bounds__(256)
void head_cls(const float* __restrict__ x,
              const float* __restrict__ lnpg, const float* __restrict__ lnpb,
              const float* __restrict__ hlng, const float* __restrict__ hlnb,
              float* __restrict__ cls) {
  __shared__ float red[4];
  int b = blockIdx.x, tid = threadIdx.x;
  const float* xr = x + (long)b * 1024 * 768;  // row t=0
  float v0 = xr[tid], v1 = xr[tid + 256], v2 = xr[tid + 512];
  float s = block_sum(v0 + v1 + v2, red, tid) * (1.f / 768.f);
  v0 -= s; v1 -= s; v2 -= s;
  float q = block_sum(v0 * v0 + v1 * v1 + v2 * v2, red, tid) * (1.f / 768.f);
  float r = rsqrtf(q + 1e-5f);
  v0 = v0 * r * lnpg[tid]       + lnpb[tid];
  v1 = v1 * r * lnpg[tid + 256] + lnpb[tid + 256];
  v2 = v2 * r * lnpg[tid + 512] + lnpb[tid + 512];
  s = block_sum(v0 + v1 + v2, red, tid) * (1.f / 768.f);
  v0 -= s; v1 -= s; v2 -= s;
  q = block_sum(v0 * v0 + v1 * v1 + v2 * v2, red, tid) * (1.f / 768.f);
  r = rsqrtf(q + 1e-5f);
  cls[b * 768 + tid]       = v0 * r * hlng[tid]       + hlnb[tid];
  cls[b * 768 + tid + 256] = v1 * r * hlng[tid + 256] + hlnb[tid + 256];
  cls[b * 768 + tid + 512] = v2 * r * hlng[tid + 512] + hlnb[tid + 512];
}

// split-K GEMV stage A
__global__ __launch_bounds__(256)
void mlp_part(const float* __restrict__ in, const float* __restrict__ wmat,
              float* __restrict__ part, int IN, int OUTP, int ET) {
  __shared__ float cin[4][96];
  __shared__ float red[8][32][16];
  int tid = threadIdx.x;
  int tx = tid & 31, ty = tid >> 5;
  int e0 = blockIdx.y * ET;
  for (int i = tid; i < 4 * ET; i += 256) {
    int b = i / ET, el = i - b * ET;
    cin[b][el] = in[b * IN + e0 + el];
  }
  __syncthreads();
  f32x4 acc[4] = {};
  const float* wp = wmat + (long)e0 * OUTP + (blockIdx.x * 32 + tx) * 4;
  const int iters = ET >> 3;
  for (int i = 0; i < iters; ++i) {
    int el = ty + i * 8;
    f32x4 w = *(const f32x4*)(wp + (long)el * OUTP);
#pragma unroll
    for (int b = 0; b < 4; ++b) acc[b] += cin[b][el] * w;
  }
#pragma unroll
  for (int b = 0; b < 4; ++b) *(f32x4*)&red[ty][tx][b * 4] = acc[b];
  __syncthreads();
  if (tid < 128) {
    int rx = tid & 31, b = tid >> 5;
    f32x4 s = {};
#pragma unroll
    for (int t = 0; t < 8; ++t) s += *(const f32x4*)&red[t][rx][b * 4];
    *(f32x4*)&part[((long)blockIdx.y * 4 + b) * OUTP + (blockIdx.x * 32 + rx) * 4] = s;
  }
}

__global__ __launch_bounds__(256)
void mlp_reduce(const float* __restrict__ part, const float* __restrict__ bias,
                float* __restrict__ out, int OUTP, int S, int relu) {
  int idx = blockIdx.x * 256 + threadIdx.x;
  int b = idx / OUTP, j = idx - b * OUTP;
  float s = bias[j];
  for (int t = 0; t < S; ++t) s += part[((long)t * 4 + b) * OUTP + j];
  out[idx] = relu ? fmaxf(s, 0.f) : s;
}

// C=527 logits in [4][640] padded rows
__global__ __launch_bounds__(256)
void head_softmax(const float* __restrict__ lg, float* __restrict__ out) {
  __shared__ float red[4];
  int b = blockIdx.x, tid = threadIdx.x;
  const float* r = lg + (long)b * 640;
  float v0 = r[tid];
  float v1 = tid + 256 < 527 ? r[tid + 256] : -1e30f;
  float v2 = tid + 512 < 527 ? r[tid + 512] : -1e30f;
  float mx = block_max(fmaxf(v0, fmaxf(v1, v2)), red, tid);
  float e0 = __expf(v0 - mx);
  float e1 = tid + 256 < 527 ? __expf(v1 - mx) : 0.f;
  float e2 = tid + 512 < 527 ? __expf(v2 - mx) : 0.f;
  float sm = block_sum(e0 + e1 + e2, red, tid);
  float inv = 1.f / sm;
  out[(long)b * 527 + tid] = e0 * inv;
  if (tid + 256 < 527) out[(long)b * 527 + tid + 256] = e1 * inv;
  if (tid + 512 < 527) out[(long)b * 527 + tid + 512] = e2 * inv;
}

// ---------------- launcher ----------------
extern "C" void kernel_launch(void* const* d_in, const int* in_sizes, int n_in,
                              void* d_out, int out_size, void* d_ws, size_t ws_size,
                              hipStream_t stream) {
  const float* x_in    = (const float*)d_in[0];
  const float* conv1_w = (const float*)d_in[1];
  const float* conv1_b = (const float*)d_in[2];
  const float* conv2_w = (const float*)d_in[3];
  const float* conv2_b = (const float*)d_in[4];
  const float* pos_emb = (const float*)d_in[5];
  const float* ln1_g   = (const float*)d_in[6];
  const float* ln1_b   = (const float*)d_in[7];
  const float* wq      = (const float*)d_in[8];
  const float* bq      = (const float*)d_in[9];
  const float* wk      = (const float*)d_in[10];
  const float* bk      = (const float*)d_in[11];
  const float* wv      = (const float*)d_in[12];
  const float* bv      = (const float*)d_in[13];
  const float* wo      = (const float*)d_in[14];
  const float* bo      = (const float*)d_in[15];
  const float* w1      = (const float*)d_in[16];
  const float* b1      = (const float*)d_in[17];
  const float* w2      = (const float*)d_in[18];
  const float* b2      = (const float*)d_in[19];
  const float* ln2_g   = (const float*)d_in[20];
  const float* ln2_b   = (const float*)d_in[21];
  const float* lnp_g   = (const float*)d_in[22];
  const float* lnp_b   = (const float*)d_in[23];
  const float* hln_g   = (const float*)d_in[24];
  const float* hln_b   = (const float*)d_in[25];
  const float* hw1     = (const float*)d_in[26];
  const float* hb1     = (const float*)d_in[27];
  const float* hw2     = (const float*)d_in[28];
  const float* hb2     = (const float*)d_in[29];

  // workspace layout
  char* w = (char*)d_ws;
  bf16*  wqkvT = (bf16*)(w);                      // 6*2304*768 bf16
  bf16*  woT   = (bf16*)(w + 21233664);           // 6*768*768
  bf16*  w1T   = (bf16*)(w + 28311552);           // 6*3072*768
  bf16*  w2T   = (bf16*)(w + 56623104);           // 6*768*3072
  bf16*  wc1T  = (bf16*)(w + 84934656);           // 768*256
  bf16*  wc2T  = (bf16*)(w + 85327872);           // 768*2304
  float* bqkv  = (float*)(w + 88866816);          // 6*2304 f32
  float* Xf    = (float*)(w + 88922112);          // 4096*768 f32
  bf16*  Xb    = (bf16*)(w + 101505024);          // 4096*768
  bf16*  qkv   = (bf16*)(w + 107796480);          // 3*4096*768 (q t-major, k t-major, v d-major)
  bf16*  CC    = (bf16*)(w + 126670848);          // 4096*768
  float* ATTN  = (float*)(w + 132962304);         // 4096*768 f32
  char*  BIG   = w + 145545216;                   // 50,331,648 shared region
  bf16*  A1  = (bf16*)(BIG);                      // 8192*256   (conv phase)
  bf16*  Y1G = (bf16*)(BIG + 4194304);            // 8192*768   (conv phase)
  bf16*  A2  = (bf16*)(BIG + 16777216);           // 4096*2304  (conv phase)
  bf16*  Hh  = (bf16*)(BIG);                      // 4096*3072  (ffn phase)
  float* FFN = (float*)(BIG + 25165824);          // 4096*768 f32 (ffn phase)
  // head phase (aliases, used only after last FFN)
  float* CLS  = (float*)(BIG);                    // 4*768
  float* HID  = (float*)(BIG + 16384);            // 4*3072
  float* LGT  = (float*)(BIG + 81920);            // 4*640
  float* PT1  = (float*)(BIG + 131072);           // 16*4*3072
  float* PT2  = (float*)(BIG + 1048576);          // 32*4*640
  float* HB2P = (float*)(BIG + 1572864);          // 640
  float* HW2P = (float*)(BIG + 1605632);          // 3072*640

  // ---- weight prep ----
  tconv<<<dim3(2, 24, 72), 256, 0, stream>>>(wq, wqkvT,            768, 64,   49152L, 1769472L, 49152L, 12);
  tconv<<<dim3(2, 24, 72), 256, 0, stream>>>(wk, wqkvT + 589824,   768, 64,   49152L, 1769472L, 49152L, 12);
  tconv<<<dim3(2, 24, 72), 256, 0, stream>>>(wv, wqkvT + 1179648,  768, 64,   49152L, 1769472L, 49152L, 12);
  tconv<<<dim3(24, 24, 6), 256, 0, stream>>>(wo, woT,              768, 768,  589824L, 589824L, 0L, 1);
  tconv<<<dim3(96, 24, 6), 256, 0, stream>>>(w1, w1T,              768, 3072, 2359296L, 2359296L, 0L, 1);
  tconv<<<dim3(24, 96, 6), 256, 0, stream>>>(w2, w2T,              3072, 768, 2359296L, 2359296L, 0L, 1);
  prep_cw<<<768,  256, 0, stream>>>(conv1_w, wc1T, 80, 256);
  prep_cw<<<6912, 256, 0, stream>>>(conv2_w, wc2T, 768, 2304);
  prep_bias<<<54, 256, 0, stream>>>(bq, bk, bv, bqkv);

  // ---- convs ----
  im2col1<<<8192, 256, 0, stream>>>(x_in, A1);
  { GP p{}; p.A = A1; p.B = wc1T; p.bias = conv1_b; p.Ob = Y1G;
    p.M = 8192; p.N = 768; p.K = 256;
    gemm_bt<128,64,2,2,EPI_GELU_BF16><<<dim3(64,12,1),256,0,stream>>>(p); }
  im2col2<<<36864, 256, 0, stream>>>(Y1G, A2);
  { GP p{}; p.A = A2; p.B = wc2T; p.bias = conv2_b; p.Of = Xf; p.Ob = Xb; p.aux = pos_emb;
    p.M = 4096; p.N = 768; p.K = 2304;
    gemm_bt<128,64,2,2,EPI_CONV2><<<dim3(32,12,1),256,0,stream>>>(p); }

  // ---- transformer layers ----
  for (int l = 0; l < 6; ++l) {
    { GP p{}; p.A = Xb; p.B = wqkvT + (long)l * 1769472; p.bias = bqkv + l * 2304;
      p.Ob = qkv; p.M = 4096; p.N = 2304; p.K = 768;
      gemm_bt<128,128,2,2,EPI_QKV><<<dim3(32,18,1),256,0,stream>>>(p); }
    attn_flash<<<384, 256, 0, stream>>>(qkv, CC);
    { GP p{}; p.A = CC; p.B = woT + (long)l * 589824; p.bias = bo + l * 768; p.Of = ATTN;
      p.M = 4096; p.N = 768; p.K = 768;
      gemm_bt<128,64,2,2,EPI_BIAS_F32><<<dim3(32,12,1),256,0,stream>>>(p); }
    ln_resid<<<4096, 256, 0, stream>>>(Xf, ATTN, ln1_g + l * 768, ln1_b + l * 768, Xf, Xb);
    { GP p{}; p.A = Xb; p.B = w1T + (long)l * 2359296; p.bias = b1 + l * 3072; p.Ob = Hh;
      p.M = 4096; p.N = 3072; p.K = 768;
      gemm_bt<256,256,2,4,EPI_RELU_BF16><<<dim3(16,12,1),512,0,stream>>>(p); }
    { GP p{}; p.A = Hh; p.B = w2T + (long)l * 2359296; p.bias = b2 + l * 768; p.Of = FFN;
      p.M = 4096; p.N = 768; p.K = 3072;
      gemm_bt<128,64,2,2,EPI_BIAS_F32><<<dim3(32,12,1),256,0,stream>>>(p); }
    ln_resid<<<4096, 256, 0, stream>>>(Xf, FFN, ln2_g + l * 768, ln2_b + l * 768, Xf, Xb);
  }

  // ---- head ----
  head_cls<<<4, 256, 0, stream>>>(Xf, lnp_g, lnp_b, hln_g, hln_b, CLS);
  prep_hw2<<<7680, 256, 0, stream>>>(hw2, hb2, HW2P, HB2P);
  mlp_part<<<dim3(24, 16), 256, 0, stream>>>(CLS, hw1, PT1, 768, 3072, 48);
  mlp_reduce<<<48, 256, 0, stream>>>(PT1, hb1, HID, 3072, 16, 1);
  mlp_part<<<dim3(5, 32), 256, 0, stream>>>(HID, HW2P, PT2, 3072, 640, 96);
  mlp_reduce<<<10, 256, 0, stream>>>(PT2, HB2P, LGT, 640, 32, 0);
  head_softmax<<<4, 256, 0, stream>>>(LGT, (float*)d_out);
}

// Round 10
// 2158.904 us; speedup vs baseline: 1.3229x; 1.0093x over previous
//
#include <hip/hip_runtime.h>
#include <hip/hip_bf16.h>

typedef __hip_bfloat16 bf16;
using v8s   = __attribute__((ext_vector_type(8))) short;
using f32x4 = __attribute__((ext_vector_type(4))) float;

#define DI __device__ __forceinline__

DI float gelu_f(float x) { return 0.5f * x * (1.f + erff(x * 0.70710678118654752f)); }

DI void g2lds16(const bf16* g, bf16* l) {
  __builtin_amdgcn_global_load_lds((const __attribute__((address_space(1))) void*)g,
                                   (__attribute__((address_space(3))) void*)l, 16, 0, 0);
}

// ---------------- block reduction helpers (256 threads, 4 waves) ----------------
DI float block_sum(float v, float* red, int tid) {
#pragma unroll
  for (int o = 32; o > 0; o >>= 1) v += __shfl_down(v, o);
  __syncthreads();
  if ((tid & 63) == 0) red[tid >> 6] = v;
  __syncthreads();
  return red[0] + red[1] + red[2] + red[3];
}
DI float block_max(float v, float* red, int tid) {
#pragma unroll
  for (int o = 32; o > 0; o >>= 1) v = fmaxf(v, __shfl_down(v, o));
  __syncthreads();
  if ((tid & 63) == 0) red[tid >> 6] = v;
  __syncthreads();
  return fmaxf(fmaxf(red[0], red[1]), fmaxf(red[2], red[3]));
}

// ---------------- weight prep ----------------
__global__ __launch_bounds__(256)
void tconv(const float* __restrict__ in, bf16* __restrict__ out,
           int R, int C, long inStrideZ, long outStrideL, long outStrideH, int zmod) {
  __shared__ float tile[32][33];
  int z = blockIdx.z;
  int lz = z / zmod, hz = z - lz * zmod;
  in  += (long)z * inStrideZ;
  out += (long)lz * outStrideL + (long)hz * outStrideH;
  int cb = blockIdx.x * 32, rb = blockIdx.y * 32;
  int tx = threadIdx.x & 31, ty = threadIdx.x >> 5;  // 32x8
#pragma unroll
  for (int i = 0; i < 32; i += 8)
    tile[ty + i][tx] = in[(long)(rb + ty + i) * C + cb + tx];
  __syncthreads();
#pragma unroll
  for (int i = 0; i < 32; i += 8)
    out[(long)(cb + ty + i) * R + rb + tx] = __float2bfloat16(tile[tx][ty + i]);
}

__global__ __launch_bounds__(256)
void prep_cw(const float* __restrict__ wsrc, bf16* __restrict__ o, int IC, int KT) {
  int idx = blockIdx.x * 256 + threadIdx.x;
  int oc = idx / KT, kp = idx - oc * KT;
  float v = 0.f;
  if (kp < IC * 3) {
    int kk = kp / IC, ic = kp - kk * IC;
    v = wsrc[(oc * IC + ic) * 3 + kk];
  }
  o[idx] = __float2bfloat16(v);
}

__global__ __launch_bounds__(256)
void prep_bias(const float* __restrict__ bq, const float* __restrict__ bk,
               const float* __restrict__ bv, float* __restrict__ o) {
  int idx = blockIdx.x * 256 + threadIdx.x;  // 6*2304
  int l = idx / 2304, n = idx - l * 2304;
  int which = n / 768, r = n - which * 768;
  const float* src = which == 0 ? bq : (which == 1 ? bk : bv);
  o[idx] = src[l * 768 + r];
}

// pad-repack head layer-2 weights: hw2 [3072][527] -> hw2p [3072][640] (zero pad)
__global__ __launch_bounds__(256)
void prep_hw2(const float* __restrict__ hw2, const float* __restrict__ hb2,
              float* __restrict__ hw2p, float* __restrict__ hb2p) {
  int idx = blockIdx.x * 256 + threadIdx.x;  // 3072*640
  int e = idx / 640, c = idx - e * 640;
  hw2p[idx] = c < 527 ? hw2[(long)e * 527 + c] : 0.f;
  if (idx < 640) hb2p[idx] = idx < 527 ? hb2[idx] : 0.f;
}

// ---------------- im2col ----------------
__global__ __launch_bounds__(256)
void im2col1(const float* __restrict__ x, bf16* __restrict__ out) {
  int idx = blockIdx.x * 256 + threadIdx.x;  // 8192*256
  int m = idx >> 8, kp = idx & 255;
  float v = 0.f;
  if (kp < 240) {
    int kk = kp / 80, ic = kp - kk * 80;
    int t = (m & 2047) + kk - 1;
    int b = m >> 11;
    if ((unsigned)t < 2048u) v = x[((long)(b * 80 + ic) << 11) + t];
  }
  out[idx] = __float2bfloat16(v);
}

__global__ __launch_bounds__(256)
void im2col2(const bf16* __restrict__ y, bf16* __restrict__ out) {
  int idx = blockIdx.x * 256 + threadIdx.x;  // 4096*2304
  int m = idx / 2304, kp = idx - m * 2304;
  int kk = kp / 768, ic = kp - kk * 768;
  int t = 2 * (m & 1023) + kk - 1;
  bf16 v = __float2bfloat16(0.f);
  if ((unsigned)t < 2048u) v = y[((long)(m >> 10) * 2048 + t) * 768 + ic];
  out[idx] = v;
}

// ---------------- GEMM: C[m][n] = sum_k A[m][k]*B[n][k]  (both bf16, K%64==0) ----------------
// 2-phase double-buffered K-loop, WAVES = WM*WN waves (64*WAVES threads).
// launch_bounds 2nd arg: for 8-wave (256^2) blocks use 1 -> VGPR cap >=256
// under BOTH plausible semantics (waves/EU or blocks/CU); round 8/9 showed
// (512,2) caps at 128 VGPR -> ~80 regs/thread spilled -> 250MB scratch writes.
enum { EPI_GELU_BF16, EPI_CONV2, EPI_QKV, EPI_BIAS_F32, EPI_RELU_BF16 };

struct GP {
  const bf16* A; const bf16* B; const float* bias;
  bf16* Ob; float* Of; const float* aux;
  int M, N, K; long sA, sB, sC; int zoff;
};

template<int BM, int BN, int WM, int WN, int EPI>
__global__ __launch_bounds__(WM * WN * 64, (WM * WN >= 8) ? 1 : 2)
void gemm_bt(GP p) {
  constexpr int WAVES = WM * WN;
  constexpr int FM = BM / WM / 16, FN = BN / WN / 16;
  __shared__ __align__(16) bf16 As0[BM * 64], Bs0[BN * 64];
  __shared__ __align__(16) bf16 As1[BM * 64], Bs1[BN * 64];
  const int tid = threadIdx.x;
  const int lane = tid & 63, wid = tid >> 6;
  const int wr = wid / WN, wc = wid - wr * WN;
  const int row0 = wr * (BM / WM), col0 = wc * (BN / WN);
  const int lr = lane & 15, lk = (lane >> 4) * 8;
  const int lrow = lane >> 3, lcol = (lane & 7) * 8;
  const int z = blockIdx.z;
  const bf16* Ab = p.A + (long)z * p.sA + (long)blockIdx.x * BM * p.K;
  const bf16* Bb = p.B + (long)z * p.sB + (long)blockIdx.y * BN * p.K;
  f32x4 acc[FM][FN] = {};

  auto stage = [&](bf16* As, bf16* Bs, int kt) {
#pragma unroll
    for (int i = 0; i < BM / 8 / WAVES; ++i) {
      const int c = wid + i * WAVES;  // chunk of 8 rows (1KB)
      g2lds16(&Ab[(long)(c * 8 + lrow) * p.K + kt + lcol], &As[c << 9]);
    }
#pragma unroll
    for (int i = 0; i < BN / 8 / WAVES; ++i) {
      const int c = wid + i * WAVES;
      g2lds16(&Bb[(long)(c * 8 + lrow) * p.K + kt + lcol], &Bs[c << 9]);
    }
  };

  auto compute = [&](const bf16* As, const bf16* Bs) {
#pragma unroll
    for (int ks = 0; ks < 2; ++ks) {
      v8s af[FM], bf_[FN];
#pragma unroll
      for (int mi = 0; mi < FM; ++mi)
        af[mi] = *(const v8s*)&As[(row0 + mi * 16 + lr) * 64 + ks * 32 + lk];
#pragma unroll
      for (int ni = 0; ni < FN; ++ni)
        bf_[ni] = *(const v8s*)&Bs[(col0 + ni * 16 + lr) * 64 + ks * 32 + lk];
      __builtin_amdgcn_s_setprio(1);
#pragma unroll
      for (int mi = 0; mi < FM; ++mi)
#pragma unroll
        for (int ni = 0; ni < FN; ++ni)
          acc[mi][ni] = __builtin_amdgcn_mfma_f32_16x16x32_bf16(af[mi], bf_[ni], acc[mi][ni], 0, 0, 0);
      __builtin_amdgcn_s_setprio(0);
    }
  };

  stage(As0, Bs0, 0);
  __syncthreads();
  int kt = 0;
  while (true) {
    if (kt + 64 < p.K) stage(As1, Bs1, kt + 64);
    compute(As0, Bs0);
    __syncthreads();
    kt += 64;
    if (kt >= p.K) break;
    if (kt + 64 < p.K) stage(As0, Bs0, kt + 64);
    compute(As1, Bs1);
    __syncthreads();
    kt += 64;
    if (kt >= p.K) break;
  }

  // epilogue; D: row=(lane>>4)*4+r, col=lane&15
#pragma unroll
  for (int mi = 0; mi < FM; ++mi) {
#pragma unroll
    for (int ni = 0; ni < FN; ++ni) {
#pragma unroll
      for (int r = 0; r < 4; ++r) {
        float v = acc[mi][ni][r];
        const int m = blockIdx.x * BM + row0 + mi * 16 + (lane >> 4) * 4 + r;
        const int n = blockIdx.y * BN + col0 + ni * 16 + lr;
        if constexpr (EPI == EPI_GELU_BF16) {
          p.Ob[(long)m * p.N + n] = __float2bfloat16(gelu_f(v + p.bias[n]));
        } else if constexpr (EPI == EPI_CONV2) {
          float t = gelu_f(v + p.bias[n]) + p.aux[(long)(m & 1023) * 768 + n];
          p.Of[(long)m * 768 + n] = t;
          p.Ob[(long)m * 768 + n] = __float2bfloat16(t);
        } else if constexpr (EPI == EPI_QKV) {
          float t = v + p.bias[n];
          int which = n / 768, nn = n - which * 768;
          int h = nn >> 6, d = nn & 63;
          long bh = (long)(m >> 10) * 12 + h;
          if (which < 2)
            p.Ob[(long)which * 3145728 + (bh << 16) + ((long)(m & 1023) << 6) + d] = __float2bfloat16(t);
          else
            p.Ob[6291456L + (bh << 16) + ((long)d << 10) + (m & 1023)] = __float2bfloat16(t);
        } else if constexpr (EPI == EPI_BIAS_F32) {
          p.Of[(long)m * p.N + n] = v + p.bias[n];
        } else if constexpr (EPI == EPI_RELU_BF16) {
          p.Ob[(long)m * p.N + n] = __float2bfloat16(fmaxf(v + p.bias[n], 0.f));
        }
      }
    }
  }
}

// ---------------- fused flash attention ----------------
// 1D grid of 384: qt = blk/48, bh = blk%48 (XCD-aligned). 4 waves x 32 q-rows.
// K/V dbuf in LDS, XOR-swizzled (rule 21): linear gload_lds dest +
// pre-swizzled global source col + matching XOR on ds_read col.
__global__ __launch_bounds__(256)
void attn_flash(const bf16* __restrict__ qkv, bf16* __restrict__ cc) {
  __shared__ __align__(16) bf16 Ks[2][64 * 64], Vs[2][64 * 64];
  __shared__ __align__(16) bf16 Pl[4][32 * 76];
  const int tid = threadIdx.x, lane = tid & 63, wid = tid >> 6;
  const int lr = lane & 15, lg = lane >> 4;
  const int blk = blockIdx.x;
  const int qt = blk / 48, bh = blk - qt * 48;
  const int b = bh / 12, h = bh - b * 12;
  const long qb = (long)bh << 16;
  const bf16* Qg = qkv + qb;
  const bf16* Kg = qkv + 3145728 + qb;
  const bf16* Vg = qkv + 6291456 + qb;
  const int q0 = qt * 128 + wid * 32;
  const int lrow8 = lane >> 3;
  const int scol = (((lane & 7) ^ (lane >> 3)) & 7) * 8;  // pre-swizzled source col
  const int rswz = (lr & 7) * 8;                          // read-side XOR

  v8s aq[2][2];
#pragma unroll
  for (int mi = 0; mi < 2; ++mi)
#pragma unroll
    for (int ks = 0; ks < 2; ++ks)
      aq[mi][ks] = *(const v8s*)&Qg[(long)(q0 + mi * 16 + lr) * 64 + ks * 32 + lg * 8];

  float mrow[2][4], lrow_[2][4];
  f32x4 acc[2][4] = {};
#pragma unroll
  for (int mi = 0; mi < 2; ++mi)
#pragma unroll
    for (int r = 0; r < 4; ++r) { mrow[mi][r] = -1e30f; lrow_[mi][r] = 0.f; }
  bf16* myP = &Pl[wid][0];

  auto stageKV = [&](int buf, int kt) {
#pragma unroll
    for (int i = 0; i < 2; ++i) {
      int c = wid + i * 4;
      g2lds16(&Kg[(long)(kt + c * 8 + lrow8) * 64 + scol], &Ks[buf][c << 9]);
      g2lds16(&Vg[((long)(c * 8 + lrow8) << 10) + kt + scol], &Vs[buf][c << 9]);
    }
  };

  stageKV(0, 0);
  __syncthreads();  // buf0 staged (vmcnt drained at barrier)

  for (int it = 0; it < 16; ++it) {
    const int cur = it & 1;
    if (it + 1 < 16) stageKV(cur ^ 1, (it + 1) * 64);
    const bf16* Kc = &Ks[cur][0];
    const bf16* Vc = &Vs[cur][0];

    // S = Q K^T
    f32x4 s[2][4] = {};
#pragma unroll
    for (int ks = 0; ks < 2; ++ks) {
      v8s bk[4];
#pragma unroll
      for (int ni = 0; ni < 4; ++ni)
        bk[ni] = *(const v8s*)&Kc[(ni * 16 + lr) * 64 + ((ks * 32 + lg * 8) ^ rswz)];
      __builtin_amdgcn_s_setprio(1);
#pragma unroll
      for (int mi = 0; mi < 2; ++mi)
#pragma unroll
        for (int ni = 0; ni < 4; ++ni)
          s[mi][ni] = __builtin_amdgcn_mfma_f32_16x16x32_bf16(aq[mi][ks], bk[ni], s[mi][ni], 0, 0, 0);
      __builtin_amdgcn_s_setprio(0);
    }

    // online softmax; write P (bf16) to per-wave LDS
#pragma unroll
    for (int mi = 0; mi < 2; ++mi) {
#pragma unroll
      for (int r = 0; r < 4; ++r) {
        float tm = fmaxf(fmaxf(s[mi][0][r], s[mi][1][r]), fmaxf(s[mi][2][r], s[mi][3][r]));
#pragma unroll
        for (int o = 1; o < 16; o <<= 1) tm = fmaxf(tm, __shfl_xor(tm, o));
        float mn = fmaxf(mrow[mi][r], tm);
        float al = __expf(mrow[mi][r] - mn);
        mrow[mi][r] = mn;
        float ps = 0.f;
        const int prow = (mi * 16 + lg * 4 + r) * 76;
#pragma unroll
        for (int ni = 0; ni < 4; ++ni) {
          float pv = __expf(s[mi][ni][r] - mn);
          myP[prow + ni * 16 + lr] = __float2bfloat16(pv);
          ps += pv;
        }
#pragma unroll
        for (int o = 1; o < 16; o <<= 1) ps += __shfl_xor(ps, o);
        lrow_[mi][r] = lrow_[mi][r] * al + ps;
#pragma unroll
        for (int ni = 0; ni < 4; ++ni) acc[mi][ni][r] *= al;
      }
    }

    // O += P * V  (V d-major -> contiguous B-frags)
#pragma unroll
    for (int ks = 0; ks < 2; ++ks) {
      v8s pa[2], bv[4];
#pragma unroll
      for (int mi = 0; mi < 2; ++mi)
        pa[mi] = *(const v8s*)&myP[(mi * 16 + lr) * 76 + ks * 32 + lg * 8];
#pragma unroll
      for (int ni = 0; ni < 4; ++ni)
        bv[ni] = *(const v8s*)&Vc[(ni * 16 + lr) * 64 + ((ks * 32 + lg * 8) ^ rswz)];
      __builtin_amdgcn_s_setprio(1);
#pragma unroll
      for (int mi = 0; mi < 2; ++mi)
#pragma unroll
        for (int ni = 0; ni < 4; ++ni)
          acc[mi][ni] = __builtin_amdgcn_mfma_f32_16x16x32_bf16(pa[mi], bv[ni], acc[mi][ni], 0, 0, 0);
      __builtin_amdgcn_s_setprio(0);
    }
    __syncthreads();  // all waves done with cur; next buffer fully staged
  }

  // epilogue: normalize and write concat layout [b*1024+t][h*64+d]
#pragma unroll
  for (int mi = 0; mi < 2; ++mi)
#pragma unroll
    for (int ni = 0; ni < 4; ++ni)
#pragma unroll
      for (int r = 0; r < 4; ++r) {
        int row = q0 + mi * 16 + lg * 4 + r;
        cc[((long)(b << 10) + row) * 768 + h * 64 + ni * 16 + lr] =
            __float2bfloat16(acc[mi][ni][r] / lrow_[mi][r]);
      }
}

// ---------------- residual + LayerNorm (row=768) ----------------
__global__ __launch_bounds__(256)
void ln_resid(const float* __restrict__ xin, const float* __restrict__ add,
              const float* __restrict__ g, const float* __restrict__ bb,
              float* __restrict__ xo, bf16* __restrict__ xbo) {
  __shared__ float red[4];
  long row = blockIdx.x;
  const float* xr = xin + row * 768;
  const float* ar = add + row * 768;
  int tid = threadIdx.x;
  float v0 = xr[tid] + ar[tid];
  float v1 = xr[tid + 256] + ar[tid + 256];
  float v2 = xr[tid + 512] + ar[tid + 512];
  float mean = block_sum(v0 + v1 + v2, red, tid) * (1.f / 768.f);
  v0 -= mean; v1 -= mean; v2 -= mean;
  float var = block_sum(v0 * v0 + v1 * v1 + v2 * v2, red, tid) * (1.f / 768.f);
  float rs = rsqrtf(var + 1e-5f);
  float o0 = v0 * rs * g[tid]       + bb[tid];
  float o1 = v1 * rs * g[tid + 256] + bb[tid + 256];
  float o2 = v2 * rs * g[tid + 512] + bb[tid + 512];
  float* xro = xo + row * 768;
  bf16*  xbr = xbo + row * 768;
  xro[tid] = o0; xro[tid + 256] = o1; xro[tid + 512] = o2;
  xbr[tid] = __float2bfloat16(o0);
  xbr[tid + 256] = __float2bfloat16(o1);
  xbr[tid + 512] = __float2bfloat16(o2);
}

// ---------------- classifier head ----------------
__global__ __launch_bounds__(256)
void head_cls(const float* __restrict__ x,
              const float* __restrict__ lnpg, const float* __restrict__ lnpb,
              const float* __restrict__ hlng, const float* __restrict__ hlnb,
              float* __restrict__ cls) {
  __shared__ float red[4];
  int b = blockIdx.x, tid = threadIdx.x;
  const float* xr = x + (long)b * 1024 * 768;  // row t=0
  float v0 = xr[tid], v1 = xr[tid + 256], v2 = xr[tid + 512];
  float s = block_sum(v0 + v1 + v2, red, tid) * (1.f / 768.f);
  v0 -= s; v1 -= s; v2 -= s;
  float q = block_sum(v0 * v0 + v1 * v1 + v2 * v2, red, tid) * (1.f / 768.f);
  float r = rsqrtf(q + 1e-5f);
  v0 = v0 * r * lnpg[tid]       + lnpb[tid];
  v1 = v1 * r * lnpg[tid + 256] + lnpb[tid + 256];
  v2 = v2 * r * lnpg[tid + 512] + lnpb[tid + 512];
  s = block_sum(v0 + v1 + v2, red, tid) * (1.f / 768.f);
  v0 -= s; v1 -= s; v2 -= s;
  q = block_sum(v0 * v0 + v1 * v1 + v2 * v2, red, tid) * (1.f / 768.f);
  r = rsqrtf(q + 1e-5f);
  cls[b * 768 + tid]       = v0 * r * hlng[tid]       + hlnb[tid];
  cls[b * 768 + tid + 256] = v1 * r * hlng[tid + 256] + hlnb[tid + 256];
  cls[b * 768 + tid + 512] = v2 * r * hlng[tid + 512] + hlnb[tid + 512];
}

// split-K GEMV stage A
__global__ __launch_bounds__(256)
void mlp_part(const float* __restrict__ in, const float* __restrict__ wmat,
              float* __restrict__ part, int IN, int OUTP, int ET) {
  __shared__ float cin[4][96];
  __shared__ float red[8][32][16];
  int tid = threadIdx.x;
  int tx = tid & 31, ty = tid >> 5;
  int e0 = blockIdx.y * ET;
  for (int i = tid; i < 4 * ET; i += 256) {
    int b = i / ET, el = i - b * ET;
    cin[b][el] = in[b * IN + e0 + el];
  }
  __syncthreads();
  f32x4 acc[4] = {};
  const float* wp = wmat + (long)e0 * OUTP + (blockIdx.x * 32 + tx) * 4;
  const int iters = ET >> 3;
  for (int i = 0; i < iters; ++i) {
    int el = ty + i * 8;
    f32x4 w = *(const f32x4*)(wp + (long)el * OUTP);
#pragma unroll
    for (int b = 0; b < 4; ++b) acc[b] += cin[b][el] * w;
  }
#pragma unroll
  for (int b = 0; b < 4; ++b) *(f32x4*)&red[ty][tx][b * 4] = acc[b];
  __syncthreads();
  if (tid < 128) {
    int rx = tid & 31, b = tid >> 5;
    f32x4 s = {};
#pragma unroll
    for (int t = 0; t < 8; ++t) s += *(const f32x4*)&red[t][rx][b * 4];
    *(f32x4*)&part[((long)blockIdx.y * 4 + b) * OUTP + (blockIdx.x * 32 + rx) * 4] = s;
  }
}

__global__ __launch_bounds__(256)
void mlp_reduce(const float* __restrict__ part, const float* __restrict__ bias,
                float* __restrict__ out, int OUTP, int S, int relu) {
  int idx = blockIdx.x * 256 + threadIdx.x;
  int b = idx / OUTP, j = idx - b * OUTP;
  float s = bias[j];
  for (int t = 0; t < S; ++t) s += part[((long)t * 4 + b) * OUTP + j];
  out[idx] = relu ? fmaxf(s, 0.f) : s;
}

// C=527 logits in [4][640] padded rows
__global__ __launch_bounds__(256)
void head_softmax(const float* __restrict__ lg, float* __restrict__ out) {
  __shared__ float red[4];
  int b = blockIdx.x, tid = threadIdx.x;
  const float* r = lg + (long)b * 640;
  float v0 = r[tid];
  float v1 = tid + 256 < 527 ? r[tid + 256] : -1e30f;
  float v2 = tid + 512 < 527 ? r[tid + 512] : -1e30f;
  float mx = block_max(fmaxf(v0, fmaxf(v1, v2)), red, tid);
  float e0 = __expf(v0 - mx);
  float e1 = tid + 256 < 527 ? __expf(v1 - mx) : 0.f;
  float e2 = tid + 512 < 527 ? __expf(v2 - mx) : 0.f;
  float sm = block_sum(e0 + e1 + e2, red, tid);
  float inv = 1.f / sm;
  out[(long)b * 527 + tid] = e0 * inv;
  if (tid + 256 < 527) out[(long)b * 527 + tid + 256] = e1 * inv;
  if (tid + 512 < 527) out[(long)b * 527 + tid + 512] = e2 * inv;
}

// ---------------- launcher ----------------
extern "C" void kernel_launch(void* const* d_in, const int* in_sizes, int n_in,
                              void* d_out, int out_size, void* d_ws, size_t ws_size,
                              hipStream_t stream) {
  const float* x_in    = (const float*)d_in[0];
  const float* conv1_w = (const float*)d_in[1];
  const float* conv1_b = (const float*)d_in[2];
  const float* conv2_w = (const float*)d_in[3];
  const float* conv2_b = (const float*)d_in[4];
  const float* pos_emb = (const float*)d_in[5];
  const float* ln1_g   = (const float*)d_in[6];
  const float* ln1_b   = (const float*)d_in[7];
  const float* wq      = (const float*)d_in[8];
  const float* bq      = (const float*)d_in[9];
  const float* wk      = (const float*)d_in[10];
  const float* bk      = (const float*)d_in[11];
  const float* wv      = (const float*)d_in[12];
  const float* bv      = (const float*)d_in[13];
  const float* wo      = (const float*)d_in[14];
  const float* bo      = (const float*)d_in[15];
  const float* w1      = (const float*)d_in[16];
  const float* b1      = (const float*)d_in[17];
  const float* w2      = (const float*)d_in[18];
  const float* b2      = (const float*)d_in[19];
  const float* ln2_g   = (const float*)d_in[20];
  const float* ln2_b   = (const float*)d_in[21];
  const float* lnp_g   = (const float*)d_in[22];
  const float* lnp_b   = (const float*)d_in[23];
  const float* hln_g   = (const float*)d_in[24];
  const float* hln_b   = (const float*)d_in[25];
  const float* hw1     = (const float*)d_in[26];
  const float* hb1     = (const float*)d_in[27];
  const float* hw2     = (const float*)d_in[28];
  const float* hb2     = (const float*)d_in[29];

  // workspace layout
  char* w = (char*)d_ws;
  bf16*  wqkvT = (bf16*)(w);                      // 6*2304*768 bf16
  bf16*  woT   = (bf16*)(w + 21233664);           // 6*768*768
  bf16*  w1T   = (bf16*)(w + 28311552);           // 6*3072*768
  bf16*  w2T   = (bf16*)(w + 56623104);           // 6*768*3072
  bf16*  wc1T  = (bf16*)(w + 84934656);           // 768*256
  bf16*  wc2T  = (bf16*)(w + 85327872);           // 768*2304
  float* bqkv  = (float*)(w + 88866816);          // 6*2304 f32
  float* Xf    = (float*)(w + 88922112);          // 4096*768 f32
  bf16*  Xb    = (bf16*)(w + 101505024);          // 4096*768
  bf16*  qkv   = (bf16*)(w + 107796480);          // 3*4096*768 (q t-major, k t-major, v d-major)
  bf16*  CC    = (bf16*)(w + 126670848);          // 4096*768
  float* ATTN  = (float*)(w + 132962304);         // 4096*768 f32
  char*  BIG   = w + 145545216;                   // 50,331,648 shared region
  bf16*  A1  = (bf16*)(BIG);                      // 8192*256   (conv phase)
  bf16*  Y1G = (bf16*)(BIG + 4194304);            // 8192*768   (conv phase)
  bf16*  A2  = (bf16*)(BIG + 16777216);           // 4096*2304  (conv phase)
  bf16*  Hh  = (bf16*)(BIG);                      // 4096*3072  (ffn phase)
  float* FFN = (float*)(BIG + 25165824);          // 4096*768 f32 (ffn phase)
  // head phase (aliases, used only after last FFN)
  float* CLS  = (float*)(BIG);                    // 4*768
  float* HID  = (float*)(BIG + 16384);            // 4*3072
  float* LGT  = (float*)(BIG + 81920);            // 4*640
  float* PT1  = (float*)(BIG + 131072);           // 16*4*3072
  float* PT2  = (float*)(BIG + 1048576);          // 32*4*640
  float* HB2P = (float*)(BIG + 1572864);          // 640
  float* HW2P = (float*)(BIG + 1605632);          // 3072*640

  // ---- weight prep ----
  tconv<<<dim3(2, 24, 72), 256, 0, stream>>>(wq, wqkvT,            768, 64,   49152L, 1769472L, 49152L, 12);
  tconv<<<dim3(2, 24, 72), 256, 0, stream>>>(wk, wqkvT + 589824,   768, 64,   49152L, 1769472L, 49152L, 12);
  tconv<<<dim3(2, 24, 72), 256, 0, stream>>>(wv, wqkvT + 1179648,  768, 64,   49152L, 1769472L, 49152L, 12);
  tconv<<<dim3(24, 24, 6), 256, 0, stream>>>(wo, woT,              768, 768,  589824L, 589824L, 0L, 1);
  tconv<<<dim3(96, 24, 6), 256, 0, stream>>>(w1, w1T,              768, 3072, 2359296L, 2359296L, 0L, 1);
  tconv<<<dim3(24, 96, 6), 256, 0, stream>>>(w2, w2T,              3072, 768, 2359296L, 2359296L, 0L, 1);
  prep_cw<<<768,  256, 0, stream>>>(conv1_w, wc1T, 80, 256);
  prep_cw<<<6912, 256, 0, stream>>>(conv2_w, wc2T, 768, 2304);
  prep_bias<<<54, 256, 0, stream>>>(bq, bk, bv, bqkv);

  // ---- convs ----
  im2col1<<<8192, 256, 0, stream>>>(x_in, A1);
  { GP p{}; p.A = A1; p.B = wc1T; p.bias = conv1_b; p.Ob = Y1G;
    p.M = 8192; p.N = 768; p.K = 256;
    gemm_bt<128,64,2,2,EPI_GELU_BF16><<<dim3(64,12,1),256,0,stream>>>(p); }
  im2col2<<<36864, 256, 0, stream>>>(Y1G, A2);
  { GP p{}; p.A = A2; p.B = wc2T; p.bias = conv2_b; p.Of = Xf; p.Ob = Xb; p.aux = pos_emb;
    p.M = 4096; p.N = 768; p.K = 2304;
    gemm_bt<128,64,2,2,EPI_CONV2><<<dim3(32,12,1),256,0,stream>>>(p); }

  // ---- transformer layers ----
  for (int l = 0; l < 6; ++l) {
    { GP p{}; p.A = Xb; p.B = wqkvT + (long)l * 1769472; p.bias = bqkv + l * 2304;
      p.Ob = qkv; p.M = 4096; p.N = 2304; p.K = 768;
      gemm_bt<128,128,2,2,EPI_QKV><<<dim3(32,18,1),256,0,stream>>>(p); }
    attn_flash<<<384, 256, 0, stream>>>(qkv, CC);
    { GP p{}; p.A = CC; p.B = woT + (long)l * 589824; p.bias = bo + l * 768; p.Of = ATTN;
      p.M = 4096; p.N = 768; p.K = 768;
      gemm_bt<128,64,2,2,EPI_BIAS_F32><<<dim3(32,12,1),256,0,stream>>>(p); }
    ln_resid<<<4096, 256, 0, stream>>>(Xf, ATTN, ln1_g + l * 768, ln1_b + l * 768, Xf, Xb);
    { GP p{}; p.A = Xb; p.B = w1T + (long)l * 2359296; p.bias = b1 + l * 3072; p.Ob = Hh;
      p.M = 4096; p.N = 3072; p.K = 768;
      gemm_bt<256,256,2,4,EPI_RELU_BF16><<<dim3(16,12,1),512,0,stream>>>(p); }
    { GP p{}; p.A = Hh; p.B = w2T + (long)l * 2359296; p.bias = b2 + l * 768; p.Of = FFN;
      p.M = 4096; p.N = 768; p.K = 3072;
      gemm_bt<128,64,2,2,EPI_BIAS_F32><<<dim3(32,12,1),256,0,stream>>>(p); }
    ln_resid<<<4096, 256, 0, stream>>>(Xf, FFN, ln2_g + l * 768, ln2_b + l * 768, Xf, Xb);
  }

  // ---- head ----
  head_cls<<<4, 256, 0, stream>>>(Xf, lnp_g, lnp_b, hln_g, hln_b, CLS);
  prep_hw2<<<7680, 256, 0, stream>>>(hw2, hb2, HW2P, HB2P);
  mlp_part<<<dim3(24, 16), 256, 0, stream>>>(CLS, hw1, PT1, 768, 3072, 48);
  mlp_reduce<<<48, 256, 0, stream>>>(PT1, hb1, HID, 3072, 16, 1);
  mlp_part<<<dim3(5, 32), 256, 0, stream>>>(HID, HW2P, PT2, 3072, 640, 96);
  mlp_reduce<<<10, 256, 0, stream>>>(PT2, HB2P, LGT, 640, 32, 0);
  head_softmax<<<4, 256, 0, stream>>>(LGT, (float*)d_out);
}

// Round 11
// 1494.193 us; speedup vs baseline: 1.9114x; 1.4449x over previous
//
#include <hip/hip_runtime.h>
#include <hip/hip_bf16.h>

typedef __hip_bfloat16 bf16;
using v8s   = __attribute__((ext_vector_type(8))) short;
using f32x4 = __attribute__((ext_vector_type(4))) float;

#define DI __device__ __forceinline__

DI float gelu_f(float x) { return 0.5f * x * (1.f + erff(x * 0.70710678118654752f)); }

DI void g2lds16(const bf16* g, bf16* l) {
  __builtin_amdgcn_global_load_lds((const __attribute__((address_space(1))) void*)g,
                                   (__attribute__((address_space(3))) void*)l, 16, 0, 0);
}

// ---------------- block reduction helpers (256 threads, 4 waves) ----------------
DI float block_sum(float v, float* red, int tid) {
#pragma unroll
  for (int o = 32; o > 0; o >>= 1) v += __shfl_down(v, o);
  __syncthreads();
  if ((tid & 63) == 0) red[tid >> 6] = v;
  __syncthreads();
  return red[0] + red[1] + red[2] + red[3];
}
DI float block_max(float v, float* red, int tid) {
#pragma unroll
  for (int o = 32; o > 0; o >>= 1) v = fmaxf(v, __shfl_down(v, o));
  __syncthreads();
  if ((tid & 63) == 0) red[tid >> 6] = v;
  __syncthreads();
  return fmaxf(fmaxf(red[0], red[1]), fmaxf(red[2], red[3]));
}

// ---------------- weight prep ----------------
__global__ __launch_bounds__(256)
void tconv(const float* __restrict__ in, bf16* __restrict__ out,
           int R, int C, long inStrideZ, long outStrideL, long outStrideH, int zmod) {
  __shared__ float tile[32][33];
  int z = blockIdx.z;
  int lz = z / zmod, hz = z - lz * zmod;
  in  += (long)z * inStrideZ;
  out += (long)lz * outStrideL + (long)hz * outStrideH;
  int cb = blockIdx.x * 32, rb = blockIdx.y * 32;
  int tx = threadIdx.x & 31, ty = threadIdx.x >> 5;  // 32x8
#pragma unroll
  for (int i = 0; i < 32; i += 8)
    tile[ty + i][tx] = in[(long)(rb + ty + i) * C + cb + tx];
  __syncthreads();
#pragma unroll
  for (int i = 0; i < 32; i += 8)
    out[(long)(cb + ty + i) * R + rb + tx] = __float2bfloat16(tile[tx][ty + i]);
}

__global__ __launch_bounds__(256)
void prep_cw(const float* __restrict__ wsrc, bf16* __restrict__ o, int IC, int KT) {
  int idx = blockIdx.x * 256 + threadIdx.x;
  int oc = idx / KT, kp = idx - oc * KT;
  float v = 0.f;
  if (kp < IC * 3) {
    int kk = kp / IC, ic = kp - kk * IC;
    v = wsrc[(oc * IC + ic) * 3 + kk];
  }
  o[idx] = __float2bfloat16(v);
}

__global__ __launch_bounds__(256)
void prep_bias(const float* __restrict__ bq, const float* __restrict__ bk,
               const float* __restrict__ bv, float* __restrict__ o) {
  int idx = blockIdx.x * 256 + threadIdx.x;  // 6*2304
  int l = idx / 2304, n = idx - l * 2304;
  int which = n / 768, r = n - which * 768;
  const float* src = which == 0 ? bq : (which == 1 ? bk : bv);
  o[idx] = src[l * 768 + r];
}

// pad-repack head layer-2 weights: hw2 [3072][527] -> hw2p [3072][640] (zero pad)
__global__ __launch_bounds__(256)
void prep_hw2(const float* __restrict__ hw2, const float* __restrict__ hb2,
              float* __restrict__ hw2p, float* __restrict__ hb2p) {
  int idx = blockIdx.x * 256 + threadIdx.x;  // 3072*640
  int e = idx / 640, c = idx - e * 640;
  hw2p[idx] = c < 527 ? hw2[(long)e * 527 + c] : 0.f;
  if (idx < 640) hb2p[idx] = idx < 527 ? hb2[idx] : 0.f;
}

// ---------------- im2col ----------------
__global__ __launch_bounds__(256)
void im2col1(const float* __restrict__ x, bf16* __restrict__ out) {
  int idx = blockIdx.x * 256 + threadIdx.x;  // 8192*256
  int m = idx >> 8, kp = idx & 255;
  float v = 0.f;
  if (kp < 240) {
    int kk = kp / 80, ic = kp - kk * 80;
    int t = (m & 2047) + kk - 1;
    int b = m >> 11;
    if ((unsigned)t < 2048u) v = x[((long)(b * 80 + ic) << 11) + t];
  }
  out[idx] = __float2bfloat16(v);
}

__global__ __launch_bounds__(256)
void im2col2(const bf16* __restrict__ y, bf16* __restrict__ out) {
  int idx = blockIdx.x * 256 + threadIdx.x;  // 4096*2304
  int m = idx / 2304, kp = idx - m * 2304;
  int kk = kp / 768, ic = kp - kk * 768;
  int t = 2 * (m & 1023) + kk - 1;
  bf16 v = __float2bfloat16(0.f);
  if ((unsigned)t < 2048u) v = y[((long)(m >> 10) * 2048 + t) * 768 + ic];
  out[idx] = v;
}

// ---------------- GEMM: C[m][n] = sum_k A[m][k]*B[n][k]  (both bf16, K%64==0) ----------------
// 2-phase double-buffered K-loop, 4 waves. LDS XOR-swizzled (rule 21): the
// [rows][64]-bf16 tile has a 128B row stride -> 16-way bank conflict on
// ds_read_b128 (lanes lr=0..15 read different rows at one 16B column slot).
// Fix: pre-swizzle the GLOBAL source column by (lane&7)^(lane>>3) (LDS dest
// stays linear for global_load_lds) and XOR the ds_read col with (lr&7)*8 --
// row&7 == lr&7 for all fragment rows (row0, mi*16 are multiples of 8).
enum { EPI_GELU_BF16, EPI_CONV2, EPI_QKV, EPI_BIAS_F32, EPI_RELU_BF16 };

struct GP {
  const bf16* A; const bf16* B; const float* bias;
  bf16* Ob; float* Of; const float* aux;
  int M, N, K; long sA, sB, sC; int zoff;
};

template<int BM, int BN, int WM, int WN, int EPI>
__global__ __launch_bounds__(WM * WN * 64, 2)
void gemm_bt(GP p) {
  constexpr int WAVES = WM * WN;
  constexpr int FM = BM / WM / 16, FN = BN / WN / 16;
  __shared__ __align__(16) bf16 As0[BM * 64], Bs0[BN * 64];
  __shared__ __align__(16) bf16 As1[BM * 64], Bs1[BN * 64];
  const int tid = threadIdx.x;
  const int lane = tid & 63, wid = tid >> 6;
  const int wr = wid / WN, wc = wid - wr * WN;
  const int row0 = wr * (BM / WM), col0 = wc * (BN / WN);
  const int lr = lane & 15, lk = (lane >> 4) * 8;
  const int lrow = lane >> 3;
  const int scol = (((lane & 7) ^ (lane >> 3)) & 7) * 8;  // pre-swizzled source col
  const int rswz = (lr & 7) * 8;                          // read-side XOR
  const int z = blockIdx.z;
  const bf16* Ab = p.A + (long)z * p.sA + (long)blockIdx.x * BM * p.K;
  const bf16* Bb = p.B + (long)z * p.sB + (long)blockIdx.y * BN * p.K;
  f32x4 acc[FM][FN] = {};

  auto stage = [&](bf16* As, bf16* Bs, int kt) {
#pragma unroll
    for (int i = 0; i < BM / 8 / WAVES; ++i) {
      const int c = wid + i * WAVES;  // chunk of 8 rows (1KB)
      g2lds16(&Ab[(long)(c * 8 + lrow) * p.K + kt + scol], &As[c << 9]);
    }
#pragma unroll
    for (int i = 0; i < BN / 8 / WAVES; ++i) {
      const int c = wid + i * WAVES;
      g2lds16(&Bb[(long)(c * 8 + lrow) * p.K + kt + scol], &Bs[c << 9]);
    }
  };

  auto compute = [&](const bf16* As, const bf16* Bs) {
#pragma unroll
    for (int ks = 0; ks < 2; ++ks) {
      v8s af[FM], bf_[FN];
#pragma unroll
      for (int mi = 0; mi < FM; ++mi)
        af[mi] = *(const v8s*)&As[(row0 + mi * 16 + lr) * 64 + ((ks * 32 + lk) ^ rswz)];
#pragma unroll
      for (int ni = 0; ni < FN; ++ni)
        bf_[ni] = *(const v8s*)&Bs[(col0 + ni * 16 + lr) * 64 + ((ks * 32 + lk) ^ rswz)];
      __builtin_amdgcn_s_setprio(1);
#pragma unroll
      for (int mi = 0; mi < FM; ++mi)
#pragma unroll
        for (int ni = 0; ni < FN; ++ni)
          acc[mi][ni] = __builtin_amdgcn_mfma_f32_16x16x32_bf16(af[mi], bf_[ni], acc[mi][ni], 0, 0, 0);
      __builtin_amdgcn_s_setprio(0);
    }
  };

  stage(As0, Bs0, 0);
  __syncthreads();
  int kt = 0;
  while (true) {
    if (kt + 64 < p.K) stage(As1, Bs1, kt + 64);
    compute(As0, Bs0);
    __syncthreads();
    kt += 64;
    if (kt >= p.K) break;
    if (kt + 64 < p.K) stage(As0, Bs0, kt + 64);
    compute(As1, Bs1);
    __syncthreads();
    kt += 64;
    if (kt >= p.K) break;
  }

  // epilogue; D: row=(lane>>4)*4+r, col=lane&15
#pragma unroll
  for (int mi = 0; mi < FM; ++mi) {
#pragma unroll
    for (int ni = 0; ni < FN; ++ni) {
#pragma unroll
      for (int r = 0; r < 4; ++r) {
        float v = acc[mi][ni][r];
        const int m = blockIdx.x * BM + row0 + mi * 16 + (lane >> 4) * 4 + r;
        const int n = blockIdx.y * BN + col0 + ni * 16 + lr;
        if constexpr (EPI == EPI_GELU_BF16) {
          p.Ob[(long)m * p.N + n] = __float2bfloat16(gelu_f(v + p.bias[n]));
        } else if constexpr (EPI == EPI_CONV2) {
          float t = gelu_f(v + p.bias[n]) + p.aux[(long)(m & 1023) * 768 + n];
          p.Of[(long)m * 768 + n] = t;
          p.Ob[(long)m * 768 + n] = __float2bfloat16(t);
        } else if constexpr (EPI == EPI_QKV) {
          float t = v + p.bias[n];
          int which = n / 768, nn = n - which * 768;
          int h = nn >> 6, d = nn & 63;
          long bh = (long)(m >> 10) * 12 + h;
          if (which < 2)
            p.Ob[(long)which * 3145728 + (bh << 16) + ((long)(m & 1023) << 6) + d] = __float2bfloat16(t);
          else
            p.Ob[6291456L + (bh << 16) + ((long)d << 10) + (m & 1023)] = __float2bfloat16(t);
        } else if constexpr (EPI == EPI_BIAS_F32) {
          p.Of[(long)m * p.N + n] = v + p.bias[n];
        } else if constexpr (EPI == EPI_RELU_BF16) {
          p.Ob[(long)m * p.N + n] = __float2bfloat16(fmaxf(v + p.bias[n], 0.f));
        }
      }
    }
  }
}

// ---------------- fused flash attention ----------------
// 1D grid of 384: qt = blk/48, bh = blk%48 (XCD-aligned). 4 waves x 32 q-rows.
// K/V dbuf in LDS, XOR-swizzled (rule 21).
__global__ __launch_bounds__(256)
void attn_flash(const bf16* __restrict__ qkv, bf16* __restrict__ cc) {
  __shared__ __align__(16) bf16 Ks[2][64 * 64], Vs[2][64 * 64];
  __shared__ __align__(16) bf16 Pl[4][32 * 76];
  const int tid = threadIdx.x, lane = tid & 63, wid = tid >> 6;
  const int lr = lane & 15, lg = lane >> 4;
  const int blk = blockIdx.x;
  const int qt = blk / 48, bh = blk - qt * 48;
  const int b = bh / 12, h = bh - b * 12;
  const long qb = (long)bh << 16;
  const bf16* Qg = qkv + qb;
  const bf16* Kg = qkv + 3145728 + qb;
  const bf16* Vg = qkv + 6291456 + qb;
  const int q0 = qt * 128 + wid * 32;
  const int lrow8 = lane >> 3;
  const int scol = (((lane & 7) ^ (lane >> 3)) & 7) * 8;  // pre-swizzled source col
  const int rswz = (lr & 7) * 8;                          // read-side XOR

  v8s aq[2][2];
#pragma unroll
  for (int mi = 0; mi < 2; ++mi)
#pragma unroll
    for (int ks = 0; ks < 2; ++ks)
      aq[mi][ks] = *(const v8s*)&Qg[(long)(q0 + mi * 16 + lr) * 64 + ks * 32 + lg * 8];

  float mrow[2][4], lrow_[2][4];
  f32x4 acc[2][4] = {};
#pragma unroll
  for (int mi = 0; mi < 2; ++mi)
#pragma unroll
    for (int r = 0; r < 4; ++r) { mrow[mi][r] = -1e30f; lrow_[mi][r] = 0.f; }
  bf16* myP = &Pl[wid][0];

  auto stageKV = [&](int buf, int kt) {
#pragma unroll
    for (int i = 0; i < 2; ++i) {
      int c = wid + i * 4;
      g2lds16(&Kg[(long)(kt + c * 8 + lrow8) * 64 + scol], &Ks[buf][c << 9]);
      g2lds16(&Vg[((long)(c * 8 + lrow8) << 10) + kt + scol], &Vs[buf][c << 9]);
    }
  };

  stageKV(0, 0);
  __syncthreads();  // buf0 staged (vmcnt drained at barrier)

  for (int it = 0; it < 16; ++it) {
    const int cur = it & 1;
    if (it + 1 < 16) stageKV(cur ^ 1, (it + 1) * 64);
    const bf16* Kc = &Ks[cur][0];
    const bf16* Vc = &Vs[cur][0];

    // S = Q K^T
    f32x4 s[2][4] = {};
#pragma unroll
    for (int ks = 0; ks < 2; ++ks) {
      v8s bk[4];
#pragma unroll
      for (int ni = 0; ni < 4; ++ni)
        bk[ni] = *(const v8s*)&Kc[(ni * 16 + lr) * 64 + ((ks * 32 + lg * 8) ^ rswz)];
      __builtin_amdgcn_s_setprio(1);
#pragma unroll
      for (int mi = 0; mi < 2; ++mi)
#pragma unroll
        for (int ni = 0; ni < 4; ++ni)
          s[mi][ni] = __builtin_amdgcn_mfma_f32_16x16x32_bf16(aq[mi][ks], bk[ni], s[mi][ni], 0, 0, 0);
      __builtin_amdgcn_s_setprio(0);
    }

    // online softmax; write P (bf16) to per-wave LDS
#pragma unroll
    for (int mi = 0; mi < 2; ++mi) {
#pragma unroll
      for (int r = 0; r < 4; ++r) {
        float tm = fmaxf(fmaxf(s[mi][0][r], s[mi][1][r]), fmaxf(s[mi][2][r], s[mi][3][r]));
#pragma unroll
        for (int o = 1; o < 16; o <<= 1) tm = fmaxf(tm, __shfl_xor(tm, o));
        float mn = fmaxf(mrow[mi][r], tm);
        float al = __expf(mrow[mi][r] - mn);
        mrow[mi][r] = mn;
        float ps = 0.f;
        const int prow = (mi * 16 + lg * 4 + r) * 76;
#pragma unroll
        for (int ni = 0; ni < 4; ++ni) {
          float pv = __expf(s[mi][ni][r] - mn);
          myP[prow + ni * 16 + lr] = __float2bfloat16(pv);
          ps += pv;
        }
#pragma unroll
        for (int o = 1; o < 16; o <<= 1) ps += __shfl_xor(ps, o);
        lrow_[mi][r] = lrow_[mi][r] * al + ps;
#pragma unroll
        for (int ni = 0; ni < 4; ++ni) acc[mi][ni][r] *= al;
      }
    }

    // O += P * V  (V d-major -> contiguous B-frags)
#pragma unroll
    for (int ks = 0; ks < 2; ++ks) {
      v8s pa[2], bv[4];
#pragma unroll
      for (int mi = 0; mi < 2; ++mi)
        pa[mi] = *(const v8s*)&myP[(mi * 16 + lr) * 76 + ks * 32 + lg * 8];
#pragma unroll
      for (int ni = 0; ni < 4; ++ni)
        bv[ni] = *(const v8s*)&Vc[(ni * 16 + lr) * 64 + ((ks * 32 + lg * 8) ^ rswz)];
      __builtin_amdgcn_s_setprio(1);
#pragma unroll
      for (int mi = 0; mi < 2; ++mi)
#pragma unroll
        for (int ni = 0; ni < 4; ++ni)
          acc[mi][ni] = __builtin_amdgcn_mfma_f32_16x16x32_bf16(pa[mi], bv[ni], acc[mi][ni], 0, 0, 0);
      __builtin_amdgcn_s_setprio(0);
    }
    __syncthreads();  // all waves done with cur; next buffer fully staged
  }

  // epilogue: normalize and write concat layout [b*1024+t][h*64+d]
#pragma unroll
  for (int mi = 0; mi < 2; ++mi)
#pragma unroll
    for (int ni = 0; ni < 4; ++ni)
#pragma unroll
      for (int r = 0; r < 4; ++r) {
        int row = q0 + mi * 16 + lg * 4 + r;
        cc[((long)(b << 10) + row) * 768 + h * 64 + ni * 16 + lr] =
            __float2bfloat16(acc[mi][ni][r] / lrow_[mi][r]);
      }
}

// ---------------- residual + LayerNorm (row=768) ----------------
__global__ __launch_bounds__(256)
void ln_resid(const float* __restrict__ xin, const float* __restrict__ add,
              const float* __restrict__ g, const float* __restrict__ bb,
              float* __restrict__ xo, bf16* __restrict__ xbo) {
  __shared__ float red[4];
  long row = blockIdx.x;
  const float* xr = xin + row * 768;
  const float* ar = add + row * 768;
  int tid = threadIdx.x;
  float v0 = xr[tid] + ar[tid];
  float v1 = xr[tid + 256] + ar[tid + 256];
  float v2 = xr[tid + 512] + ar[tid + 512];
  float mean = block_sum(v0 + v1 + v2, red, tid) * (1.f / 768.f);
  v0 -= mean; v1 -= mean; v2 -= mean;
  float var = block_sum(v0 * v0 + v1 * v1 + v2 * v2, red, tid) * (1.f / 768.f);
  float rs = rsqrtf(var + 1e-5f);
  float o0 = v0 * rs * g[tid]       + bb[tid];
  float o1 = v1 * rs * g[tid + 256] + bb[tid + 256];
  float o2 = v2 * rs * g[tid + 512] + bb[tid + 512];
  float* xro = xo + row * 768;
  bf16*  xbr = xbo + row * 768;
  xro[tid] = o0; xro[tid + 256] = o1; xro[tid + 512] = o2;
  xbr[tid] = __float2bfloat16(o0);
  xbr[tid + 256] = __float2bfloat16(o1);
  xbr[tid + 512] = __float2bfloat16(o2);
}

// ---------------- classifier head ----------------
__global__ __launch_bounds__(256)
void head_cls(const float* __restrict__ x,
              const float* __restrict__ lnpg, const float* __restrict__ lnpb,
              const float* __restrict__ hlng, const float* __restrict__ hlnb,
              float* __restrict__ cls) {
  __shared__ float red[4];
  int b = blockIdx.x, tid = threadIdx.x;
  const float* xr = x + (long)b * 1024 * 768;  // row t=0
  float v0 = xr[tid], v1 = xr[tid + 256], v2 = xr[tid + 512];
  float s = block_sum(v0 + v1 + v2, red, tid) * (1.f / 768.f);
  v0 -= s; v1 -= s; v2 -= s;
  float q = block_sum(v0 * v0 + v1 * v1 + v2 * v2, red, tid) * (1.f / 768.f);
  float r = rsqrtf(q + 1e-5f);
  v0 = v0 * r * lnpg[tid]       + lnpb[tid];
  v1 = v1 * r * lnpg[tid + 256] + lnpb[tid + 256];
  v2 = v2 * r * lnpg[tid + 512] + lnpb[tid + 512];
  s = block_sum(v0 + v1 + v2, red, tid) * (1.f / 768.f);
  v0 -= s; v1 -= s; v2 -= s;
  q = block_sum(v0 * v0 + v1 * v1 + v2 * v2, red, tid) * (1.f / 768.f);
  r = rsqrtf(q + 1e-5f);
  cls[b * 768 + tid]       = v0 * r * hlng[tid]       + hlnb[tid];
  cls[b * 768 + tid + 256] = v1 * r * hlng[tid + 256] + hlnb[tid + 256];
  cls[b * 768 + tid + 512] = v2 * r * hlng[tid + 512] + hlnb[tid + 512];
}

// split-K GEMV stage A
__global__ __launch_bounds__(256)
void mlp_part(const float* __restrict__ in, const float* __restrict__ wmat,
              float* __restrict__ part, int IN, int OUTP, int ET) {
  __shared__ float cin[4][96];
  __shared__ float red[8][32][16];
  int tid = threadIdx.x;
  int tx = tid & 31, ty = tid >> 5;
  int e0 = blockIdx.y * ET;
  for (int i = tid; i < 4 * ET; i += 256) {
    int b = i / ET, el = i - b * ET;
    cin[b][el] = in[b * IN + e0 + el];
  }
  __syncthreads();
  f32x4 acc[4] = {};
  const float* wp = wmat + (long)e0 * OUTP + (blockIdx.x * 32 + tx) * 4;
  const int iters = ET >> 3;
  for (int i = 0; i < iters; ++i) {
    int el = ty + i * 8;
    f32x4 w = *(const f32x4*)(wp + (long)el * OUTP);
#pragma unroll
    for (int b = 0; b < 4; ++b) acc[b] += cin[b][el] * w;
  }
#pragma unroll
  for (int b = 0; b < 4; ++b) *(f32x4*)&red[ty][tx][b * 4] = acc[b];
  __syncthreads();
  if (tid < 128) {
    int rx = tid & 31, b = tid >> 5;
    f32x4 s = {};
#pragma unroll
    for (int t = 0; t < 8; ++t) s += *(const f32x4*)&red[t][rx][b * 4];
    *(f32x4*)&part[((long)blockIdx.y * 4 + b) * OUTP + (blockIdx.x * 32 + rx) * 4] = s;
  }
}

__global__ __launch_bounds__(256)
void mlp_reduce(const float* __restrict__ part, const float* __restrict__ bias,
                float* __restrict__ out, int OUTP, int S, int relu) {
  int idx = blockIdx.x * 256 + threadIdx.x;
  int b = idx / OUTP, j = idx - b * OUTP;
  float s = bias[j];
  for (int t = 0; t < S; ++t) s += part[((long)t * 4 + b) * OUTP + j];
  out[idx] = relu ? fmaxf(s, 0.f) : s;
}

// C=527 logits in [4][640] padded rows
__global__ __launch_bounds__(256)
void head_softmax(const float* __restrict__ lg, float* __restrict__ out) {
  __shared__ float red[4];
  int b = blockIdx.x, tid = threadIdx.x;
  const float* r = lg + (long)b * 640;
  float v0 = r[tid];
  float v1 = tid + 256 < 527 ? r[tid + 256] : -1e30f;
  float v2 = tid + 512 < 527 ? r[tid + 512] : -1e30f;
  float mx = block_max(fmaxf(v0, fmaxf(v1, v2)), red, tid);
  float e0 = __expf(v0 - mx);
  float e1 = tid + 256 < 527 ? __expf(v1 - mx) : 0.f;
  float e2 = tid + 512 < 527 ? __expf(v2 - mx) : 0.f;
  float sm = block_sum(e0 + e1 + e2, red, tid);
  float inv = 1.f / sm;
  out[(long)b * 527 + tid] = e0 * inv;
  if (tid + 256 < 527) out[(long)b * 527 + tid + 256] = e1 * inv;
  if (tid + 512 < 527) out[(long)b * 527 + tid + 512] = e2 * inv;
}

// ---------------- launcher ----------------
extern "C" void kernel_launch(void* const* d_in, const int* in_sizes, int n_in,
                              void* d_out, int out_size, void* d_ws, size_t ws_size,
                              hipStream_t stream) {
  const float* x_in    = (const float*)d_in[0];
  const float* conv1_w = (const float*)d_in[1];
  const float* conv1_b = (const float*)d_in[2];
  const float* conv2_w = (const float*)d_in[3];
  const float* conv2_b = (const float*)d_in[4];
  const float* pos_emb = (const float*)d_in[5];
  const float* ln1_g   = (const float*)d_in[6];
  const float* ln1_b   = (const float*)d_in[7];
  const float* wq      = (const float*)d_in[8];
  const float* bq      = (const float*)d_in[9];
  const float* wk      = (const float*)d_in[10];
  const float* bk      = (const float*)d_in[11];
  const float* wv      = (const float*)d_in[12];
  const float* bv      = (const float*)d_in[13];
  const float* wo      = (const float*)d_in[14];
  const float* bo      = (const float*)d_in[15];
  const float* w1      = (const float*)d_in[16];
  const float* b1      = (const float*)d_in[17];
  const float* w2      = (const float*)d_in[18];
  const float* b2      = (const float*)d_in[19];
  const float* ln2_g   = (const float*)d_in[20];
  const float* ln2_b   = (const float*)d_in[21];
  const float* lnp_g   = (const float*)d_in[22];
  const float* lnp_b   = (const float*)d_in[23];
  const float* hln_g   = (const float*)d_in[24];
  const float* hln_b   = (const float*)d_in[25];
  const float* hw1     = (const float*)d_in[26];
  const float* hb1     = (const float*)d_in[27];
  const float* hw2     = (const float*)d_in[28];
  const float* hb2     = (const float*)d_in[29];

  // workspace layout
  char* w = (char*)d_ws;
  bf16*  wqkvT = (bf16*)(w);                      // 6*2304*768 bf16
  bf16*  woT   = (bf16*)(w + 21233664);           // 6*768*768
  bf16*  w1T   = (bf16*)(w + 28311552);           // 6*3072*768
  bf16*  w2T   = (bf16*)(w + 56623104);           // 6*768*3072
  bf16*  wc1T  = (bf16*)(w + 84934656);           // 768*256
  bf16*  wc2T  = (bf16*)(w + 85327872);           // 768*2304
  float* bqkv  = (float*)(w + 88866816);          // 6*2304 f32
  float* Xf    = (float*)(w + 88922112);          // 4096*768 f32
  bf16*  Xb    = (bf16*)(w + 101505024);          // 4096*768
  bf16*  qkv   = (bf16*)(w + 107796480);          // 3*4096*768 (q t-major, k t-major, v d-major)
  bf16*  CC    = (bf16*)(w + 126670848);          // 4096*768
  float* ATTN  = (float*)(w + 132962304);         // 4096*768 f32
  char*  BIG   = w + 145545216;                   // 50,331,648 shared region
  bf16*  A1  = (bf16*)(BIG);                      // 8192*256   (conv phase)
  bf16*  Y1G = (bf16*)(BIG + 4194304);            // 8192*768   (conv phase)
  bf16*  A2  = (bf16*)(BIG + 16777216);           // 4096*2304  (conv phase)
  bf16*  Hh  = (bf16*)(BIG);                      // 4096*3072  (ffn phase)
  float* FFN = (float*)(BIG + 25165824);          // 4096*768 f32 (ffn phase)
  // head phase (aliases, used only after last FFN)
  float* CLS  = (float*)(BIG);                    // 4*768
  float* HID  = (float*)(BIG + 16384);            // 4*3072
  float* LGT  = (float*)(BIG + 81920);            // 4*640
  float* PT1  = (float*)(BIG + 131072);           // 16*4*3072
  float* PT2  = (float*)(BIG + 1048576);          // 32*4*640
  float* HB2P = (float*)(BIG + 1572864);          // 640
  float* HW2P = (float*)(BIG + 1605632);          // 3072*640

  // ---- weight prep ----
  tconv<<<dim3(2, 24, 72), 256, 0, stream>>>(wq, wqkvT,            768, 64,   49152L, 1769472L, 49152L, 12);
  tconv<<<dim3(2, 24, 72), 256, 0, stream>>>(wk, wqkvT + 589824,   768, 64,   49152L, 1769472L, 49152L, 12);
  tconv<<<dim3(2, 24, 72), 256, 0, stream>>>(wv, wqkvT + 1179648,  768, 64,   49152L, 1769472L, 49152L, 12);
  tconv<<<dim3(24, 24, 6), 256, 0, stream>>>(wo, woT,              768, 768,  589824L, 589824L, 0L, 1);
  tconv<<<dim3(96, 24, 6), 256, 0, stream>>>(w1, w1T,              768, 3072, 2359296L, 2359296L, 0L, 1);
  tconv<<<dim3(24, 96, 6), 256, 0, stream>>>(w2, w2T,              3072, 768, 2359296L, 2359296L, 0L, 1);
  prep_cw<<<768,  256, 0, stream>>>(conv1_w, wc1T, 80, 256);
  prep_cw<<<6912, 256, 0, stream>>>(conv2_w, wc2T, 768, 2304);
  prep_bias<<<54, 256, 0, stream>>>(bq, bk, bv, bqkv);

  // ---- convs ----
  im2col1<<<8192, 256, 0, stream>>>(x_in, A1);
  { GP p{}; p.A = A1; p.B = wc1T; p.bias = conv1_b; p.Ob = Y1G;
    p.M = 8192; p.N = 768; p.K = 256;
    gemm_bt<128,64,2,2,EPI_GELU_BF16><<<dim3(64,12,1),256,0,stream>>>(p); }
  im2col2<<<36864, 256, 0, stream>>>(Y1G, A2);
  { GP p{}; p.A = A2; p.B = wc2T; p.bias = conv2_b; p.Of = Xf; p.Ob = Xb; p.aux = pos_emb;
    p.M = 4096; p.N = 768; p.K = 2304;
    gemm_bt<128,64,2,2,EPI_CONV2><<<dim3(32,12,1),256,0,stream>>>(p); }

  // ---- transformer layers ----
  for (int l = 0; l < 6; ++l) {
    { GP p{}; p.A = Xb; p.B = wqkvT + (long)l * 1769472; p.bias = bqkv + l * 2304;
      p.Ob = qkv; p.M = 4096; p.N = 2304; p.K = 768;
      gemm_bt<128,128,2,2,EPI_QKV><<<dim3(32,18,1),256,0,stream>>>(p); }
    attn_flash<<<384, 256, 0, stream>>>(qkv, CC);
    { GP p{}; p.A = CC; p.B = woT + (long)l * 589824; p.bias = bo + l * 768; p.Of = ATTN;
      p.M = 4096; p.N = 768; p.K = 768;
      gemm_bt<128,64,2,2,EPI_BIAS_F32><<<dim3(32,12,1),256,0,stream>>>(p); }
    ln_resid<<<4096, 256, 0, stream>>>(Xf, ATTN, ln1_g + l * 768, ln1_b + l * 768, Xf, Xb);
    { GP p{}; p.A = Xb; p.B = w1T + (long)l * 2359296; p.bias = b1 + l * 3072; p.Ob = Hh;
      p.M = 4096; p.N = 3072; p.K = 768;
      gemm_bt<128,128,2,2,EPI_RELU_BF16><<<dim3(32,24,1),256,0,stream>>>(p); }
    { GP p{}; p.A = Hh; p.B = w2T + (long)l * 2359296; p.bias = b2 + l * 768; p.Of = FFN;
      p.M = 4096; p.N = 768; p.K = 3072;
      gemm_bt<128,64,2,2,EPI_BIAS_F32><<<dim3(32,12,1),256,0,stream>>>(p); }
    ln_resid<<<4096, 256, 0, stream>>>(Xf, FFN, ln2_g + l * 768, ln2_b + l * 768, Xf, Xb);
  }

  // ---- head ----
  head_cls<<<4, 256, 0, stream>>>(Xf, lnp_g, lnp_b, hln_g, hln_b, CLS);
  prep_hw2<<<7680, 256, 0, stream>>>(hw2, hb2, HW2P, HB2P);
  mlp_part<<<dim3(24, 16), 256, 0, stream>>>(CLS, hw1, PT1, 768, 3072, 48);
  mlp_reduce<<<48, 256, 0, stream>>>(PT1, hb1, HID, 3072, 16, 1);
  mlp_part<<<dim3(5, 32), 256, 0, stream>>>(HID, HW2P, PT2, 3072, 640, 96);
  mlp_reduce<<<10, 256, 0, stream>>>(PT2, HB2P, LGT, 640, 32, 0);
  head_softmax<<<4, 256, 0, stream>>>(LGT, (float*)d_out);
}

// Round 12
// 1401.777 us; speedup vs baseline: 2.0374x; 1.0659x over previous
//
#include <hip/hip_runtime.h>
#include <hip/hip_bf16.h>

typedef __hip_bfloat16 bf16;
using v8s   = __attribute__((ext_vector_type(8))) short;
using f32x4 = __attribute__((ext_vector_type(4))) float;

#define DI __device__ __forceinline__

DI float gelu_f(float x) { return 0.5f * x * (1.f + erff(x * 0.70710678118654752f)); }

DI void g2lds16(const bf16* g, bf16* l) {
  __builtin_amdgcn_global_load_lds((const __attribute__((address_space(1))) void*)g,
                                   (__attribute__((address_space(3))) void*)l, 16, 0, 0);
}

// ---------------- block reduction helpers (256 threads, 4 waves) ----------------
DI float block_sum(float v, float* red, int tid) {
#pragma unroll
  for (int o = 32; o > 0; o >>= 1) v += __shfl_down(v, o);
  __syncthreads();
  if ((tid & 63) == 0) red[tid >> 6] = v;
  __syncthreads();
  return red[0] + red[1] + red[2] + red[3];
}
DI float block_max(float v, float* red, int tid) {
#pragma unroll
  for (int o = 32; o > 0; o >>= 1) v = fmaxf(v, __shfl_down(v, o));
  __syncthreads();
  if ((tid & 63) == 0) red[tid >> 6] = v;
  __syncthreads();
  return fmaxf(fmaxf(red[0], red[1]), fmaxf(red[2], red[3]));
}

// ---------------- weight prep ----------------
__global__ __launch_bounds__(256)
void tconv(const float* __restrict__ in, bf16* __restrict__ out,
           int R, int C, long inStrideZ, long outStrideL, long outStrideH, int zmod) {
  __shared__ float tile[32][33];
  int z = blockIdx.z;
  int lz = z / zmod, hz = z - lz * zmod;
  in  += (long)z * inStrideZ;
  out += (long)lz * outStrideL + (long)hz * outStrideH;
  int cb = blockIdx.x * 32, rb = blockIdx.y * 32;
  int tx = threadIdx.x & 31, ty = threadIdx.x >> 5;  // 32x8
#pragma unroll
  for (int i = 0; i < 32; i += 8)
    tile[ty + i][tx] = in[(long)(rb + ty + i) * C + cb + tx];
  __syncthreads();
#pragma unroll
  for (int i = 0; i < 32; i += 8)
    out[(long)(cb + ty + i) * R + rb + tx] = __float2bfloat16(tile[tx][ty + i]);
}

__global__ __launch_bounds__(256)
void prep_cw(const float* __restrict__ wsrc, bf16* __restrict__ o, int IC, int KT) {
  int idx = blockIdx.x * 256 + threadIdx.x;
  int oc = idx / KT, kp = idx - oc * KT;
  float v = 0.f;
  if (kp < IC * 3) {
    int kk = kp / IC, ic = kp - kk * IC;
    v = wsrc[(oc * IC + ic) * 3 + kk];
  }
  o[idx] = __float2bfloat16(v);
}

__global__ __launch_bounds__(256)
void prep_bias(const float* __restrict__ bq, const float* __restrict__ bk,
               const float* __restrict__ bv, float* __restrict__ o) {
  int idx = blockIdx.x * 256 + threadIdx.x;  // 6*2304
  int l = idx / 2304, n = idx - l * 2304;
  int which = n / 768, r = n - which * 768;
  const float* src = which == 0 ? bq : (which == 1 ? bk : bv);
  o[idx] = src[l * 768 + r];
}

// pad-repack head layer-2 weights: hw2 [3072][527] -> hw2p [3072][640] (zero pad)
__global__ __launch_bounds__(256)
void prep_hw2(const float* __restrict__ hw2, const float* __restrict__ hb2,
              float* __restrict__ hw2p, float* __restrict__ hb2p) {
  int idx = blockIdx.x * 256 + threadIdx.x;  // 3072*640
  int e = idx / 640, c = idx - e * 640;
  hw2p[idx] = c < 527 ? hw2[(long)e * 527 + c] : 0.f;
  if (idx < 640) hb2p[idx] = idx < 527 ? hb2[idx] : 0.f;
}

// ---------------- im2col ----------------
__global__ __launch_bounds__(256)
void im2col1(const float* __restrict__ x, bf16* __restrict__ out) {
  int idx = blockIdx.x * 256 + threadIdx.x;  // 8192*256
  int m = idx >> 8, kp = idx & 255;
  float v = 0.f;
  if (kp < 240) {
    int kk = kp / 80, ic = kp - kk * 80;
    int t = (m & 2047) + kk - 1;
    int b = m >> 11;
    if ((unsigned)t < 2048u) v = x[((long)(b * 80 + ic) << 11) + t];
  }
  out[idx] = __float2bfloat16(v);
}

__global__ __launch_bounds__(256)
void im2col2(const bf16* __restrict__ y, bf16* __restrict__ out) {
  int idx = blockIdx.x * 256 + threadIdx.x;  // 4096*2304
  int m = idx / 2304, kp = idx - m * 2304;
  int kk = kp / 768, ic = kp - kk * 768;
  int t = 2 * (m & 1023) + kk - 1;
  bf16 v = __float2bfloat16(0.f);
  if ((unsigned)t < 2048u) v = y[((long)(m >> 10) * 2048 + t) * 768 + ic];
  out[idx] = v;
}

// ---------------- GEMM: C[m][n] = sum_k A[m][k]*B[n][k]  (both bf16, K%64==0) ----------------
// 2-phase double-buffered K-loop, 4 waves, rule-21 XOR swizzle (conflicts = 0,
// verified round 11: SQ_LDS_BANK_CONFLICT 5.3M -> 0).
enum { EPI_GELU_BF16, EPI_CONV2, EPI_QKV, EPI_BIAS_F32, EPI_RELU_BF16 };

struct GP {
  const bf16* A; const bf16* B; const float* bias;
  bf16* Ob; float* Of; const float* aux;
  int M, N, K; long sA, sB, sC; int zoff;
};

template<int BM, int BN, int WM, int WN, int EPI>
__global__ __launch_bounds__(WM * WN * 64, 2)
void gemm_bt(GP p) {
  constexpr int WAVES = WM * WN;
  constexpr int FM = BM / WM / 16, FN = BN / WN / 16;
  __shared__ __align__(16) bf16 As0[BM * 64], Bs0[BN * 64];
  __shared__ __align__(16) bf16 As1[BM * 64], Bs1[BN * 64];
  const int tid = threadIdx.x;
  const int lane = tid & 63, wid = tid >> 6;
  const int wr = wid / WN, wc = wid - wr * WN;
  const int row0 = wr * (BM / WM), col0 = wc * (BN / WN);
  const int lr = lane & 15, lk = (lane >> 4) * 8;
  const int lrow = lane >> 3;
  const int scol = (((lane & 7) ^ (lane >> 3)) & 7) * 8;  // pre-swizzled source col
  const int rswz = (lr & 7) * 8;                          // read-side XOR
  const int z = blockIdx.z;
  const bf16* Ab = p.A + (long)z * p.sA + (long)blockIdx.x * BM * p.K;
  const bf16* Bb = p.B + (long)z * p.sB + (long)blockIdx.y * BN * p.K;
  f32x4 acc[FM][FN] = {};

  auto stage = [&](bf16* As, bf16* Bs, int kt) {
#pragma unroll
    for (int i = 0; i < BM / 8 / WAVES; ++i) {
      const int c = wid + i * WAVES;  // chunk of 8 rows (1KB)
      g2lds16(&Ab[(long)(c * 8 + lrow) * p.K + kt + scol], &As[c << 9]);
    }
#pragma unroll
    for (int i = 0; i < BN / 8 / WAVES; ++i) {
      const int c = wid + i * WAVES;
      g2lds16(&Bb[(long)(c * 8 + lrow) * p.K + kt + scol], &Bs[c << 9]);
    }
  };

  auto compute = [&](const bf16* As, const bf16* Bs) {
#pragma unroll
    for (int ks = 0; ks < 2; ++ks) {
      v8s af[FM], bf_[FN];
#pragma unroll
      for (int mi = 0; mi < FM; ++mi)
        af[mi] = *(const v8s*)&As[(row0 + mi * 16 + lr) * 64 + ((ks * 32 + lk) ^ rswz)];
#pragma unroll
      for (int ni = 0; ni < FN; ++ni)
        bf_[ni] = *(const v8s*)&Bs[(col0 + ni * 16 + lr) * 64 + ((ks * 32 + lk) ^ rswz)];
      __builtin_amdgcn_s_setprio(1);
#pragma unroll
      for (int mi = 0; mi < FM; ++mi)
#pragma unroll
        for (int ni = 0; ni < FN; ++ni)
          acc[mi][ni] = __builtin_amdgcn_mfma_f32_16x16x32_bf16(af[mi], bf_[ni], acc[mi][ni], 0, 0, 0);
      __builtin_amdgcn_s_setprio(0);
    }
  };

  stage(As0, Bs0, 0);
  __syncthreads();
  int kt = 0;
  while (true) {
    if (kt + 64 < p.K) stage(As1, Bs1, kt + 64);
    compute(As0, Bs0);
    __syncthreads();
    kt += 64;
    if (kt >= p.K) break;
    if (kt + 64 < p.K) stage(As0, Bs0, kt + 64);
    compute(As1, Bs1);
    __syncthreads();
    kt += 64;
    if (kt >= p.K) break;
  }

  // epilogue; D: row=(lane>>4)*4+r, col=lane&15
#pragma unroll
  for (int mi = 0; mi < FM; ++mi) {
#pragma unroll
    for (int ni = 0; ni < FN; ++ni) {
#pragma unroll
      for (int r = 0; r < 4; ++r) {
        float v = acc[mi][ni][r];
        const int m = blockIdx.x * BM + row0 + mi * 16 + (lane >> 4) * 4 + r;
        const int n = blockIdx.y * BN + col0 + ni * 16 + lr;
        if constexpr (EPI == EPI_GELU_BF16) {
          p.Ob[(long)m * p.N + n] = __float2bfloat16(gelu_f(v + p.bias[n]));
        } else if constexpr (EPI == EPI_CONV2) {
          float t = gelu_f(v + p.bias[n]) + p.aux[(long)(m & 1023) * 768 + n];
          p.Of[(long)m * 768 + n] = t;
          p.Ob[(long)m * 768 + n] = __float2bfloat16(t);
        } else if constexpr (EPI == EPI_QKV) {
          float t = v + p.bias[n];
          int which = n / 768, nn = n - which * 768;
          int h = nn >> 6, d = nn & 63;
          long bh = (long)(m >> 10) * 12 + h;
          if (which < 2)
            p.Ob[(long)which * 3145728 + (bh << 16) + ((long)(m & 1023) << 6) + d] = __float2bfloat16(t);
          else
            p.Ob[6291456L + (bh << 16) + ((long)d << 10) + (m & 1023)] = __float2bfloat16(t);
        } else if constexpr (EPI == EPI_BIAS_F32) {
          p.Of[(long)m * p.N + n] = v + p.bias[n];
        } else if constexpr (EPI == EPI_RELU_BF16) {
          p.Ob[(long)m * p.N + n] = __float2bfloat16(fmaxf(v + p.bias[n], 0.f));
        }
      }
    }
  }
}

// ---------------- fused flash attention ----------------
// 1D grid of 384: qt = blk/48, bh = blk%48 (XCD-aligned). 4 waves x 32 q-rows.
// K/V dbuf in LDS, XOR-swizzled. Softmax denominator accumulated via an extra
// ones-B MFMA in the PV phase (lacc = P @ ones, rescaled like acc) -- deletes
// the 32-shfl sum tree per iteration; only the max tree remains cross-lane.
__global__ __launch_bounds__(256)
void attn_flash(const bf16* __restrict__ qkv, bf16* __restrict__ cc) {
  __shared__ __align__(16) bf16 Ks[2][64 * 64], Vs[2][64 * 64];
  __shared__ __align__(16) bf16 Pl[4][32 * 76];
  const int tid = threadIdx.x, lane = tid & 63, wid = tid >> 6;
  const int lr = lane & 15, lg = lane >> 4;
  const int blk = blockIdx.x;
  const int qt = blk / 48, bh = blk - qt * 48;
  const int b = bh / 12, h = bh - b * 12;
  const long qb = (long)bh << 16;
  const bf16* Qg = qkv + qb;
  const bf16* Kg = qkv + 3145728 + qb;
  const bf16* Vg = qkv + 6291456 + qb;
  const int q0 = qt * 128 + wid * 32;
  const int lrow8 = lane >> 3;
  const int scol = (((lane & 7) ^ (lane >> 3)) & 7) * 8;  // pre-swizzled source col
  const int rswz = (lr & 7) * 8;                          // read-side XOR

  v8s aq[2][2];
#pragma unroll
  for (int mi = 0; mi < 2; ++mi)
#pragma unroll
    for (int ks = 0; ks < 2; ++ks)
      aq[mi][ks] = *(const v8s*)&Qg[(long)(q0 + mi * 16 + lr) * 64 + ks * 32 + lg * 8];

  const short oneb = (short)0x3F80;  // bf16 1.0
  const v8s ones = {oneb, oneb, oneb, oneb, oneb, oneb, oneb, oneb};

  float mrow[2][4];
  f32x4 acc[2][4] = {};
  f32x4 lacc[2] = {};
#pragma unroll
  for (int mi = 0; mi < 2; ++mi)
#pragma unroll
    for (int r = 0; r < 4; ++r) mrow[mi][r] = -1e30f;
  bf16* myP = &Pl[wid][0];

  auto stageKV = [&](int buf, int kt) {
#pragma unroll
    for (int i = 0; i < 2; ++i) {
      int c = wid + i * 4;
      g2lds16(&Kg[(long)(kt + c * 8 + lrow8) * 64 + scol], &Ks[buf][c << 9]);
      g2lds16(&Vg[((long)(c * 8 + lrow8) << 10) + kt + scol], &Vs[buf][c << 9]);
    }
  };

  stageKV(0, 0);
  __syncthreads();  // buf0 staged (vmcnt drained at barrier)

  for (int it = 0; it < 16; ++it) {
    const int cur = it & 1;
    if (it + 1 < 16) stageKV(cur ^ 1, (it + 1) * 64);
    const bf16* Kc = &Ks[cur][0];
    const bf16* Vc = &Vs[cur][0];

    // S = Q K^T
    f32x4 s[2][4] = {};
#pragma unroll
    for (int ks = 0; ks < 2; ++ks) {
      v8s bk[4];
#pragma unroll
      for (int ni = 0; ni < 4; ++ni)
        bk[ni] = *(const v8s*)&Kc[(ni * 16 + lr) * 64 + ((ks * 32 + lg * 8) ^ rswz)];
      __builtin_amdgcn_s_setprio(1);
#pragma unroll
      for (int mi = 0; mi < 2; ++mi)
#pragma unroll
        for (int ni = 0; ni < 4; ++ni)
          s[mi][ni] = __builtin_amdgcn_mfma_f32_16x16x32_bf16(aq[mi][ks], bk[ni], s[mi][ni], 0, 0, 0);
      __builtin_amdgcn_s_setprio(0);
    }

    // online softmax; write P (bf16) to per-wave LDS; rescale acc+lacc
#pragma unroll
    for (int mi = 0; mi < 2; ++mi) {
#pragma unroll
      for (int r = 0; r < 4; ++r) {
        float tm = fmaxf(fmaxf(s[mi][0][r], s[mi][1][r]), fmaxf(s[mi][2][r], s[mi][3][r]));
#pragma unroll
        for (int o = 1; o < 16; o <<= 1) tm = fmaxf(tm, __shfl_xor(tm, o));
        float mn = fmaxf(mrow[mi][r], tm);
        float al = __expf(mrow[mi][r] - mn);
        mrow[mi][r] = mn;
        const int prow = (mi * 16 + lg * 4 + r) * 76;
#pragma unroll
        for (int ni = 0; ni < 4; ++ni)
          myP[prow + ni * 16 + lr] = __float2bfloat16(__expf(s[mi][ni][r] - mn));
        lacc[mi][r] *= al;
#pragma unroll
        for (int ni = 0; ni < 4; ++ni) acc[mi][ni][r] *= al;
      }
    }

    // O += P * V ; l += P * ones  (V d-major -> contiguous B-frags)
#pragma unroll
    for (int ks = 0; ks < 2; ++ks) {
      v8s pa[2], bv[4];
#pragma unroll
      for (int mi = 0; mi < 2; ++mi)
        pa[mi] = *(const v8s*)&myP[(mi * 16 + lr) * 76 + ks * 32 + lg * 8];
#pragma unroll
      for (int ni = 0; ni < 4; ++ni)
        bv[ni] = *(const v8s*)&Vc[(ni * 16 + lr) * 64 + ((ks * 32 + lg * 8) ^ rswz)];
      __builtin_amdgcn_s_setprio(1);
#pragma unroll
      for (int mi = 0; mi < 2; ++mi) {
#pragma unroll
        for (int ni = 0; ni < 4; ++ni)
          acc[mi][ni] = __builtin_amdgcn_mfma_f32_16x16x32_bf16(pa[mi], bv[ni], acc[mi][ni], 0, 0, 0);
        lacc[mi] = __builtin_amdgcn_mfma_f32_16x16x32_bf16(pa[mi], ones, lacc[mi], 0, 0, 0);
      }
      __builtin_amdgcn_s_setprio(0);
    }
    __syncthreads();  // all waves done with cur; next buffer fully staged
  }

  // epilogue: normalize and write concat layout [b*1024+t][h*64+d]
#pragma unroll
  for (int mi = 0; mi < 2; ++mi)
#pragma unroll
    for (int ni = 0; ni < 4; ++ni)
#pragma unroll
      for (int r = 0; r < 4; ++r) {
        int row = q0 + mi * 16 + lg * 4 + r;
        cc[((long)(b << 10) + row) * 768 + h * 64 + ni * 16 + lr] =
            __float2bfloat16(acc[mi][ni][r] / lacc[mi][r]);
      }
}

// ---------------- residual + LayerNorm (row=768), float4-vectorized ----------------
__global__ __launch_bounds__(256)
void ln_resid(const float* __restrict__ xin, const float* __restrict__ add,
              const float* __restrict__ g, const float* __restrict__ bb,
              float* __restrict__ xo, bf16* __restrict__ xbo) {
  __shared__ float red[4];
  long row = blockIdx.x;
  int tid = threadIdx.x;
  const f32x4* xr = (const f32x4*)(xin + row * 768);
  const f32x4* ar = (const f32x4*)(add + row * 768);
  f32x4 v = {0.f, 0.f, 0.f, 0.f};
  if (tid < 192) {
    f32x4 a = xr[tid], c = ar[tid];
    v[0] = a[0] + c[0]; v[1] = a[1] + c[1]; v[2] = a[2] + c[2]; v[3] = a[3] + c[3];
  }
  float mean = block_sum(v[0] + v[1] + v[2] + v[3], red, tid) * (1.f / 768.f);
  if (tid < 192) { v[0] -= mean; v[1] -= mean; v[2] -= mean; v[3] -= mean; }
  float sq = tid < 192 ? v[0] * v[0] + v[1] * v[1] + v[2] * v[2] + v[3] * v[3] : 0.f;
  float var = block_sum(sq, red, tid) * (1.f / 768.f);
  float rs = rsqrtf(var + 1e-5f);
  if (tid < 192) {
    f32x4 gv = ((const f32x4*)g)[tid];
    f32x4 bv = ((const f32x4*)bb)[tid];
    f32x4 o;
    o[0] = v[0] * rs * gv[0] + bv[0];
    o[1] = v[1] * rs * gv[1] + bv[1];
    o[2] = v[2] * rs * gv[2] + bv[2];
    o[3] = v[3] * rs * gv[3] + bv[3];
    ((f32x4*)(xo + row * 768))[tid] = o;
    bf16 t0 = __float2bfloat16(o[0]), t1 = __float2bfloat16(o[1]);
    bf16 t2 = __float2bfloat16(o[2]), t3 = __float2bfloat16(o[3]);
    ushort4 pk;
    pk.x = *(unsigned short*)&t0; pk.y = *(unsigned short*)&t1;
    pk.z = *(unsigned short*)&t2; pk.w = *(unsigned short*)&t3;
    *(ushort4*)&xbo[row * 768 + tid * 4] = pk;
  }
}

// ---------------- classifier head ----------------
__global__ __launch_bounds__(256)
void head_cls(const float* __restrict__ x,
              const float* __restrict__ lnpg, const float* __restrict__ lnpb,
              const float* __restrict__ hlng, const float* __restrict__ hlnb,
              float* __restrict__ cls) {
  __shared__ float red[4];
  int b = blockIdx.x, tid = threadIdx.x;
  const float* xr = x + (long)b * 1024 * 768;  // row t=0
  float v0 = xr[tid], v1 = xr[tid + 256], v2 = xr[tid + 512];
  float s = block_sum(v0 + v1 + v2, red, tid) * (1.f / 768.f);
  v0 -= s; v1 -= s; v2 -= s;
  float q = block_sum(v0 * v0 + v1 * v1 + v2 * v2, red, tid) * (1.f / 768.f);
  float r = rsqrtf(q + 1e-5f);
  v0 = v0 * r * lnpg[tid]       + lnpb[tid];
  v1 = v1 * r * lnpg[tid + 256] + lnpb[tid + 256];
  v2 = v2 * r * lnpg[tid + 512] + lnpb[tid + 512];
  s = block_sum(v0 + v1 + v2, red, tid) * (1.f / 768.f);
  v0 -= s; v1 -= s; v2 -= s;
  q = block_sum(v0 * v0 + v1 * v1 + v2 * v2, red, tid) * (1.f / 768.f);
  r = rsqrtf(q + 1e-5f);
  cls[b * 768 + tid]       = v0 * r * hlng[tid]       + hlnb[tid];
  cls[b * 768 + tid + 256] = v1 * r * hlng[tid + 256] + hlnb[tid + 256];
  cls[b * 768 + tid + 512] = v2 * r * hlng[tid + 512] + hlnb[tid + 512];
}

// split-K GEMV stage A
__global__ __launch_bounds__(256)
void mlp_part(const float* __restrict__ in, const float* __restrict__ wmat,
              float* __restrict__ part, int IN, int OUTP, int ET) {
  __shared__ float cin[4][96];
  __shared__ float red[8][32][16];
  int tid = threadIdx.x;
  int tx = tid & 31, ty = tid >> 5;
  int e0 = blockIdx.y * ET;
  for (int i = tid; i < 4 * ET; i += 256) {
    int b = i / ET, el = i - b * ET;
    cin[b][el] = in[b * IN + e0 + el];
  }
  __syncthreads();
  f32x4 acc[4] = {};
  const float* wp = wmat + (long)e0 * OUTP + (blockIdx.x * 32 + tx) * 4;
  const int iters = ET >> 3;
  for (int i = 0; i < iters; ++i) {
    int el = ty + i * 8;
    f32x4 w = *(const f32x4*)(wp + (long)el * OUTP);
#pragma unroll
    for (int b = 0; b < 4; ++b) acc[b] += cin[b][el] * w;
  }
#pragma unroll
  for (int b = 0; b < 4; ++b) *(f32x4*)&red[ty][tx][b * 4] = acc[b];
  __syncthreads();
  if (tid < 128) {
    int rx = tid & 31, b = tid >> 5;
    f32x4 s = {};
#pragma unroll
    for (int t = 0; t < 8; ++t) s += *(const f32x4*)&red[t][rx][b * 4];
    *(f32x4*)&part[((long)blockIdx.y * 4 + b) * OUTP + (blockIdx.x * 32 + rx) * 4] = s;
  }
}

__global__ __launch_bounds__(256)
void mlp_reduce(const float* __restrict__ part, const float* __restrict__ bias,
                float* __restrict__ out, int OUTP, int S, int relu) {
  int idx = blockIdx.x * 256 + threadIdx.x;
  int b = idx / OUTP, j = idx - b * OUTP;
  float s = bias[j];
  for (int t = 0; t < S; ++t) s += part[((long)t * 4 + b) * OUTP + j];
  out[idx] = relu ? fmaxf(s, 0.f) : s;
}

// C=527 logits in [4][640] padded rows
__global__ __launch_bounds__(256)
void head_softmax(const float* __restrict__ lg, float* __restrict__ out) {
  __shared__ float red[4];
  int b = blockIdx.x, tid = threadIdx.x;
  const float* r = lg + (long)b * 640;
  float v0 = r[tid];
  float v1 = tid + 256 < 527 ? r[tid + 256] : -1e30f;
  float v2 = tid + 512 < 527 ? r[tid + 512] : -1e30f;
  float mx = block_max(fmaxf(v0, fmaxf(v1, v2)), red, tid);
  float e0 = __expf(v0 - mx);
  float e1 = tid + 256 < 527 ? __expf(v1 - mx) : 0.f;
  float e2 = tid + 512 < 527 ? __expf(v2 - mx) : 0.f;
  float sm = block_sum(e0 + e1 + e2, red, tid);
  float inv = 1.f / sm;
  out[(long)b * 527 + tid] = e0 * inv;
  if (tid + 256 < 527) out[(long)b * 527 + tid + 256] = e1 * inv;
  if (tid + 512 < 527) out[(long)b * 527 + tid + 512] = e2 * inv;
}

// ---------------- launcher ----------------
extern "C" void kernel_launch(void* const* d_in, const int* in_sizes, int n_in,
                              void* d_out, int out_size, void* d_ws, size_t ws_size,
                              hipStream_t stream) {
  const float* x_in    = (const float*)d_in[0];
  const float* conv1_w = (const float*)d_in[1];
  const float* conv1_b = (const float*)d_in[2];
  const float* conv2_w = (const float*)d_in[3];
  const float* conv2_b = (const float*)d_in[4];
  const float* pos_emb = (const float*)d_in[5];
  const float* ln1_g   = (const float*)d_in[6];
  const float* ln1_b   = (const float*)d_in[7];
  const float* wq      = (const float*)d_in[8];
  const float* bq      = (const float*)d_in[9];
  const float* wk      = (const float*)d_in[10];
  const float* bk      = (const float*)d_in[11];
  const float* wv      = (const float*)d_in[12];
  const float* bv      = (const float*)d_in[13];
  const float* wo      = (const float*)d_in[14];
  const float* bo      = (const float*)d_in[15];
  const float* w1      = (const float*)d_in[16];
  const float* b1      = (const float*)d_in[17];
  const float* w2      = (const float*)d_in[18];
  const float* b2      = (const float*)d_in[19];
  const float* ln2_g   = (const float*)d_in[20];
  const float* ln2_b   = (const float*)d_in[21];
  const float* lnp_g   = (const float*)d_in[22];
  const float* lnp_b   = (const float*)d_in[23];
  const float* hln_g   = (const float*)d_in[24];
  const float* hln_b   = (const float*)d_in[25];
  const float* hw1     = (const float*)d_in[26];
  const float* hb1     = (const float*)d_in[27];
  const float* hw2     = (const float*)d_in[28];
  const float* hb2     = (const float*)d_in[29];

  // workspace layout
  char* w = (char*)d_ws;
  bf16*  wqkvT = (bf16*)(w);                      // 6*2304*768 bf16
  bf16*  woT   = (bf16*)(w + 21233664);           // 6*768*768
  bf16*  w1T   = (bf16*)(w + 28311552);           // 6*3072*768
  bf16*  w2T   = (bf16*)(w + 56623104);           // 6*768*3072
  bf16*  wc1T  = (bf16*)(w + 84934656);           // 768*256
  bf16*  wc2T  = (bf16*)(w + 85327872);           // 768*2304
  float* bqkv  = (float*)(w + 88866816);          // 6*2304 f32
  float* Xf    = (float*)(w + 88922112);          // 4096*768 f32
  bf16*  Xb    = (bf16*)(w + 101505024);          // 4096*768
  bf16*  qkv   = (bf16*)(w + 107796480);          // 3*4096*768 (q t-major, k t-major, v d-major)
  bf16*  CC    = (bf16*)(w + 126670848);          // 4096*768
  float* ATTN  = (float*)(w + 132962304);         // 4096*768 f32
  char*  BIG   = w + 145545216;                   // 50,331,648 shared region
  bf16*  A1  = (bf16*)(BIG);                      // 8192*256   (conv phase)
  bf16*  Y1G = (bf16*)(BIG + 4194304);            // 8192*768   (conv phase)
  bf16*  A2  = (bf16*)(BIG + 16777216);           // 4096*2304  (conv phase)
  bf16*  Hh  = (bf16*)(BIG);                      // 4096*3072  (ffn phase)
  float* FFN = (float*)(BIG + 25165824);          // 4096*768 f32 (ffn phase)
  // head phase (aliases, used only after last FFN)
  float* CLS  = (float*)(BIG);                    // 4*768
  float* HID  = (float*)(BIG + 16384);            // 4*3072
  float* LGT  = (float*)(BIG + 81920);            // 4*640
  float* PT1  = (float*)(BIG + 131072);           // 16*4*3072
  float* PT2  = (float*)(BIG + 1048576);          // 32*4*640
  float* HB2P = (float*)(BIG + 1572864);          // 640
  float* HW2P = (float*)(BIG + 1605632);          // 3072*640

  // ---- weight prep ----
  tconv<<<dim3(2, 24, 72), 256, 0, stream>>>(wq, wqkvT,            768, 64,   49152L, 1769472L, 49152L, 12);
  tconv<<<dim3(2, 24, 72), 256, 0, stream>>>(wk, wqkvT + 589824,   768, 64,   49152L, 1769472L, 49152L, 12);
  tconv<<<dim3(2, 24, 72), 256, 0, stream>>>(wv, wqkvT + 1179648,  768, 64,   49152L, 1769472L, 49152L, 12);
  tconv<<<dim3(24, 24, 6), 256, 0, stream>>>(wo, woT,              768, 768,  589824L, 589824L, 0L, 1);
  tconv<<<dim3(96, 24, 6), 256, 0, stream>>>(w1, w1T,              768, 3072, 2359296L, 2359296L, 0L, 1);
  tconv<<<dim3(24, 96, 6), 256, 0, stream>>>(w2, w2T,              3072, 768, 2359296L, 2359296L, 0L, 1);
  prep_cw<<<768,  256, 0, stream>>>(conv1_w, wc1T, 80, 256);
  prep_cw<<<6912, 256, 0, stream>>>(conv2_w, wc2T, 768, 2304);
  prep_bias<<<54, 256, 0, stream>>>(bq, bk, bv, bqkv);

  // ---- convs ----
  im2col1<<<8192, 256, 0, stream>>>(x_in, A1);
  { GP p{}; p.A = A1; p.B = wc1T; p.bias = conv1_b; p.Ob = Y1G;
    p.M = 8192; p.N = 768; p.K = 256;
    gemm_bt<128,64,2,2,EPI_GELU_BF16><<<dim3(64,12,1),256,0,stream>>>(p); }
  im2col2<<<36864, 256, 0, stream>>>(Y1G, A2);
  { GP p{}; p.A = A2; p.B = wc2T; p.bias = conv2_b; p.Of = Xf; p.Ob = Xb; p.aux = pos_emb;
    p.M = 4096; p.N = 768; p.K = 2304;
    gemm_bt<128,64,2,2,EPI_CONV2><<<dim3(32,12,1),256,0,stream>>>(p); }

  // ---- transformer layers ----
  for (int l = 0; l < 6; ++l) {
    { GP p{}; p.A = Xb; p.B = wqkvT + (long)l * 1769472; p.bias = bqkv + l * 2304;
      p.Ob = qkv; p.M = 4096; p.N = 2304; p.K = 768;
      gemm_bt<128,128,2,2,EPI_QKV><<<dim3(32,18,1),256,0,stream>>>(p); }
    attn_flash<<<384, 256, 0, stream>>>(qkv, CC);
    { GP p{}; p.A = CC; p.B = woT + (long)l * 589824; p.bias = bo + l * 768; p.Of = ATTN;
      p.M = 4096; p.N = 768; p.K = 768;
      gemm_bt<128,64,2,2,EPI_BIAS_F32><<<dim3(32,12,1),256,0,stream>>>(p); }
    ln_resid<<<4096, 256, 0, stream>>>(Xf, ATTN, ln1_g + l * 768, ln1_b + l * 768, Xf, Xb);
    { GP p{}; p.A = Xb; p.B = w1T + (long)l * 2359296; p.bias = b1 + l * 3072; p.Ob = Hh;
      p.M = 4096; p.N = 3072; p.K = 768;
      gemm_bt<128,128,2,2,EPI_RELU_BF16><<<dim3(32,24,1),256,0,stream>>>(p); }
    { GP p{}; p.A = Hh; p.B = w2T + (long)l * 2359296; p.bias = b2 + l * 768; p.Of = FFN;
      p.M = 4096; p.N = 768; p.K = 3072;
      gemm_bt<128,64,2,2,EPI_BIAS_F32><<<dim3(32,12,1),256,0,stream>>>(p); }
    ln_resid<<<4096, 256, 0, stream>>>(Xf, FFN, ln2_g + l * 768, ln2_b + l * 768, Xf, Xb);
  }

  // ---- head ----
  head_cls<<<4, 256, 0, stream>>>(Xf, lnp_g, lnp_b, hln_g, hln_b, CLS);
  prep_hw2<<<7680, 256, 0, stream>>>(hw2, hb2, HW2P, HB2P);
  mlp_part<<<dim3(24, 16), 256, 0, stream>>>(CLS, hw1, PT1, 768, 3072, 48);
  mlp_reduce<<<48, 256, 0, stream>>>(PT1, hb1, HID, 3072, 16, 1);
  mlp_part<<<dim3(5, 32), 256, 0, stream>>>(HID, HW2P, PT2, 3072, 640, 96);
  mlp_reduce<<<10, 256, 0, stream>>>(PT2, HB2P, LGT, 640, 32, 0);
  head_softmax<<<4, 256, 0, stream>>>(LGT, (float*)d_out);
}

// Round 13
// 1357.321 us; speedup vs baseline: 2.1042x; 1.0328x over previous
//
#include <hip/hip_runtime.h>
#include <hip/hip_bf16.h>

typedef __hip_bfloat16 bf16;
using v8s   = __attribute__((ext_vector_type(8))) short;
using f32x4 = __attribute__((ext_vector_type(4))) float;

#define DI __device__ __forceinline__

DI float gelu_f(float x) { return 0.5f * x * (1.f + erff(x * 0.70710678118654752f)); }

DI void g2lds16(const bf16* g, bf16* l) {
  __builtin_amdgcn_global_load_lds((const __attribute__((address_space(1))) void*)g,
                                   (__attribute__((address_space(3))) void*)l, 16, 0, 0);
}

// ---------------- block reduction helpers (256 threads, 4 waves) ----------------
DI float block_sum(float v, float* red, int tid) {
#pragma unroll
  for (int o = 32; o > 0; o >>= 1) v += __shfl_down(v, o);
  __syncthreads();
  if ((tid & 63) == 0) red[tid >> 6] = v;
  __syncthreads();
  return red[0] + red[1] + red[2] + red[3];
}
DI float block_max(float v, float* red, int tid) {
#pragma unroll
  for (int o = 32; o > 0; o >>= 1) v = fmaxf(v, __shfl_down(v, o));
  __syncthreads();
  if ((tid & 63) == 0) red[tid >> 6] = v;
  __syncthreads();
  return fmaxf(fmaxf(red[0], red[1]), fmaxf(red[2], red[3]));
}

// ---------------- weight prep ----------------
__global__ __launch_bounds__(256)
void tconv(const float* __restrict__ in, bf16* __restrict__ out,
           int R, int C, long inStrideZ, long outStrideL, long outStrideH, int zmod) {
  __shared__ float tile[32][33];
  int z = blockIdx.z;
  int lz = z / zmod, hz = z - lz * zmod;
  in  += (long)z * inStrideZ;
  out += (long)lz * outStrideL + (long)hz * outStrideH;
  int cb = blockIdx.x * 32, rb = blockIdx.y * 32;
  int tx = threadIdx.x & 31, ty = threadIdx.x >> 5;  // 32x8
#pragma unroll
  for (int i = 0; i < 32; i += 8)
    tile[ty + i][tx] = in[(long)(rb + ty + i) * C + cb + tx];
  __syncthreads();
#pragma unroll
  for (int i = 0; i < 32; i += 8)
    out[(long)(cb + ty + i) * R + rb + tx] = __float2bfloat16(tile[tx][ty + i]);
}

__global__ __launch_bounds__(256)
void prep_cw(const float* __restrict__ wsrc, bf16* __restrict__ o, int IC, int KT) {
  int idx = blockIdx.x * 256 + threadIdx.x;
  int oc = idx / KT, kp = idx - oc * KT;
  float v = 0.f;
  if (kp < IC * 3) {
    int kk = kp / IC, ic = kp - kk * IC;
    v = wsrc[(oc * IC + ic) * 3 + kk];
  }
  o[idx] = __float2bfloat16(v);
}

__global__ __launch_bounds__(256)
void prep_bias(const float* __restrict__ bq, const float* __restrict__ bk,
               const float* __restrict__ bv, float* __restrict__ o) {
  int idx = blockIdx.x * 256 + threadIdx.x;  // 6*2304
  int l = idx / 2304, n = idx - l * 2304;
  int which = n / 768, r = n - which * 768;
  const float* src = which == 0 ? bq : (which == 1 ? bk : bv);
  o[idx] = src[l * 768 + r];
}

// pad-repack head layer-2 weights: hw2 [3072][527] -> hw2p [3072][640] (zero pad)
__global__ __launch_bounds__(256)
void prep_hw2(const float* __restrict__ hw2, const float* __restrict__ hb2,
              float* __restrict__ hw2p, float* __restrict__ hb2p) {
  int idx = blockIdx.x * 256 + threadIdx.x;  // 3072*640
  int e = idx / 640, c = idx - e * 640;
  hw2p[idx] = c < 527 ? hw2[(long)e * 527 + c] : 0.f;
  if (idx < 640) hb2p[idx] = idx < 527 ? hb2[idx] : 0.f;
}

// ---------------- im2col ----------------
__global__ __launch_bounds__(256)
void im2col1(const float* __restrict__ x, bf16* __restrict__ out) {
  int idx = blockIdx.x * 256 + threadIdx.x;  // 8192*256
  int m = idx >> 8, kp = idx & 255;
  float v = 0.f;
  if (kp < 240) {
    int kk = kp / 80, ic = kp - kk * 80;
    int t = (m & 2047) + kk - 1;
    int b = m >> 11;
    if ((unsigned)t < 2048u) v = x[((long)(b * 80 + ic) << 11) + t];
  }
  out[idx] = __float2bfloat16(v);
}

__global__ __launch_bounds__(256)
void im2col2(const bf16* __restrict__ y, bf16* __restrict__ out) {
  int idx = blockIdx.x * 256 + threadIdx.x;  // 4096*2304
  int m = idx / 2304, kp = idx - m * 2304;
  int kk = kp / 768, ic = kp - kk * 768;
  int t = 2 * (m & 1023) + kk - 1;
  bf16 v = __float2bfloat16(0.f);
  if ((unsigned)t < 2048u) v = y[((long)(m >> 10) * 2048 + t) * 768 + ic];
  out[idx] = v;
}

// ---------------- GEMM: C[m][n] = sum_k A[m][k]*B[n][k]  (both bf16, K%64==0) ----------------
// 2-phase double-buffered K-loop, 4 waves, rule-21 XOR swizzle (conflicts = 0,
// verified round 11: SQ_LDS_BANK_CONFLICT 5.3M -> 0).
enum { EPI_GELU_BF16, EPI_CONV2, EPI_QKV, EPI_BIAS_F32, EPI_RELU_BF16 };

struct GP {
  const bf16* A; const bf16* B; const float* bias;
  bf16* Ob; float* Of; const float* aux;
  int M, N, K; long sA, sB, sC; int zoff;
};

template<int BM, int BN, int WM, int WN, int EPI>
__global__ __launch_bounds__(WM * WN * 64, 2)
void gemm_bt(GP p) {
  constexpr int WAVES = WM * WN;
  constexpr int FM = BM / WM / 16, FN = BN / WN / 16;
  __shared__ __align__(16) bf16 As0[BM * 64], Bs0[BN * 64];
  __shared__ __align__(16) bf16 As1[BM * 64], Bs1[BN * 64];
  const int tid = threadIdx.x;
  const int lane = tid & 63, wid = tid >> 6;
  const int wr = wid / WN, wc = wid - wr * WN;
  const int row0 = wr * (BM / WM), col0 = wc * (BN / WN);
  const int lr = lane & 15, lk = (lane >> 4) * 8;
  const int lrow = lane >> 3;
  const int scol = (((lane & 7) ^ (lane >> 3)) & 7) * 8;  // pre-swizzled source col
  const int rswz = (lr & 7) * 8;                          // read-side XOR
  const int z = blockIdx.z;
  const bf16* Ab = p.A + (long)z * p.sA + (long)blockIdx.x * BM * p.K;
  const bf16* Bb = p.B + (long)z * p.sB + (long)blockIdx.y * BN * p.K;
  f32x4 acc[FM][FN] = {};

  auto stage = [&](bf16* As, bf16* Bs, int kt) {
#pragma unroll
    for (int i = 0; i < BM / 8 / WAVES; ++i) {
      const int c = wid + i * WAVES;  // chunk of 8 rows (1KB)
      g2lds16(&Ab[(long)(c * 8 + lrow) * p.K + kt + scol], &As[c << 9]);
    }
#pragma unroll
    for (int i = 0; i < BN / 8 / WAVES; ++i) {
      const int c = wid + i * WAVES;
      g2lds16(&Bb[(long)(c * 8 + lrow) * p.K + kt + scol], &Bs[c << 9]);
    }
  };

  auto compute = [&](const bf16* As, const bf16* Bs) {
#pragma unroll
    for (int ks = 0; ks < 2; ++ks) {
      v8s af[FM], bf_[FN];
#pragma unroll
      for (int mi = 0; mi < FM; ++mi)
        af[mi] = *(const v8s*)&As[(row0 + mi * 16 + lr) * 64 + ((ks * 32 + lk) ^ rswz)];
#pragma unroll
      for (int ni = 0; ni < FN; ++ni)
        bf_[ni] = *(const v8s*)&Bs[(col0 + ni * 16 + lr) * 64 + ((ks * 32 + lk) ^ rswz)];
      __builtin_amdgcn_s_setprio(1);
#pragma unroll
      for (int mi = 0; mi < FM; ++mi)
#pragma unroll
        for (int ni = 0; ni < FN; ++ni)
          acc[mi][ni] = __builtin_amdgcn_mfma_f32_16x16x32_bf16(af[mi], bf_[ni], acc[mi][ni], 0, 0, 0);
      __builtin_amdgcn_s_setprio(0);
    }
  };

  stage(As0, Bs0, 0);
  __syncthreads();
  int kt = 0;
  while (true) {
    if (kt + 64 < p.K) stage(As1, Bs1, kt + 64);
    compute(As0, Bs0);
    __syncthreads();
    kt += 64;
    if (kt >= p.K) break;
    if (kt + 64 < p.K) stage(As0, Bs0, kt + 64);
    compute(As1, Bs1);
    __syncthreads();
    kt += 64;
    if (kt >= p.K) break;
  }

  // epilogue; D: row=(lane>>4)*4+r, col=lane&15
#pragma unroll
  for (int mi = 0; mi < FM; ++mi) {
#pragma unroll
    for (int ni = 0; ni < FN; ++ni) {
#pragma unroll
      for (int r = 0; r < 4; ++r) {
        float v = acc[mi][ni][r];
        const int m = blockIdx.x * BM + row0 + mi * 16 + (lane >> 4) * 4 + r;
        const int n = blockIdx.y * BN + col0 + ni * 16 + lr;
        if constexpr (EPI == EPI_GELU_BF16) {
          p.Ob[(long)m * p.N + n] = __float2bfloat16(gelu_f(v + p.bias[n]));
        } else if constexpr (EPI == EPI_CONV2) {
          float t = gelu_f(v + p.bias[n]) + p.aux[(long)(m & 1023) * 768 + n];
          p.Of[(long)m * 768 + n] = t;
          p.Ob[(long)m * 768 + n] = __float2bfloat16(t);
        } else if constexpr (EPI == EPI_QKV) {
          float t = v + p.bias[n];
          int which = n / 768, nn = n - which * 768;
          int h = nn >> 6, d = nn & 63;
          long bh = (long)(m >> 10) * 12 + h;
          if (which < 2)
            p.Ob[(long)which * 3145728 + (bh << 16) + ((long)(m & 1023) << 6) + d] = __float2bfloat16(t);
          else
            p.Ob[6291456L + (bh << 16) + ((long)d << 10) + (m & 1023)] = __float2bfloat16(t);
        } else if constexpr (EPI == EPI_BIAS_F32) {
          p.Of[(long)m * p.N + n] = v + p.bias[n];
        } else if constexpr (EPI == EPI_RELU_BF16) {
          p.Ob[(long)m * p.N + n] = __float2bfloat16(fmaxf(v + p.bias[n], 0.f));
        }
      }
    }
  }
}

// ---------------- fused flash attention ----------------
// QBLK=64: grid 768 = exactly 3 blocks/CU (removes the 2-vs-1 block imbalance
// of grid 384). qt = blk/48, bh = blk%48 (same-head blocks spaced 48 = 0 mod 8
// -> same XCD L2). 4 waves x 16 q-rows. K/V dbuf + XOR swizzle. Denominator
// via ones-MFMA. Defer-max (THR=8): skip the acc/lacc rescale pass when no
// row's max grew past mrow+8 -- P stays bounded by e^8; numerator and
// denominator use the same P so normalization is exact.
__global__ __launch_bounds__(256)
void attn_flash(const bf16* __restrict__ qkv, bf16* __restrict__ cc) {
  __shared__ __align__(16) bf16 Ks[2][64 * 64], Vs[2][64 * 64];
  __shared__ __align__(16) bf16 Pl[4][16 * 76];
  const int tid = threadIdx.x, lane = tid & 63, wid = tid >> 6;
  const int lr = lane & 15, lg = lane >> 4;
  const int blk = blockIdx.x;
  const int qt = blk / 48, bh = blk - qt * 48;
  const int b = bh / 12, h = bh - b * 12;
  const long qb = (long)bh << 16;
  const bf16* Qg = qkv + qb;
  const bf16* Kg = qkv + 3145728 + qb;
  const bf16* Vg = qkv + 6291456 + qb;
  const int q0 = qt * 64 + wid * 16;
  const int lrow8 = lane >> 3;
  const int scol = (((lane & 7) ^ (lane >> 3)) & 7) * 8;  // pre-swizzled source col
  const int rswz = (lr & 7) * 8;                          // read-side XOR

  v8s aq[2];
#pragma unroll
  for (int ks = 0; ks < 2; ++ks)
    aq[ks] = *(const v8s*)&Qg[(long)(q0 + lr) * 64 + ks * 32 + lg * 8];

  const short oneb = (short)0x3F80;  // bf16 1.0
  const v8s ones = {oneb, oneb, oneb, oneb, oneb, oneb, oneb, oneb};

  float mrow[4] = {-1e30f, -1e30f, -1e30f, -1e30f};
  f32x4 acc[4] = {};
  f32x4 lacc = {};
  bf16* myP = &Pl[wid][0];

  auto stageKV = [&](int buf, int kt) {
#pragma unroll
    for (int i = 0; i < 2; ++i) {
      int c = wid + i * 4;
      g2lds16(&Kg[(long)(kt + c * 8 + lrow8) * 64 + scol], &Ks[buf][c << 9]);
      g2lds16(&Vg[((long)(c * 8 + lrow8) << 10) + kt + scol], &Vs[buf][c << 9]);
    }
  };

  stageKV(0, 0);
  __syncthreads();  // buf0 staged (vmcnt drained at barrier)

  for (int it = 0; it < 16; ++it) {
    const int cur = it & 1;
    if (it + 1 < 16) stageKV(cur ^ 1, (it + 1) * 64);
    const bf16* Kc = &Ks[cur][0];
    const bf16* Vc = &Vs[cur][0];

    // S = Q K^T
    f32x4 s[4] = {};
#pragma unroll
    for (int ks = 0; ks < 2; ++ks) {
      v8s bk[4];
#pragma unroll
      for (int ni = 0; ni < 4; ++ni)
        bk[ni] = *(const v8s*)&Kc[(ni * 16 + lr) * 64 + ((ks * 32 + lg * 8) ^ rswz)];
      __builtin_amdgcn_s_setprio(1);
#pragma unroll
      for (int ni = 0; ni < 4; ++ni)
        s[ni] = __builtin_amdgcn_mfma_f32_16x16x32_bf16(aq[ks], bk[ni], s[ni], 0, 0, 0);
      __builtin_amdgcn_s_setprio(0);
    }

    // online softmax with defer-max; write P (bf16) to per-wave LDS
    float tm[4];
    bool need = false;
#pragma unroll
    for (int r = 0; r < 4; ++r) {
      float t = fmaxf(fmaxf(s[0][r], s[1][r]), fmaxf(s[2][r], s[3][r]));
#pragma unroll
      for (int o = 1; o < 16; o <<= 1) t = fmaxf(t, __shfl_xor(t, o));
      tm[r] = t;
      need = need || (t > mrow[r] + 8.f);
    }
    if (__any(need)) {
#pragma unroll
      for (int r = 0; r < 4; ++r) {
        float mn = fmaxf(mrow[r], tm[r]);
        float al = __expf(mrow[r] - mn);
        mrow[r] = mn;
        lacc[r] *= al;
#pragma unroll
        for (int ni = 0; ni < 4; ++ni) acc[ni][r] *= al;
      }
    }
#pragma unroll
    for (int r = 0; r < 4; ++r) {
      const int prow = (lg * 4 + r) * 76;
#pragma unroll
      for (int ni = 0; ni < 4; ++ni)
        myP[prow + ni * 16 + lr] = __float2bfloat16(__expf(s[ni][r] - mrow[r]));
    }

    // O += P * V ; l += P * ones  (V d-major -> contiguous B-frags)
#pragma unroll
    for (int ks = 0; ks < 2; ++ks) {
      v8s pa, bv[4];
      pa = *(const v8s*)&myP[lr * 76 + ks * 32 + lg * 8];
#pragma unroll
      for (int ni = 0; ni < 4; ++ni)
        bv[ni] = *(const v8s*)&Vc[(ni * 16 + lr) * 64 + ((ks * 32 + lg * 8) ^ rswz)];
      __builtin_amdgcn_s_setprio(1);
#pragma unroll
      for (int ni = 0; ni < 4; ++ni)
        acc[ni] = __builtin_amdgcn_mfma_f32_16x16x32_bf16(pa, bv[ni], acc[ni], 0, 0, 0);
      lacc = __builtin_amdgcn_mfma_f32_16x16x32_bf16(pa, ones, lacc, 0, 0, 0);
      __builtin_amdgcn_s_setprio(0);
    }
    __syncthreads();  // all waves done with cur; next buffer fully staged
  }

  // epilogue: normalize and write concat layout [b*1024+t][h*64+d]
#pragma unroll
  for (int ni = 0; ni < 4; ++ni)
#pragma unroll
    for (int r = 0; r < 4; ++r) {
      int row = q0 + lg * 4 + r;
      cc[((long)(b << 10) + row) * 768 + h * 64 + ni * 16 + lr] =
          __float2bfloat16(acc[ni][r] / lacc[r]);
    }
}

// ---------------- residual + LayerNorm (row=768), float4-vectorized ----------------
__global__ __launch_bounds__(256)
void ln_resid(const float* __restrict__ xin, const float* __restrict__ add,
              const float* __restrict__ g, const float* __restrict__ bb,
              float* __restrict__ xo, bf16* __restrict__ xbo) {
  __shared__ float red[4];
  long row = blockIdx.x;
  int tid = threadIdx.x;
  const f32x4* xr = (const f32x4*)(xin + row * 768);
  const f32x4* ar = (const f32x4*)(add + row * 768);
  f32x4 v = {0.f, 0.f, 0.f, 0.f};
  if (tid < 192) {
    f32x4 a = xr[tid], c = ar[tid];
    v[0] = a[0] + c[0]; v[1] = a[1] + c[1]; v[2] = a[2] + c[2]; v[3] = a[3] + c[3];
  }
  float mean = block_sum(v[0] + v[1] + v[2] + v[3], red, tid) * (1.f / 768.f);
  if (tid < 192) { v[0] -= mean; v[1] -= mean; v[2] -= mean; v[3] -= mean; }
  float sq = tid < 192 ? v[0] * v[0] + v[1] * v[1] + v[2] * v[2] + v[3] * v[3] : 0.f;
  float var = block_sum(sq, red, tid) * (1.f / 768.f);
  float rs = rsqrtf(var + 1e-5f);
  if (tid < 192) {
    f32x4 gv = ((const f32x4*)g)[tid];
    f32x4 bv = ((const f32x4*)bb)[tid];
    f32x4 o;
    o[0] = v[0] * rs * gv[0] + bv[0];
    o[1] = v[1] * rs * gv[1] + bv[1];
    o[2] = v[2] * rs * gv[2] + bv[2];
    o[3] = v[3] * rs * gv[3] + bv[3];
    ((f32x4*)(xo + row * 768))[tid] = o;
    bf16 t0 = __float2bfloat16(o[0]), t1 = __float2bfloat16(o[1]);
    bf16 t2 = __float2bfloat16(o[2]), t3 = __float2bfloat16(o[3]);
    ushort4 pk;
    pk.x = *(unsigned short*)&t0; pk.y = *(unsigned short*)&t1;
    pk.z = *(unsigned short*)&t2; pk.w = *(unsigned short*)&t3;
    *(ushort4*)&xbo[row * 768 + tid * 4] = pk;
  }
}

// ---------------- classifier head ----------------
__global__ __launch_bounds__(256)
void head_cls(const float* __restrict__ x,
              const float* __restrict__ lnpg, const float* __restrict__ lnpb,
              const float* __restrict__ hlng, const float* __restrict__ hlnb,
              float* __restrict__ cls) {
  __shared__ float red[4];
  int b = blockIdx.x, tid = threadIdx.x;
  const float* xr = x + (long)b * 1024 * 768;  // row t=0
  float v0 = xr[tid], v1 = xr[tid + 256], v2 = xr[tid + 512];
  float s = block_sum(v0 + v1 + v2, red, tid) * (1.f / 768.f);
  v0 -= s; v1 -= s; v2 -= s;
  float q = block_sum(v0 * v0 + v1 * v1 + v2 * v2, red, tid) * (1.f / 768.f);
  float r = rsqrtf(q + 1e-5f);
  v0 = v0 * r * lnpg[tid]       + lnpb[tid];
  v1 = v1 * r * lnpg[tid + 256] + lnpb[tid + 256];
  v2 = v2 * r * lnpg[tid + 512] + lnpb[tid + 512];
  s = block_sum(v0 + v1 + v2, red, tid) * (1.f / 768.f);
  v0 -= s; v1 -= s; v2 -= s;
  q = block_sum(v0 * v0 + v1 * v1 + v2 * v2, red, tid) * (1.f / 768.f);
  r = rsqrtf(q + 1e-5f);
  cls[b * 768 + tid]       = v0 * r * hlng[tid]       + hlnb[tid];
  cls[b * 768 + tid + 256] = v1 * r * hlng[tid + 256] + hlnb[tid + 256];
  cls[b * 768 + tid + 512] = v2 * r * hlng[tid + 512] + hlnb[tid + 512];
}

// split-K GEMV stage A
__global__ __launch_bounds__(256)
void mlp_part(const float* __restrict__ in, const float* __restrict__ wmat,
              float* __restrict__ part, int IN, int OUTP, int ET) {
  __shared__ float cin[4][96];
  __shared__ float red[8][32][16];
  int tid = threadIdx.x;
  int tx = tid & 31, ty = tid >> 5;
  int e0 = blockIdx.y * ET;
  for (int i = tid; i < 4 * ET; i += 256) {
    int b = i / ET, el = i - b * ET;
    cin[b][el] = in[b * IN + e0 + el];
  }
  __syncthreads();
  f32x4 acc[4] = {};
  const float* wp = wmat + (long)e0 * OUTP + (blockIdx.x * 32 + tx) * 4;
  const int iters = ET >> 3;
  for (int i = 0; i < iters; ++i) {
    int el = ty + i * 8;
    f32x4 w = *(const f32x4*)(wp + (long)el * OUTP);
#pragma unroll
    for (int b = 0; b < 4; ++b) acc[b] += cin[b][el] * w;
  }
#pragma unroll
  for (int b = 0; b < 4; ++b) *(f32x4*)&red[ty][tx][b * 4] = acc[b];
  __syncthreads();
  if (tid < 128) {
    int rx = tid & 31, b = tid >> 5;
    f32x4 s = {};
#pragma unroll
    for (int t = 0; t < 8; ++t) s += *(const f32x4*)&red[t][rx][b * 4];
    *(f32x4*)&part[((long)blockIdx.y * 4 + b) * OUTP + (blockIdx.x * 32 + rx) * 4] = s;
  }
}

__global__ __launch_bounds__(256)
void mlp_reduce(const float* __restrict__ part, const float* __restrict__ bias,
                float* __restrict__ out, int OUTP, int S, int relu) {
  int idx = blockIdx.x * 256 + threadIdx.x;
  int b = idx / OUTP, j = idx - b * OUTP;
  float s = bias[j];
  for (int t = 0; t < S; ++t) s += part[((long)t * 4 + b) * OUTP + j];
  out[idx] = relu ? fmaxf(s, 0.f) : s;
}

// C=527 logits in [4][640] padded rows
__global__ __launch_bounds__(256)
void head_softmax(const float* __restrict__ lg, float* __restrict__ out) {
  __shared__ float red[4];
  int b = blockIdx.x, tid = threadIdx.x;
  const float* r = lg + (long)b * 640;
  float v0 = r[tid];
  float v1 = tid + 256 < 527 ? r[tid + 256] : -1e30f;
  float v2 = tid + 512 < 527 ? r[tid + 512] : -1e30f;
  float mx = block_max(fmaxf(v0, fmaxf(v1, v2)), red, tid);
  float e0 = __expf(v0 - mx);
  float e1 = tid + 256 < 527 ? __expf(v1 - mx) : 0.f;
  float e2 = tid + 512 < 527 ? __expf(v2 - mx) : 0.f;
  float sm = block_sum(e0 + e1 + e2, red, tid);
  float inv = 1.f / sm;
  out[(long)b * 527 + tid] = e0 * inv;
  if (tid + 256 < 527) out[(long)b * 527 + tid + 256] = e1 * inv;
  if (tid + 512 < 527) out[(long)b * 527 + tid + 512] = e2 * inv;
}

// ---------------- launcher ----------------
extern "C" void kernel_launch(void* const* d_in, const int* in_sizes, int n_in,
                              void* d_out, int out_size, void* d_ws, size_t ws_size,
                              hipStream_t stream) {
  const float* x_in    = (const float*)d_in[0];
  const float* conv1_w = (const float*)d_in[1];
  const float* conv1_b = (const float*)d_in[2];
  const float* conv2_w = (const float*)d_in[3];
  const float* conv2_b = (const float*)d_in[4];
  const float* pos_emb = (const float*)d_in[5];
  const float* ln1_g   = (const float*)d_in[6];
  const float* ln1_b   = (const float*)d_in[7];
  const float* wq      = (const float*)d_in[8];
  const float* bq      = (const float*)d_in[9];
  const float* wk      = (const float*)d_in[10];
  const float* bk      = (const float*)d_in[11];
  const float* wv      = (const float*)d_in[12];
  const float* bv      = (const float*)d_in[13];
  const float* wo      = (const float*)d_in[14];
  const float* bo      = (const float*)d_in[15];
  const float* w1      = (const float*)d_in[16];
  const float* b1      = (const float*)d_in[17];
  const float* w2      = (const float*)d_in[18];
  const float* b2      = (const float*)d_in[19];
  const float* ln2_g   = (const float*)d_in[20];
  const float* ln2_b   = (const float*)d_in[21];
  const float* lnp_g   = (const float*)d_in[22];
  const float* lnp_b   = (const float*)d_in[23];
  const float* hln_g   = (const float*)d_in[24];
  const float* hln_b   = (const float*)d_in[25];
  const float* hw1     = (const float*)d_in[26];
  const float* hb1     = (const float*)d_in[27];
  const float* hw2     = (const float*)d_in[28];
  const float* hb2     = (const float*)d_in[29];

  // workspace layout
  char* w = (char*)d_ws;
  bf16*  wqkvT = (bf16*)(w);                      // 6*2304*768 bf16
  bf16*  woT   = (bf16*)(w + 21233664);           // 6*768*768
  bf16*  w1T   = (bf16*)(w + 28311552);           // 6*3072*768
  bf16*  w2T   = (bf16*)(w + 56623104);           // 6*768*3072
  bf16*  wc1T  = (bf16*)(w + 84934656);           // 768*256
  bf16*  wc2T  = (bf16*)(w + 85327872);           // 768*2304
  float* bqkv  = (float*)(w + 88866816);          // 6*2304 f32
  float* Xf    = (float*)(w + 88922112);          // 4096*768 f32
  bf16*  Xb    = (bf16*)(w + 101505024);          // 4096*768
  bf16*  qkv   = (bf16*)(w + 107796480);          // 3*4096*768 (q t-major, k t-major, v d-major)
  bf16*  CC    = (bf16*)(w + 126670848);          // 4096*768
  float* ATTN  = (float*)(w + 132962304);         // 4096*768 f32
  char*  BIG   = w + 145545216;                   // 50,331,648 shared region
  bf16*  A1  = (bf16*)(BIG);                      // 8192*256   (conv phase)
  bf16*  Y1G = (bf16*)(BIG + 4194304);            // 8192*768   (conv phase)
  bf16*  A2  = (bf16*)(BIG + 16777216);           // 4096*2304  (conv phase)
  bf16*  Hh  = (bf16*)(BIG);                      // 4096*3072  (ffn phase)
  float* FFN = (float*)(BIG + 25165824);          // 4096*768 f32 (ffn phase)
  // head phase (aliases, used only after last FFN)
  float* CLS  = (float*)(BIG);                    // 4*768
  float* HID  = (float*)(BIG + 16384);            // 4*3072
  float* LGT  = (float*)(BIG + 81920);            // 4*640
  float* PT1  = (float*)(BIG + 131072);           // 16*4*3072
  float* PT2  = (float*)(BIG + 1048576);          // 32*4*640
  float* HB2P = (float*)(BIG + 1572864);          // 640
  float* HW2P = (float*)(BIG + 1605632);          // 3072*640

  // ---- weight prep ----
  tconv<<<dim3(2, 24, 72), 256, 0, stream>>>(wq, wqkvT,            768, 64,   49152L, 1769472L, 49152L, 12);
  tconv<<<dim3(2, 24, 72), 256, 0, stream>>>(wk, wqkvT + 589824,   768, 64,   49152L, 1769472L, 49152L, 12);
  tconv<<<dim3(2, 24, 72), 256, 0, stream>>>(wv, wqkvT + 1179648,  768, 64,   49152L, 1769472L, 49152L, 12);
  tconv<<<dim3(24, 24, 6), 256, 0, stream>>>(wo, woT,              768, 768,  589824L, 589824L, 0L, 1);
  tconv<<<dim3(96, 24, 6), 256, 0, stream>>>(w1, w1T,              768, 3072, 2359296L, 2359296L, 0L, 1);
  tconv<<<dim3(24, 96, 6), 256, 0, stream>>>(w2, w2T,              3072, 768, 2359296L, 2359296L, 0L, 1);
  prep_cw<<<768,  256, 0, stream>>>(conv1_w, wc1T, 80, 256);
  prep_cw<<<6912, 256, 0, stream>>>(conv2_w, wc2T, 768, 2304);
  prep_bias<<<54, 256, 0, stream>>>(bq, bk, bv, bqkv);

  // ---- convs ----
  im2col1<<<8192, 256, 0, stream>>>(x_in, A1);
  { GP p{}; p.A = A1; p.B = wc1T; p.bias = conv1_b; p.Ob = Y1G;
    p.M = 8192; p.N = 768; p.K = 256;
    gemm_bt<128,64,2,2,EPI_GELU_BF16><<<dim3(64,12,1),256,0,stream>>>(p); }
  im2col2<<<36864, 256, 0, stream>>>(Y1G, A2);
  { GP p{}; p.A = A2; p.B = wc2T; p.bias = conv2_b; p.Of = Xf; p.Ob = Xb; p.aux = pos_emb;
    p.M = 4096; p.N = 768; p.K = 2304;
    gemm_bt<128,64,2,2,EPI_CONV2><<<dim3(32,12,1),256,0,stream>>>(p); }

  // ---- transformer layers ----
  for (int l = 0; l < 6; ++l) {
    { GP p{}; p.A = Xb; p.B = wqkvT + (long)l * 1769472; p.bias = bqkv + l * 2304;
      p.Ob = qkv; p.M = 4096; p.N = 2304; p.K = 768;
      gemm_bt<128,128,2,2,EPI_QKV><<<dim3(32,18,1),256,0,stream>>>(p); }
    attn_flash<<<768, 256, 0, stream>>>(qkv, CC);
    { GP p{}; p.A = CC; p.B = woT + (long)l * 589824; p.bias = bo + l * 768; p.Of = ATTN;
      p.M = 4096; p.N = 768; p.K = 768;
      gemm_bt<128,64,2,2,EPI_BIAS_F32><<<dim3(32,12,1),256,0,stream>>>(p); }
    ln_resid<<<4096, 256, 0, stream>>>(Xf, ATTN, ln1_g + l * 768, ln1_b + l * 768, Xf, Xb);
    { GP p{}; p.A = Xb; p.B = w1T + (long)l * 2359296; p.bias = b1 + l * 3072; p.Ob = Hh;
      p.M = 4096; p.N = 3072; p.K = 768;
      gemm_bt<128,128,2,2,EPI_RELU_BF16><<<dim3(32,24,1),256,0,stream>>>(p); }
    { GP p{}; p.A = Hh; p.B = w2T + (long)l * 2359296; p.bias = b2 + l * 768; p.Of = FFN;
      p.M = 4096; p.N = 768; p.K = 3072;
      gemm_bt<128,64,2,2,EPI_BIAS_F32><<<dim3(32,12,1),256,0,stream>>>(p); }
    ln_resid<<<4096, 256, 0, stream>>>(Xf, FFN, ln2_g + l * 768, ln2_b + l * 768, Xf, Xb);
  }

  // ---- head ----
  head_cls<<<4, 256, 0, stream>>>(Xf, lnp_g, lnp_b, hln_g, hln_b, CLS);
  prep_hw2<<<7680, 256, 0, stream>>>(hw2, hb2, HW2P, HB2P);
  mlp_part<<<dim3(24, 16), 256, 0, stream>>>(CLS, hw1, PT1, 768, 3072, 48);
  mlp_reduce<<<48, 256, 0, stream>>>(PT1, hb1, HID, 3072, 16, 1);
  mlp_part<<<dim3(5, 32), 256, 0, stream>>>(HID, HW2P, PT2, 3072, 640, 96);
  mlp_reduce<<<10, 256, 0, stream>>>(PT2, HB2P, LGT, 640, 32, 0);
  head_softmax<<<4, 256, 0, stream>>>(LGT, (float*)d_out);
}

// Round 14
// 1212.450 us; speedup vs baseline: 2.3556x; 1.1195x over previous
//
#include <hip/hip_runtime.h>
#include <hip/hip_bf16.h>

typedef __hip_bfloat16 bf16;
using v8s   = __attribute__((ext_vector_type(8))) short;
using f32x4 = __attribute__((ext_vector_type(4))) float;

#define DI __device__ __forceinline__

DI float gelu_f(float x) { return 0.5f * x * (1.f + erff(x * 0.70710678118654752f)); }

DI void g2lds16(const bf16* g, bf16* l) {
  __builtin_amdgcn_global_load_lds((const __attribute__((address_space(1))) void*)g,
                                   (__attribute__((address_space(3))) void*)l, 16, 0, 0);
}

// ---------------- block reduction helpers (256 threads, 4 waves) ----------------
DI float block_sum(float v, float* red, int tid) {
#pragma unroll
  for (int o = 32; o > 0; o >>= 1) v += __shfl_down(v, o);
  __syncthreads();
  if ((tid & 63) == 0) red[tid >> 6] = v;
  __syncthreads();
  return red[0] + red[1] + red[2] + red[3];
}
DI float block_max(float v, float* red, int tid) {
#pragma unroll
  for (int o = 32; o > 0; o >>= 1) v = fmaxf(v, __shfl_down(v, o));
  __syncthreads();
  if ((tid & 63) == 0) red[tid >> 6] = v;
  __syncthreads();
  return fmaxf(fmaxf(red[0], red[1]), fmaxf(red[2], red[3]));
}

// ---------------- weight prep ----------------
__global__ __launch_bounds__(256)
void tconv(const float* __restrict__ in, bf16* __restrict__ out,
           int R, int C, long inStrideZ, long outStrideL, long outStrideH, int zmod) {
  __shared__ float tile[32][33];
  int z = blockIdx.z;
  int lz = z / zmod, hz = z - lz * zmod;
  in  += (long)z * inStrideZ;
  out += (long)lz * outStrideL + (long)hz * outStrideH;
  int cb = blockIdx.x * 32, rb = blockIdx.y * 32;
  int tx = threadIdx.x & 31, ty = threadIdx.x >> 5;  // 32x8
#pragma unroll
  for (int i = 0; i < 32; i += 8)
    tile[ty + i][tx] = in[(long)(rb + ty + i) * C + cb + tx];
  __syncthreads();
#pragma unroll
  for (int i = 0; i < 32; i += 8)
    out[(long)(cb + ty + i) * R + rb + tx] = __float2bfloat16(tile[tx][ty + i]);
}

__global__ __launch_bounds__(256)
void prep_cw(const float* __restrict__ wsrc, bf16* __restrict__ o, int IC, int KT) {
  int idx = blockIdx.x * 256 + threadIdx.x;
  int oc = idx / KT, kp = idx - oc * KT;
  float v = 0.f;
  if (kp < IC * 3) {
    int kk = kp / IC, ic = kp - kk * IC;
    v = wsrc[(oc * IC + ic) * 3 + kk];
  }
  o[idx] = __float2bfloat16(v);
}

__global__ __launch_bounds__(256)
void prep_bias(const float* __restrict__ bq, const float* __restrict__ bk,
               const float* __restrict__ bv, float* __restrict__ o) {
  int idx = blockIdx.x * 256 + threadIdx.x;  // 6*2304
  int l = idx / 2304, n = idx - l * 2304;
  int which = n / 768, r = n - which * 768;
  const float* src = which == 0 ? bq : (which == 1 ? bk : bv);
  o[idx] = src[l * 768 + r];
}

// pad-repack head layer-2 weights: hw2 [3072][527] -> hw2p [3072][640] (zero pad)
__global__ __launch_bounds__(256)
void prep_hw2(const float* __restrict__ hw2, const float* __restrict__ hb2,
              float* __restrict__ hw2p, float* __restrict__ hb2p) {
  int idx = blockIdx.x * 256 + threadIdx.x;  // 3072*640
  int e = idx / 640, c = idx - e * 640;
  hw2p[idx] = c < 527 ? hw2[(long)e * 527 + c] : 0.f;
  if (idx < 640) hb2p[idx] = idx < 527 ? hb2[idx] : 0.f;
}

// ---------------- im2col ----------------
__global__ __launch_bounds__(256)
void im2col1(const float* __restrict__ x, bf16* __restrict__ out) {
  int idx = blockIdx.x * 256 + threadIdx.x;  // 8192*256
  int m = idx >> 8, kp = idx & 255;
  float v = 0.f;
  if (kp < 240) {
    int kk = kp / 80, ic = kp - kk * 80;
    int t = (m & 2047) + kk - 1;
    int b = m >> 11;
    if ((unsigned)t < 2048u) v = x[((long)(b * 80 + ic) << 11) + t];
  }
  out[idx] = __float2bfloat16(v);
}

__global__ __launch_bounds__(256)
void im2col2(const bf16* __restrict__ y, bf16* __restrict__ out) {
  int idx = blockIdx.x * 256 + threadIdx.x;  // 4096*2304
  int m = idx / 2304, kp = idx - m * 2304;
  int kk = kp / 768, ic = kp - kk * 768;
  int t = 2 * (m & 1023) + kk - 1;
  bf16 v = __float2bfloat16(0.f);
  if ((unsigned)t < 2048u) v = y[((long)(m >> 10) * 2048 + t) * 768 + ic];
  out[idx] = v;
}

// ---------------- GEMM: C[m][n] = sum_k A[m][k]*B[n][k]  (both bf16, K%64==0) ----------------
// Rule-21 XOR swizzle (conflicts = 0, verified r11). DBUF=1: 2-phase ping-pong
// (64KB LDS, 2 blocks/CU) -- for grid-limited GEMMs. DBUF=0: single-buffer m97
// structure (32KB LDS, 4 blocks/CU) -- for large-grid GEMMs where cross-block
// wave overlap hides the barrier drain (m114 mechanism).
enum { EPI_GELU_BF16, EPI_CONV2, EPI_QKV, EPI_BIAS_F32, EPI_RELU_BF16 };

struct GP {
  const bf16* A; const bf16* B; const float* bias;
  bf16* Ob; float* Of; const float* aux;
  int M, N, K; long sA, sB, sC; int zoff;
};

template<int BM, int BN, int WM, int WN, int EPI, int DBUF>
__global__ __launch_bounds__(WM * WN * 64, 2)
void gemm_bt(GP p) {
  constexpr int WAVES = WM * WN;
  constexpr int FM = BM / WM / 16, FN = BN / WN / 16;
  __shared__ __align__(16) bf16 As0[BM * 64], Bs0[BN * 64];
  __shared__ __align__(16) bf16 As1[DBUF ? BM * 64 : 8], Bs1[DBUF ? BN * 64 : 8];
  const int tid = threadIdx.x;
  const int lane = tid & 63, wid = tid >> 6;
  const int wr = wid / WN, wc = wid - wr * WN;
  const int row0 = wr * (BM / WM), col0 = wc * (BN / WN);
  const int lr = lane & 15, lk = (lane >> 4) * 8;
  const int lrow = lane >> 3;
  const int scol = (((lane & 7) ^ (lane >> 3)) & 7) * 8;  // pre-swizzled source col
  const int rswz = (lr & 7) * 8;                          // read-side XOR
  const int z = blockIdx.z;
  const bf16* Ab = p.A + (long)z * p.sA + (long)blockIdx.x * BM * p.K;
  const bf16* Bb = p.B + (long)z * p.sB + (long)blockIdx.y * BN * p.K;
  f32x4 acc[FM][FN] = {};

  auto stage = [&](bf16* As, bf16* Bs, int kt) {
#pragma unroll
    for (int i = 0; i < BM / 8 / WAVES; ++i) {
      const int c = wid + i * WAVES;  // chunk of 8 rows (1KB)
      g2lds16(&Ab[(long)(c * 8 + lrow) * p.K + kt + scol], &As[c << 9]);
    }
#pragma unroll
    for (int i = 0; i < BN / 8 / WAVES; ++i) {
      const int c = wid + i * WAVES;
      g2lds16(&Bb[(long)(c * 8 + lrow) * p.K + kt + scol], &Bs[c << 9]);
    }
  };

  auto compute = [&](const bf16* As, const bf16* Bs) {
#pragma unroll
    for (int ks = 0; ks < 2; ++ks) {
      v8s af[FM], bf_[FN];
#pragma unroll
      for (int mi = 0; mi < FM; ++mi)
        af[mi] = *(const v8s*)&As[(row0 + mi * 16 + lr) * 64 + ((ks * 32 + lk) ^ rswz)];
#pragma unroll
      for (int ni = 0; ni < FN; ++ni)
        bf_[ni] = *(const v8s*)&Bs[(col0 + ni * 16 + lr) * 64 + ((ks * 32 + lk) ^ rswz)];
      __builtin_amdgcn_s_setprio(1);
#pragma unroll
      for (int mi = 0; mi < FM; ++mi)
#pragma unroll
        for (int ni = 0; ni < FN; ++ni)
          acc[mi][ni] = __builtin_amdgcn_mfma_f32_16x16x32_bf16(af[mi], bf_[ni], acc[mi][ni], 0, 0, 0);
      __builtin_amdgcn_s_setprio(0);
    }
  };

  if constexpr (DBUF) {
    stage(As0, Bs0, 0);
    __syncthreads();
    int kt = 0;
    while (true) {
      if (kt + 64 < p.K) stage(As1, Bs1, kt + 64);
      compute(As0, Bs0);
      __syncthreads();
      kt += 64;
      if (kt >= p.K) break;
      if (kt + 64 < p.K) stage(As0, Bs0, kt + 64);
      compute(As1, Bs1);
      __syncthreads();
      kt += 64;
      if (kt >= p.K) break;
    }
  } else {
    for (int kt = 0; kt < p.K; kt += 64) {
      __syncthreads();
      stage(As0, Bs0, kt);
      __syncthreads();
      compute(As0, Bs0);
    }
  }

  // epilogue; D: row=(lane>>4)*4+r, col=lane&15
#pragma unroll
  for (int mi = 0; mi < FM; ++mi) {
#pragma unroll
    for (int ni = 0; ni < FN; ++ni) {
#pragma unroll
      for (int r = 0; r < 4; ++r) {
        float v = acc[mi][ni][r];
        const int m = blockIdx.x * BM + row0 + mi * 16 + (lane >> 4) * 4 + r;
        const int n = blockIdx.y * BN + col0 + ni * 16 + lr;
        if constexpr (EPI == EPI_GELU_BF16) {
          p.Ob[(long)m * p.N + n] = __float2bfloat16(gelu_f(v + p.bias[n]));
        } else if constexpr (EPI == EPI_CONV2) {
          float t = gelu_f(v + p.bias[n]) + p.aux[(long)(m & 1023) * 768 + n];
          p.Of[(long)m * 768 + n] = t;
          p.Ob[(long)m * 768 + n] = __float2bfloat16(t);
        } else if constexpr (EPI == EPI_QKV) {
          float t = v + p.bias[n];
          int which = n / 768, nn = n - which * 768;
          int h = nn >> 6, d = nn & 63;
          long bh = (long)(m >> 10) * 12 + h;
          if (which < 2)
            p.Ob[(long)which * 3145728 + (bh << 16) + ((long)(m & 1023) << 6) + d] = __float2bfloat16(t);
          else
            p.Ob[6291456L + (bh << 16) + ((long)d << 10) + (m & 1023)] = __float2bfloat16(t);
        } else if constexpr (EPI == EPI_BIAS_F32) {
          p.Of[(long)m * p.N + n] = v + p.bias[n];
        } else if constexpr (EPI == EPI_RELU_BF16) {
          p.Ob[(long)m * p.N + n] = __float2bfloat16(fmaxf(v + p.bias[n], 0.f));
        }
      }
    }
  }
}

// ---------------- fused flash attention ----------------
// QBLK=64: grid 768 = exactly 3 blocks/CU. qt = blk/48, bh = blk%48
// (same-head blocks spaced 48 = 0 mod 8 -> same XCD L2). 4 waves x 16 q-rows.
// K/V dbuf + XOR swizzle; denominator via ones-MFMA; defer-max THR=8.
__global__ __launch_bounds__(256)
void attn_flash(const bf16* __restrict__ qkv, bf16* __restrict__ cc) {
  __shared__ __align__(16) bf16 Ks[2][64 * 64], Vs[2][64 * 64];
  __shared__ __align__(16) bf16 Pl[4][16 * 76];
  const int tid = threadIdx.x, lane = tid & 63, wid = tid >> 6;
  const int lr = lane & 15, lg = lane >> 4;
  const int blk = blockIdx.x;
  const int qt = blk / 48, bh = blk - qt * 48;
  const int b = bh / 12, h = bh - b * 12;
  const long qb = (long)bh << 16;
  const bf16* Qg = qkv + qb;
  const bf16* Kg = qkv + 3145728 + qb;
  const bf16* Vg = qkv + 6291456 + qb;
  const int q0 = qt * 64 + wid * 16;
  const int lrow8 = lane >> 3;
  const int scol = (((lane & 7) ^ (lane >> 3)) & 7) * 8;  // pre-swizzled source col
  const int rswz = (lr & 7) * 8;                          // read-side XOR

  v8s aq[2];
#pragma unroll
  for (int ks = 0; ks < 2; ++ks)
    aq[ks] = *(const v8s*)&Qg[(long)(q0 + lr) * 64 + ks * 32 + lg * 8];

  const short oneb = (short)0x3F80;  // bf16 1.0
  const v8s ones = {oneb, oneb, oneb, oneb, oneb, oneb, oneb, oneb};

  float mrow[4] = {-1e30f, -1e30f, -1e30f, -1e30f};
  f32x4 acc[4] = {};
  f32x4 lacc = {};
  bf16* myP = &Pl[wid][0];

  auto stageKV = [&](int buf, int kt) {
#pragma unroll
    for (int i = 0; i < 2; ++i) {
      int c = wid + i * 4;
      g2lds16(&Kg[(long)(kt + c * 8 + lrow8) * 64 + scol], &Ks[buf][c << 9]);
      g2lds16(&Vg[((long)(c * 8 + lrow8) << 10) + kt + scol], &Vs[buf][c << 9]);
    }
  };

  stageKV(0, 0);
  __syncthreads();  // buf0 staged (vmcnt drained at barrier)

  for (int it = 0; it < 16; ++it) {
    const int cur = it & 1;
    if (it + 1 < 16) stageKV(cur ^ 1, (it + 1) * 64);
    const bf16* Kc = &Ks[cur][0];
    const bf16* Vc = &Vs[cur][0];

    // S = Q K^T
    f32x4 s[4] = {};
#pragma unroll
    for (int ks = 0; ks < 2; ++ks) {
      v8s bk[4];
#pragma unroll
      for (int ni = 0; ni < 4; ++ni)
        bk[ni] = *(const v8s*)&Kc[(ni * 16 + lr) * 64 + ((ks * 32 + lg * 8) ^ rswz)];
      __builtin_amdgcn_s_setprio(1);
#pragma unroll
      for (int ni = 0; ni < 4; ++ni)
        s[ni] = __builtin_amdgcn_mfma_f32_16x16x32_bf16(aq[ks], bk[ni], s[ni], 0, 0, 0);
      __builtin_amdgcn_s_setprio(0);
    }

    // online softmax with defer-max; write P (bf16) to per-wave LDS
    float tm[4];
    bool need = false;
#pragma unroll
    for (int r = 0; r < 4; ++r) {
      float t = fmaxf(fmaxf(s[0][r], s[1][r]), fmaxf(s[2][r], s[3][r]));
#pragma unroll
      for (int o = 1; o < 16; o <<= 1) t = fmaxf(t, __shfl_xor(t, o));
      tm[r] = t;
      need = need || (t > mrow[r] + 8.f);
    }
    if (__any(need)) {
#pragma unroll
      for (int r = 0; r < 4; ++r) {
        float mn = fmaxf(mrow[r], tm[r]);
        float al = __expf(mrow[r] - mn);
        mrow[r] = mn;
        lacc[r] *= al;
#pragma unroll
        for (int ni = 0; ni < 4; ++ni) acc[ni][r] *= al;
      }
    }
#pragma unroll
    for (int r = 0; r < 4; ++r) {
      const int prow = (lg * 4 + r) * 76;
#pragma unroll
      for (int ni = 0; ni < 4; ++ni)
        myP[prow + ni * 16 + lr] = __float2bfloat16(__expf(s[ni][r] - mrow[r]));
    }

    // O += P * V ; l += P * ones  (V d-major -> contiguous B-frags)
#pragma unroll
    for (int ks = 0; ks < 2; ++ks) {
      v8s pa, bv[4];
      pa = *(const v8s*)&myP[lr * 76 + ks * 32 + lg * 8];
#pragma unroll
      for (int ni = 0; ni < 4; ++ni)
        bv[ni] = *(const v8s*)&Vc[(ni * 16 + lr) * 64 + ((ks * 32 + lg * 8) ^ rswz)];
      __builtin_amdgcn_s_setprio(1);
#pragma unroll
      for (int ni = 0; ni < 4; ++ni)
        acc[ni] = __builtin_amdgcn_mfma_f32_16x16x32_bf16(pa, bv[ni], acc[ni], 0, 0, 0);
      lacc = __builtin_amdgcn_mfma_f32_16x16x32_bf16(pa, ones, lacc, 0, 0, 0);
      __builtin_amdgcn_s_setprio(0);
    }
    __syncthreads();  // all waves done with cur; next buffer fully staged
  }

  // epilogue: normalize and write concat layout [b*1024+t][h*64+d]
#pragma unroll
  for (int ni = 0; ni < 4; ++ni)
#pragma unroll
    for (int r = 0; r < 4; ++r) {
      int row = q0 + lg * 4 + r;
      cc[((long)(b << 10) + row) * 768 + h * 64 + ni * 16 + lr] =
          __float2bfloat16(acc[ni][r] / lacc[r]);
    }
}

// ---------------- residual + LayerNorm (row=768), float4-vectorized ----------------
__global__ __launch_bounds__(256)
void ln_resid(const float* __restrict__ xin, const float* __restrict__ add,
              const float* __restrict__ g, const float* __restrict__ bb,
              float* __restrict__ xo, bf16* __restrict__ xbo) {
  __shared__ float red[4];
  long row = blockIdx.x;
  int tid = threadIdx.x;
  const f32x4* xr = (const f32x4*)(xin + row * 768);
  const f32x4* ar = (const f32x4*)(add + row * 768);
  f32x4 v = {0.f, 0.f, 0.f, 0.f};
  if (tid < 192) {
    f32x4 a = xr[tid], c = ar[tid];
    v[0] = a[0] + c[0]; v[1] = a[1] + c[1]; v[2] = a[2] + c[2]; v[3] = a[3] + c[3];
  }
  float mean = block_sum(v[0] + v[1] + v[2] + v[3], red, tid) * (1.f / 768.f);
  if (tid < 192) { v[0] -= mean; v[1] -= mean; v[2] -= mean; v[3] -= mean; }
  float sq = tid < 192 ? v[0] * v[0] + v[1] * v[1] + v[2] * v[2] + v[3] * v[3] : 0.f;
  float var = block_sum(sq, red, tid) * (1.f / 768.f);
  float rs = rsqrtf(var + 1e-5f);
  if (tid < 192) {
    f32x4 gv = ((const f32x4*)g)[tid];
    f32x4 bv = ((const f32x4*)bb)[tid];
    f32x4 o;
    o[0] = v[0] * rs * gv[0] + bv[0];
    o[1] = v[1] * rs * gv[1] + bv[1];
    o[2] = v[2] * rs * gv[2] + bv[2];
    o[3] = v[3] * rs * gv[3] + bv[3];
    ((f32x4*)(xo + row * 768))[tid] = o;
    bf16 t0 = __float2bfloat16(o[0]), t1 = __float2bfloat16(o[1]);
    bf16 t2 = __float2bfloat16(o[2]), t3 = __float2bfloat16(o[3]);
    ushort4 pk;
    pk.x = *(unsigned short*)&t0; pk.y = *(unsigned short*)&t1;
    pk.z = *(unsigned short*)&t2; pk.w = *(unsigned short*)&t3;
    *(ushort4*)&xbo[row * 768 + tid * 4] = pk;
  }
}

// ---------------- classifier head ----------------
__global__ __launch_bounds__(256)
void head_cls(const float* __restrict__ x,
              const float* __restrict__ lnpg, const float* __restrict__ lnpb,
              const float* __restrict__ hlng, const float* __restrict__ hlnb,
              float* __restrict__ cls) {
  __shared__ float red[4];
  int b = blockIdx.x, tid = threadIdx.x;
  const float* xr = x + (long)b * 1024 * 768;  // row t=0
  float v0 = xr[tid], v1 = xr[tid + 256], v2 = xr[tid + 512];
  float s = block_sum(v0 + v1 + v2, red, tid) * (1.f / 768.f);
  v0 -= s; v1 -= s; v2 -= s;
  float q = block_sum(v0 * v0 + v1 * v1 + v2 * v2, red, tid) * (1.f / 768.f);
  float r = rsqrtf(q + 1e-5f);
  v0 = v0 * r * lnpg[tid]       + lnpb[tid];
  v1 = v1 * r * lnpg[tid + 256] + lnpb[tid + 256];
  v2 = v2 * r * lnpg[tid + 512] + lnpb[tid + 512];
  s = block_sum(v0 + v1 + v2, red, tid) * (1.f / 768.f);
  v0 -= s; v1 -= s; v2 -= s;
  q = block_sum(v0 * v0 + v1 * v1 + v2 * v2, red, tid) * (1.f / 768.f);
  r = rsqrtf(q + 1e-5f);
  cls[b * 768 + tid]       = v0 * r * hlng[tid]       + hlnb[tid];
  cls[b * 768 + tid + 256] = v1 * r * hlng[tid + 256] + hlnb[tid + 256];
  cls[b * 768 + tid + 512] = v2 * r * hlng[tid + 512] + hlnb[tid + 512];
}

// split-K GEMV stage A
__global__ __launch_bounds__(256)
void mlp_part(const float* __restrict__ in, const float* __restrict__ wmat,
              float* __restrict__ part, int IN, int OUTP, int ET) {
  __shared__ float cin[4][96];
  __shared__ float red[8][32][16];
  int tid = threadIdx.x;
  int tx = tid & 31, ty = tid >> 5;
  int e0 = blockIdx.y * ET;
  for (int i = tid; i < 4 * ET; i += 256) {
    int b = i / ET, el = i - b * ET;
    cin[b][el] = in[b * IN + e0 + el];
  }
  __syncthreads();
  f32x4 acc[4] = {};
  const float* wp = wmat + (long)e0 * OUTP + (blockIdx.x * 32 + tx) * 4;
  const int iters = ET >> 3;
  for (int i = 0; i < iters; ++i) {
    int el = ty + i * 8;
    f32x4 w = *(const f32x4*)(wp + (long)el * OUTP);
#pragma unroll
    for (int b = 0; b < 4; ++b) acc[b] += cin[b][el] * w;
  }
#pragma unroll
  for (int b = 0; b < 4; ++b) *(f32x4*)&red[ty][tx][b * 4] = acc[b];
  __syncthreads();
  if (tid < 128) {
    int rx = tid & 31, b = tid >> 5;
    f32x4 s = {};
#pragma unroll
    for (int t = 0; t < 8; ++t) s += *(const f32x4*)&red[t][rx][b * 4];
    *(f32x4*)&part[((long)blockIdx.y * 4 + b) * OUTP + (blockIdx.x * 32 + rx) * 4] = s;
  }
}

__global__ __launch_bounds__(256)
void mlp_reduce(const float* __restrict__ part, const float* __restrict__ bias,
                float* __restrict__ out, int OUTP, int S, int relu) {
  int idx = blockIdx.x * 256 + threadIdx.x;
  int b = idx / OUTP, j = idx - b * OUTP;
  float s = bias[j];
  for (int t = 0; t < S; ++t) s += part[((long)t * 4 + b) * OUTP + j];
  out[idx] = relu ? fmaxf(s, 0.f) : s;
}

// C=527 logits in [4][640] padded rows
__global__ __launch_bounds__(256)
void head_softmax(const float* __restrict__ lg, float* __restrict__ out) {
  __shared__ float red[4];
  int b = blockIdx.x, tid = threadIdx.x;
  const float* r = lg + (long)b * 640;
  float v0 = r[tid];
  float v1 = tid + 256 < 527 ? r[tid + 256] : -1e30f;
  float v2 = tid + 512 < 527 ? r[tid + 512] : -1e30f;
  float mx = block_max(fmaxf(v0, fmaxf(v1, v2)), red, tid);
  float e0 = __expf(v0 - mx);
  float e1 = tid + 256 < 527 ? __expf(v1 - mx) : 0.f;
  float e2 = tid + 512 < 527 ? __expf(v2 - mx) : 0.f;
  float sm = block_sum(e0 + e1 + e2, red, tid);
  float inv = 1.f / sm;
  out[(long)b * 527 + tid] = e0 * inv;
  if (tid + 256 < 527) out[(long)b * 527 + tid + 256] = e1 * inv;
  if (tid + 512 < 527) out[(long)b * 527 + tid + 512] = e2 * inv;
}

// ---------------- launcher ----------------
extern "C" void kernel_launch(void* const* d_in, const int* in_sizes, int n_in,
                              void* d_out, int out_size, void* d_ws, size_t ws_size,
                              hipStream_t stream) {
  const float* x_in    = (const float*)d_in[0];
  const float* conv1_w = (const float*)d_in[1];
  const float* conv1_b = (const float*)d_in[2];
  const float* conv2_w = (const float*)d_in[3];
  const float* conv2_b = (const float*)d_in[4];
  const float* pos_emb = (const float*)d_in[5];
  const float* ln1_g   = (const float*)d_in[6];
  const float* ln1_b   = (const float*)d_in[7];
  const float* wq      = (const float*)d_in[8];
  const float* bq      = (const float*)d_in[9];
  const float* wk      = (const float*)d_in[10];
  const float* bk      = (const float*)d_in[11];
  const float* wv      = (const float*)d_in[12];
  const float* bv      = (const float*)d_in[13];
  const float* wo      = (const float*)d_in[14];
  const float* bo      = (const float*)d_in[15];
  const float* w1      = (const float*)d_in[16];
  const float* b1      = (const float*)d_in[17];
  const float* w2      = (const float*)d_in[18];
  const float* b2      = (const float*)d_in[19];
  const float* ln2_g   = (const float*)d_in[20];
  const float* ln2_b   = (const float*)d_in[21];
  const float* lnp_g   = (const float*)d_in[22];
  const float* lnp_b   = (const float*)d_in[23];
  const float* hln_g   = (const float*)d_in[24];
  const float* hln_b   = (const float*)d_in[25];
  const float* hw1     = (const float*)d_in[26];
  const float* hb1     = (const float*)d_in[27];
  const float* hw2     = (const float*)d_in[28];
  const float* hb2     = (const float*)d_in[29];

  // workspace layout
  char* w = (char*)d_ws;
  bf16*  wqkvT = (bf16*)(w);                      // 6*2304*768 bf16
  bf16*  woT   = (bf16*)(w + 21233664);           // 6*768*768
  bf16*  w1T   = (bf16*)(w + 28311552);           // 6*3072*768
  bf16*  w2T   = (bf16*)(w + 56623104);           // 6*768*3072
  bf16*  wc1T  = (bf16*)(w + 84934656);           // 768*256
  bf16*  wc2T  = (bf16*)(w + 85327872);           // 768*2304
  float* bqkv  = (float*)(w + 88866816);          // 6*2304 f32
  float* Xf    = (float*)(w + 88922112);          // 4096*768 f32
  bf16*  Xb    = (bf16*)(w + 101505024);          // 4096*768
  bf16*  qkv   = (bf16*)(w + 107796480);          // 3*4096*768 (q t-major, k t-major, v d-major)
  bf16*  CC    = (bf16*)(w + 126670848);          // 4096*768
  float* ATTN  = (float*)(w + 132962304);         // 4096*768 f32
  char*  BIG   = w + 145545216;                   // 50,331,648 shared region
  bf16*  A1  = (bf16*)(BIG);                      // 8192*256   (conv phase)
  bf16*  Y1G = (bf16*)(BIG + 4194304);            // 8192*768   (conv phase)
  bf16*  A2  = (bf16*)(BIG + 16777216);           // 4096*2304  (conv phase)
  bf16*  Hh  = (bf16*)(BIG);                      // 4096*3072  (ffn phase)
  float* FFN = (float*)(BIG + 25165824);          // 4096*768 f32 (ffn phase)
  // head phase (aliases, used only after last FFN)
  float* CLS  = (float*)(BIG);                    // 4*768
  float* HID  = (float*)(BIG + 16384);            // 4*3072
  float* LGT  = (float*)(BIG + 81920);            // 4*640
  float* PT1  = (float*)(BIG + 131072);           // 16*4*3072
  float* PT2  = (float*)(BIG + 1048576);          // 32*4*640
  float* HB2P = (float*)(BIG + 1572864);          // 640
  float* HW2P = (float*)(BIG + 1605632);          // 3072*640

  // ---- weight prep ----
  tconv<<<dim3(2, 24, 72), 256, 0, stream>>>(wq, wqkvT,            768, 64,   49152L, 1769472L, 49152L, 12);
  tconv<<<dim3(2, 24, 72), 256, 0, stream>>>(wk, wqkvT + 589824,   768, 64,   49152L, 1769472L, 49152L, 12);
  tconv<<<dim3(2, 24, 72), 256, 0, stream>>>(wv, wqkvT + 1179648,  768, 64,   49152L, 1769472L, 49152L, 12);
  tconv<<<dim3(24, 24, 6), 256, 0, stream>>>(wo, woT,              768, 768,  589824L, 589824L, 0L, 1);
  tconv<<<dim3(96, 24, 6), 256, 0, stream>>>(w1, w1T,              768, 3072, 2359296L, 2359296L, 0L, 1);
  tconv<<<dim3(24, 96, 6), 256, 0, stream>>>(w2, w2T,              3072, 768, 2359296L, 2359296L, 0L, 1);
  prep_cw<<<768,  256, 0, stream>>>(conv1_w, wc1T, 80, 256);
  prep_cw<<<6912, 256, 0, stream>>>(conv2_w, wc2T, 768, 2304);
  prep_bias<<<54, 256, 0, stream>>>(bq, bk, bv, bqkv);

  // ---- convs ----
  im2col1<<<8192, 256, 0, stream>>>(x_in, A1);
  { GP p{}; p.A = A1; p.B = wc1T; p.bias = conv1_b; p.Ob = Y1G;
    p.M = 8192; p.N = 768; p.K = 256;
    gemm_bt<128,64,2,2,EPI_GELU_BF16,1><<<dim3(64,12,1),256,0,stream>>>(p); }
  im2col2<<<36864, 256, 0, stream>>>(Y1G, A2);
  { GP p{}; p.A = A2; p.B = wc2T; p.bias = conv2_b; p.Of = Xf; p.Ob = Xb; p.aux = pos_emb;
    p.M = 4096; p.N = 768; p.K = 2304;
    gemm_bt<128,64,2,2,EPI_CONV2,1><<<dim3(32,12,1),256,0,stream>>>(p); }

  // ---- transformer layers ----
  for (int l = 0; l < 6; ++l) {
    { GP p{}; p.A = Xb; p.B = wqkvT + (long)l * 1769472; p.bias = bqkv + l * 2304;
      p.Ob = qkv; p.M = 4096; p.N = 2304; p.K = 768;
      gemm_bt<128,128,2,2,EPI_QKV,0><<<dim3(32,18,1),256,0,stream>>>(p); }
    attn_flash<<<768, 256, 0, stream>>>(qkv, CC);
    { GP p{}; p.A = CC; p.B = woT + (long)l * 589824; p.bias = bo + l * 768; p.Of = ATTN;
      p.M = 4096; p.N = 768; p.K = 768;
      gemm_bt<128,64,2,2,EPI_BIAS_F32,1><<<dim3(32,12,1),256,0,stream>>>(p); }
    ln_resid<<<4096, 256, 0, stream>>>(Xf, ATTN, ln1_g + l * 768, ln1_b + l * 768, Xf, Xb);
    { GP p{}; p.A = Xb; p.B = w1T + (long)l * 2359296; p.bias = b1 + l * 3072; p.Ob = Hh;
      p.M = 4096; p.N = 3072; p.K = 768;
      gemm_bt<128,128,2,2,EPI_RELU_BF16,0><<<dim3(32,24,1),256,0,stream>>>(p); }
    { GP p{}; p.A = Hh; p.B = w2T + (long)l * 2359296; p.bias = b2 + l * 768; p.Of = FFN;
      p.M = 4096; p.N = 768; p.K = 3072;
      gemm_bt<128,64,2,2,EPI_BIAS_F32,1><<<dim3(32,12,1),256,0,stream>>>(p); }
    ln_resid<<<4096, 256, 0, stream>>>(Xf, FFN, ln2_g + l * 768, ln2_b + l * 768, Xf, Xb);
  }

  // ---- head ----
  head_cls<<<4, 256, 0, stream>>>(Xf, lnp_g, lnp_b, hln_g, hln_b, CLS);
  prep_hw2<<<7680, 256, 0, stream>>>(hw2, hb2, HW2P, HB2P);
  mlp_part<<<dim3(24, 16), 256, 0, stream>>>(CLS, hw1, PT1, 768, 3072, 48);
  mlp_reduce<<<48, 256, 0, stream>>>(PT1, hb1, HID, 3072, 16, 1);
  mlp_part<<<dim3(5, 32), 256, 0, stream>>>(HID, HW2P, PT2, 3072, 640, 96);
  mlp_reduce<<<10, 256, 0, stream>>>(PT2, HB2P, LGT, 640, 32, 0);
  head_softmax<<<4, 256, 0, stream>>>(LGT, (float*)d_out);
}

// Round 15
// 1197.121 us; speedup vs baseline: 2.3858x; 1.0128x over previous
//
#include <hip/hip_runtime.h>
#include <hip/hip_bf16.h>

typedef __hip_bfloat16 bf16;
using v8s   = __attribute__((ext_vector_type(8))) short;
using f32x4 = __attribute__((ext_vector_type(4))) float;

#define DI __device__ __forceinline__

DI float gelu_f(float x) { return 0.5f * x * (1.f + erff(x * 0.70710678118654752f)); }

DI void g2lds16(const bf16* g, bf16* l) {
  __builtin_amdgcn_global_load_lds((const __attribute__((address_space(1))) void*)g,
                                   (__attribute__((address_space(3))) void*)l, 16, 0, 0);
}

// ---------------- block reduction helpers (256 threads, 4 waves) ----------------
DI float block_sum(float v, float* red, int tid) {
#pragma unroll
  for (int o = 32; o > 0; o >>= 1) v += __shfl_down(v, o);
  __syncthreads();
  if ((tid & 63) == 0) red[tid >> 6] = v;
  __syncthreads();
  return red[0] + red[1] + red[2] + red[3];
}
DI float block_max(float v, float* red, int tid) {
#pragma unroll
  for (int o = 32; o > 0; o >>= 1) v = fmaxf(v, __shfl_down(v, o));
  __syncthreads();
  if ((tid & 63) == 0) red[tid >> 6] = v;
  __syncthreads();
  return fmaxf(fmaxf(red[0], red[1]), fmaxf(red[2], red[3]));
}

// ---------------- weight prep ----------------
__global__ __launch_bounds__(256)
void tconv(const float* __restrict__ in, bf16* __restrict__ out,
           int R, int C, long inStrideZ, long outStrideL, long outStrideH, int zmod) {
  __shared__ float tile[32][33];
  int z = blockIdx.z;
  int lz = z / zmod, hz = z - lz * zmod;
  in  += (long)z * inStrideZ;
  out += (long)lz * outStrideL + (long)hz * outStrideH;
  int cb = blockIdx.x * 32, rb = blockIdx.y * 32;
  int tx = threadIdx.x & 31, ty = threadIdx.x >> 5;  // 32x8
#pragma unroll
  for (int i = 0; i < 32; i += 8)
    tile[ty + i][tx] = in[(long)(rb + ty + i) * C + cb + tx];
  __syncthreads();
#pragma unroll
  for (int i = 0; i < 32; i += 8)
    out[(long)(cb + ty + i) * R + rb + tx] = __float2bfloat16(tile[tx][ty + i]);
}

__global__ __launch_bounds__(256)
void prep_cw(const float* __restrict__ wsrc, bf16* __restrict__ o, int IC, int KT) {
  int idx = blockIdx.x * 256 + threadIdx.x;
  int oc = idx / KT, kp = idx - oc * KT;
  float v = 0.f;
  if (kp < IC * 3) {
    int kk = kp / IC, ic = kp - kk * IC;
    v = wsrc[(oc * IC + ic) * 3 + kk];
  }
  o[idx] = __float2bfloat16(v);
}

__global__ __launch_bounds__(256)
void prep_bias(const float* __restrict__ bq, const float* __restrict__ bk,
               const float* __restrict__ bv, float* __restrict__ o) {
  int idx = blockIdx.x * 256 + threadIdx.x;  // 6*2304
  int l = idx / 2304, n = idx - l * 2304;
  int which = n / 768, r = n - which * 768;
  const float* src = which == 0 ? bq : (which == 1 ? bk : bv);
  o[idx] = src[l * 768 + r];
}

// pad-repack head layer-2 weights: hw2 [3072][527] -> hw2p [3072][640] (zero pad)
__global__ __launch_bounds__(256)
void prep_hw2(const float* __restrict__ hw2, const float* __restrict__ hb2,
              float* __restrict__ hw2p, float* __restrict__ hb2p) {
  int idx = blockIdx.x * 256 + threadIdx.x;  // 3072*640
  int e = idx / 640, c = idx - e * 640;
  hw2p[idx] = c < 527 ? hw2[(long)e * 527 + c] : 0.f;
  if (idx < 640) hb2p[idx] = idx < 527 ? hb2[idx] : 0.f;
}

// ---------------- im2col ----------------
__global__ __launch_bounds__(256)
void im2col1(const float* __restrict__ x, bf16* __restrict__ out) {
  int idx = blockIdx.x * 256 + threadIdx.x;  // 8192*256
  int m = idx >> 8, kp = idx & 255;
  float v = 0.f;
  if (kp < 240) {
    int kk = kp / 80, ic = kp - kk * 80;
    int t = (m & 2047) + kk - 1;
    int b = m >> 11;
    if ((unsigned)t < 2048u) v = x[((long)(b * 80 + ic) << 11) + t];
  }
  out[idx] = __float2bfloat16(v);
}

__global__ __launch_bounds__(256)
void im2col2(const bf16* __restrict__ y, bf16* __restrict__ out) {
  int idx = blockIdx.x * 256 + threadIdx.x;  // 4096*2304
  int m = idx / 2304, kp = idx - m * 2304;
  int kk = kp / 768, ic = kp - kk * 768;
  int t = 2 * (m & 1023) + kk - 1;
  bf16 v = __float2bfloat16(0.f);
  if ((unsigned)t < 2048u) v = y[((long)(m >> 10) * 2048 + t) * 768 + ic];
  out[idx] = v;
}

// ---------------- GEMM: C[m][n] = sum_k A[m][k]*B[n][k]  (both bf16, K%64==0) ----------------
// Rule-21 XOR swizzle (conflicts = 0, verified r11). DBUF=1: 2-phase ping-pong
// -- for grids with 3 balanced blocks/CU already. DBUF=0: single-buffer m97
// structure -- cross-block wave overlap hides the barrier drain (m114); use
// with grids sized to an exact multiple of 256 blocks.
enum { EPI_GELU_BF16, EPI_CONV2, EPI_QKV, EPI_BIAS_F32, EPI_RELU_BF16 };

struct GP {
  const bf16* A; const bf16* B; const float* bias;
  bf16* Ob; float* Of; const float* aux;
  int M, N, K; long sA, sB, sC; int zoff;
};

template<int BM, int BN, int WM, int WN, int EPI, int DBUF>
__global__ __launch_bounds__(WM * WN * 64, 2)
void gemm_bt(GP p) {
  constexpr int WAVES = WM * WN;
  constexpr int FM = BM / WM / 16, FN = BN / WN / 16;
  __shared__ __align__(16) bf16 As0[BM * 64], Bs0[BN * 64];
  __shared__ __align__(16) bf16 As1[DBUF ? BM * 64 : 8], Bs1[DBUF ? BN * 64 : 8];
  const int tid = threadIdx.x;
  const int lane = tid & 63, wid = tid >> 6;
  const int wr = wid / WN, wc = wid - wr * WN;
  const int row0 = wr * (BM / WM), col0 = wc * (BN / WN);
  const int lr = lane & 15, lk = (lane >> 4) * 8;
  const int lrow = lane >> 3;
  const int scol = (((lane & 7) ^ (lane >> 3)) & 7) * 8;  // pre-swizzled source col
  const int rswz = (lr & 7) * 8;                          // read-side XOR
  const int z = blockIdx.z;
  const bf16* Ab = p.A + (long)z * p.sA + (long)blockIdx.x * BM * p.K;
  const bf16* Bb = p.B + (long)z * p.sB + (long)blockIdx.y * BN * p.K;
  f32x4 acc[FM][FN] = {};

  auto stage = [&](bf16* As, bf16* Bs, int kt) {
#pragma unroll
    for (int i = 0; i < BM / 8 / WAVES; ++i) {
      const int c = wid + i * WAVES;  // chunk of 8 rows (1KB)
      g2lds16(&Ab[(long)(c * 8 + lrow) * p.K + kt + scol], &As[c << 9]);
    }
#pragma unroll
    for (int i = 0; i < BN / 8 / WAVES; ++i) {
      const int c = wid + i * WAVES;
      g2lds16(&Bb[(long)(c * 8 + lrow) * p.K + kt + scol], &Bs[c << 9]);
    }
  };

  auto compute = [&](const bf16* As, const bf16* Bs) {
#pragma unroll
    for (int ks = 0; ks < 2; ++ks) {
      v8s af[FM], bf_[FN];
#pragma unroll
      for (int mi = 0; mi < FM; ++mi)
        af[mi] = *(const v8s*)&As[(row0 + mi * 16 + lr) * 64 + ((ks * 32 + lk) ^ rswz)];
#pragma unroll
      for (int ni = 0; ni < FN; ++ni)
        bf_[ni] = *(const v8s*)&Bs[(col0 + ni * 16 + lr) * 64 + ((ks * 32 + lk) ^ rswz)];
      __builtin_amdgcn_s_setprio(1);
#pragma unroll
      for (int mi = 0; mi < FM; ++mi)
#pragma unroll
        for (int ni = 0; ni < FN; ++ni)
          acc[mi][ni] = __builtin_amdgcn_mfma_f32_16x16x32_bf16(af[mi], bf_[ni], acc[mi][ni], 0, 0, 0);
      __builtin_amdgcn_s_setprio(0);
    }
  };

  if constexpr (DBUF) {
    stage(As0, Bs0, 0);
    __syncthreads();
    int kt = 0;
    while (true) {
      if (kt + 64 < p.K) stage(As1, Bs1, kt + 64);
      compute(As0, Bs0);
      __syncthreads();
      kt += 64;
      if (kt >= p.K) break;
      if (kt + 64 < p.K) stage(As0, Bs0, kt + 64);
      compute(As1, Bs1);
      __syncthreads();
      kt += 64;
      if (kt >= p.K) break;
    }
  } else {
    for (int kt = 0; kt < p.K; kt += 64) {
      __syncthreads();
      stage(As0, Bs0, kt);
      __syncthreads();
      compute(As0, Bs0);
    }
  }

  // epilogue; D: row=(lane>>4)*4+r, col=lane&15
#pragma unroll
  for (int mi = 0; mi < FM; ++mi) {
#pragma unroll
    for (int ni = 0; ni < FN; ++ni) {
#pragma unroll
      for (int r = 0; r < 4; ++r) {
        float v = acc[mi][ni][r];
        const int m = blockIdx.x * BM + row0 + mi * 16 + (lane >> 4) * 4 + r;
        const int n = blockIdx.y * BN + col0 + ni * 16 + lr;
        if constexpr (EPI == EPI_GELU_BF16) {
          p.Ob[(long)m * p.N + n] = __float2bfloat16(gelu_f(v + p.bias[n]));
        } else if constexpr (EPI == EPI_CONV2) {
          float t = gelu_f(v + p.bias[n]) + p.aux[(long)(m & 1023) * 768 + n];
          p.Of[(long)m * 768 + n] = t;
          p.Ob[(long)m * 768 + n] = __float2bfloat16(t);
        } else if constexpr (EPI == EPI_QKV) {
          float t = v + p.bias[n];
          int which = n / 768, nn = n - which * 768;
          int h = nn >> 6, d = nn & 63;
          long bh = (long)(m >> 10) * 12 + h;
          if (which < 2)
            p.Ob[(long)which * 3145728 + (bh << 16) + ((long)(m & 1023) << 6) + d] = __float2bfloat16(t);
          else
            p.Ob[6291456L + (bh << 16) + ((long)d << 10) + (m & 1023)] = __float2bfloat16(t);
        } else if constexpr (EPI == EPI_BIAS_F32) {
          p.Of[(long)m * p.N + n] = v + p.bias[n];
        } else if constexpr (EPI == EPI_RELU_BF16) {
          p.Ob[(long)m * p.N + n] = __float2bfloat16(fmaxf(v + p.bias[n], 0.f));
        }
      }
    }
  }
}

// ---------------- fused flash attention ----------------
// QBLK=64: grid 768 = exactly 3 blocks/CU. qt = blk/48, bh = blk%48
// (same-head blocks spaced 48 = 0 mod 8 -> same XCD L2). 4 waves x 16 q-rows.
// K/V dbuf + XOR swizzle; denominator via ones-MFMA; defer-max THR=8.
__global__ __launch_bounds__(256)
void attn_flash(const bf16* __restrict__ qkv, bf16* __restrict__ cc) {
  __shared__ __align__(16) bf16 Ks[2][64 * 64], Vs[2][64 * 64];
  __shared__ __align__(16) bf16 Pl[4][16 * 76];
  const int tid = threadIdx.x, lane = tid & 63, wid = tid >> 6;
  const int lr = lane & 15, lg = lane >> 4;
  const int blk = blockIdx.x;
  const int qt = blk / 48, bh = blk - qt * 48;
  const int b = bh / 12, h = bh - b * 12;
  const long qb = (long)bh << 16;
  const bf16* Qg = qkv + qb;
  const bf16* Kg = qkv + 3145728 + qb;
  const bf16* Vg = qkv + 6291456 + qb;
  const int q0 = qt * 64 + wid * 16;
  const int lrow8 = lane >> 3;
  const int scol = (((lane & 7) ^ (lane >> 3)) & 7) * 8;  // pre-swizzled source col
  const int rswz = (lr & 7) * 8;                          // read-side XOR

  v8s aq[2];
#pragma unroll
  for (int ks = 0; ks < 2; ++ks)
    aq[ks] = *(const v8s*)&Qg[(long)(q0 + lr) * 64 + ks * 32 + lg * 8];

  const short oneb = (short)0x3F80;  // bf16 1.0
  const v8s ones = {oneb, oneb, oneb, oneb, oneb, oneb, oneb, oneb};

  float mrow[4] = {-1e30f, -1e30f, -1e30f, -1e30f};
  f32x4 acc[4] = {};
  f32x4 lacc = {};
  bf16* myP = &Pl[wid][0];

  auto stageKV = [&](int buf, int kt) {
#pragma unroll
    for (int i = 0; i < 2; ++i) {
      int c = wid + i * 4;
      g2lds16(&Kg[(long)(kt + c * 8 + lrow8) * 64 + scol], &Ks[buf][c << 9]);
      g2lds16(&Vg[((long)(c * 8 + lrow8) << 10) + kt + scol], &Vs[buf][c << 9]);
    }
  };

  stageKV(0, 0);
  __syncthreads();  // buf0 staged (vmcnt drained at barrier)

  for (int it = 0; it < 16; ++it) {
    const int cur = it & 1;
    if (it + 1 < 16) stageKV(cur ^ 1, (it + 1) * 64);
    const bf16* Kc = &Ks[cur][0];
    const bf16* Vc = &Vs[cur][0];

    // S = Q K^T
    f32x4 s[4] = {};
#pragma unroll
    for (int ks = 0; ks < 2; ++ks) {
      v8s bk[4];
#pragma unroll
      for (int ni = 0; ni < 4; ++ni)
        bk[ni] = *(const v8s*)&Kc[(ni * 16 + lr) * 64 + ((ks * 32 + lg * 8) ^ rswz)];
      __builtin_amdgcn_s_setprio(1);
#pragma unroll
      for (int ni = 0; ni < 4; ++ni)
        s[ni] = __builtin_amdgcn_mfma_f32_16x16x32_bf16(aq[ks], bk[ni], s[ni], 0, 0, 0);
      __builtin_amdgcn_s_setprio(0);
    }

    // online softmax with defer-max; write P (bf16) to per-wave LDS
    float tm[4];
    bool need = false;
#pragma unroll
    for (int r = 0; r < 4; ++r) {
      float t = fmaxf(fmaxf(s[0][r], s[1][r]), fmaxf(s[2][r], s[3][r]));
#pragma unroll
      for (int o = 1; o < 16; o <<= 1) t = fmaxf(t, __shfl_xor(t, o));
      tm[r] = t;
      need = need || (t > mrow[r] + 8.f);
    }
    if (__any(need)) {
#pragma unroll
      for (int r = 0; r < 4; ++r) {
        float mn = fmaxf(mrow[r], tm[r]);
        float al = __expf(mrow[r] - mn);
        mrow[r] = mn;
        lacc[r] *= al;
#pragma unroll
        for (int ni = 0; ni < 4; ++ni) acc[ni][r] *= al;
      }
    }
#pragma unroll
    for (int r = 0; r < 4; ++r) {
      const int prow = (lg * 4 + r) * 76;
#pragma unroll
      for (int ni = 0; ni < 4; ++ni)
        myP[prow + ni * 16 + lr] = __float2bfloat16(__expf(s[ni][r] - mrow[r]));
    }

    // O += P * V ; l += P * ones  (V d-major -> contiguous B-frags)
#pragma unroll
    for (int ks = 0; ks < 2; ++ks) {
      v8s pa, bv[4];
      pa = *(const v8s*)&myP[lr * 76 + ks * 32 + lg * 8];
#pragma unroll
      for (int ni = 0; ni < 4; ++ni)
        bv[ni] = *(const v8s*)&Vc[(ni * 16 + lr) * 64 + ((ks * 32 + lg * 8) ^ rswz)];
      __builtin_amdgcn_s_setprio(1);
#pragma unroll
      for (int ni = 0; ni < 4; ++ni)
        acc[ni] = __builtin_amdgcn_mfma_f32_16x16x32_bf16(pa, bv[ni], acc[ni], 0, 0, 0);
      lacc = __builtin_amdgcn_mfma_f32_16x16x32_bf16(pa, ones, lacc, 0, 0, 0);
      __builtin_amdgcn_s_setprio(0);
    }
    __syncthreads();  // all waves done with cur; next buffer fully staged
  }

  // epilogue: normalize and write concat layout [b*1024+t][h*64+d]
#pragma unroll
  for (int ni = 0; ni < 4; ++ni)
#pragma unroll
    for (int r = 0; r < 4; ++r) {
      int row = q0 + lg * 4 + r;
      cc[((long)(b << 10) + row) * 768 + h * 64 + ni * 16 + lr] =
          __float2bfloat16(acc[ni][r] / lacc[r]);
    }
}

// ---------------- residual + LayerNorm (row=768), float4-vectorized ----------------
__global__ __launch_bounds__(256)
void ln_resid(const float* __restrict__ xin, const float* __restrict__ add,
              const float* __restrict__ g, const float* __restrict__ bb,
              float* __restrict__ xo, bf16* __restrict__ xbo) {
  __shared__ float red[4];
  long row = blockIdx.x;
  int tid = threadIdx.x;
  const f32x4* xr = (const f32x4*)(xin + row * 768);
  const f32x4* ar = (const f32x4*)(add + row * 768);
  f32x4 v = {0.f, 0.f, 0.f, 0.f};
  if (tid < 192) {
    f32x4 a = xr[tid], c = ar[tid];
    v[0] = a[0] + c[0]; v[1] = a[1] + c[1]; v[2] = a[2] + c[2]; v[3] = a[3] + c[3];
  }
  float mean = block_sum(v[0] + v[1] + v[2] + v[3], red, tid) * (1.f / 768.f);
  if (tid < 192) { v[0] -= mean; v[1] -= mean; v[2] -= mean; v[3] -= mean; }
  float sq = tid < 192 ? v[0] * v[0] + v[1] * v[1] + v[2] * v[2] + v[3] * v[3] : 0.f;
  float var = block_sum(sq, red, tid) * (1.f / 768.f);
  float rs = rsqrtf(var + 1e-5f);
  if (tid < 192) {
    f32x4 gv = ((const f32x4*)g)[tid];
    f32x4 bv = ((const f32x4*)bb)[tid];
    f32x4 o;
    o[0] = v[0] * rs * gv[0] + bv[0];
    o[1] = v[1] * rs * gv[1] + bv[1];
    o[2] = v[2] * rs * gv[2] + bv[2];
    o[3] = v[3] * rs * gv[3] + bv[3];
    ((f32x4*)(xo + row * 768))[tid] = o;
    bf16 t0 = __float2bfloat16(o[0]), t1 = __float2bfloat16(o[1]);
    bf16 t2 = __float2bfloat16(o[2]), t3 = __float2bfloat16(o[3]);
    ushort4 pk;
    pk.x = *(unsigned short*)&t0; pk.y = *(unsigned short*)&t1;
    pk.z = *(unsigned short*)&t2; pk.w = *(unsigned short*)&t3;
    *(ushort4*)&xbo[row * 768 + tid * 4] = pk;
  }
}

// ---------------- classifier head ----------------
__global__ __launch_bounds__(256)
void head_cls(const float* __restrict__ x,
              const float* __restrict__ lnpg, const float* __restrict__ lnpb,
              const float* __restrict__ hlng, const float* __restrict__ hlnb,
              float* __restrict__ cls) {
  __shared__ float red[4];
  int b = blockIdx.x, tid = threadIdx.x;
  const float* xr = x + (long)b * 1024 * 768;  // row t=0
  float v0 = xr[tid], v1 = xr[tid + 256], v2 = xr[tid + 512];
  float s = block_sum(v0 + v1 + v2, red, tid) * (1.f / 768.f);
  v0 -= s; v1 -= s; v2 -= s;
  float q = block_sum(v0 * v0 + v1 * v1 + v2 * v2, red, tid) * (1.f / 768.f);
  float r = rsqrtf(q + 1e-5f);
  v0 = v0 * r * lnpg[tid]       + lnpb[tid];
  v1 = v1 * r * lnpg[tid + 256] + lnpb[tid + 256];
  v2 = v2 * r * lnpg[tid + 512] + lnpb[tid + 512];
  s = block_sum(v0 + v1 + v2, red, tid) * (1.f / 768.f);
  v0 -= s; v1 -= s; v2 -= s;
  q = block_sum(v0 * v0 + v1 * v1 + v2 * v2, red, tid) * (1.f / 768.f);
  r = rsqrtf(q + 1e-5f);
  cls[b * 768 + tid]       = v0 * r * hlng[tid]       + hlnb[tid];
  cls[b * 768 + tid + 256] = v1 * r * hlng[tid + 256] + hlnb[tid + 256];
  cls[b * 768 + tid + 512] = v2 * r * hlng[tid + 512] + hlnb[tid + 512];
}

// split-K GEMV stage A
__global__ __launch_bounds__(256)
void mlp_part(const float* __restrict__ in, const float* __restrict__ wmat,
              float* __restrict__ part, int IN, int OUTP, int ET) {
  __shared__ float cin[4][96];
  __shared__ float red[8][32][16];
  int tid = threadIdx.x;
  int tx = tid & 31, ty = tid >> 5;
  int e0 = blockIdx.y * ET;
  for (int i = tid; i < 4 * ET; i += 256) {
    int b = i / ET, el = i - b * ET;
    cin[b][el] = in[b * IN + e0 + el];
  }
  __syncthreads();
  f32x4 acc[4] = {};
  const float* wp = wmat + (long)e0 * OUTP + (blockIdx.x * 32 + tx) * 4;
  const int iters = ET >> 3;
  for (int i = 0; i < iters; ++i) {
    int el = ty + i * 8;
    f32x4 w = *(const f32x4*)(wp + (long)el * OUTP);
#pragma unroll
    for (int b = 0; b < 4; ++b) acc[b] += cin[b][el] * w;
  }
#pragma unroll
  for (int b = 0; b < 4; ++b) *(f32x4*)&red[ty][tx][b * 4] = acc[b];
  __syncthreads();
  if (tid < 128) {
    int rx = tid & 31, b = tid >> 5;
    f32x4 s = {};
#pragma unroll
    for (int t = 0; t < 8; ++t) s += *(const f32x4*)&red[t][rx][b * 4];
    *(f32x4*)&part[((long)blockIdx.y * 4 + b) * OUTP + (blockIdx.x * 32 + rx) * 4] = s;
  }
}

__global__ __launch_bounds__(256)
void mlp_reduce(const float* __restrict__ part, const float* __restrict__ bias,
                float* __restrict__ out, int OUTP, int S, int relu) {
  int idx = blockIdx.x * 256 + threadIdx.x;
  int b = idx / OUTP, j = idx - b * OUTP;
  float s = bias[j];
  for (int t = 0; t < S; ++t) s += part[((long)t * 4 + b) * OUTP + j];
  out[idx] = relu ? fmaxf(s, 0.f) : s;
}

// C=527 logits in [4][640] padded rows
__global__ __launch_bounds__(256)
void head_softmax(const float* __restrict__ lg, float* __restrict__ out) {
  __shared__ float red[4];
  int b = blockIdx.x, tid = threadIdx.x;
  const float* r = lg + (long)b * 640;
  float v0 = r[tid];
  float v1 = tid + 256 < 527 ? r[tid + 256] : -1e30f;
  float v2 = tid + 512 < 527 ? r[tid + 512] : -1e30f;
  float mx = block_max(fmaxf(v0, fmaxf(v1, v2)), red, tid);
  float e0 = __expf(v0 - mx);
  float e1 = tid + 256 < 527 ? __expf(v1 - mx) : 0.f;
  float e2 = tid + 512 < 527 ? __expf(v2 - mx) : 0.f;
  float sm = block_sum(e0 + e1 + e2, red, tid);
  float inv = 1.f / sm;
  out[(long)b * 527 + tid] = e0 * inv;
  if (tid + 256 < 527) out[(long)b * 527 + tid + 256] = e1 * inv;
  if (tid + 512 < 527) out[(long)b * 527 + tid + 512] = e2 * inv;
}

// ---------------- launcher ----------------
extern "C" void kernel_launch(void* const* d_in, const int* in_sizes, int n_in,
                              void* d_out, int out_size, void* d_ws, size_t ws_size,
                              hipStream_t stream) {
  const float* x_in    = (const float*)d_in[0];
  const float* conv1_w = (const float*)d_in[1];
  const float* conv1_b = (const float*)d_in[2];
  const float* conv2_w = (const float*)d_in[3];
  const float* conv2_b = (const float*)d_in[4];
  const float* pos_emb = (const float*)d_in[5];
  const float* ln1_g   = (const float*)d_in[6];
  const float* ln1_b   = (const float*)d_in[7];
  const float* wq      = (const float*)d_in[8];
  const float* bq      = (const float*)d_in[9];
  const float* wk      = (const float*)d_in[10];
  const float* bk      = (const float*)d_in[11];
  const float* wv      = (const float*)d_in[12];
  const float* bv      = (const float*)d_in[13];
  const float* wo      = (const float*)d_in[14];
  const float* bo      = (const float*)d_in[15];
  const float* w1      = (const float*)d_in[16];
  const float* b1      = (const float*)d_in[17];
  const float* w2      = (const float*)d_in[18];
  const float* b2      = (const float*)d_in[19];
  const float* ln2_g   = (const float*)d_in[20];
  const float* ln2_b   = (const float*)d_in[21];
  const float* lnp_g   = (const float*)d_in[22];
  const float* lnp_b   = (const float*)d_in[23];
  const float* hln_g   = (const float*)d_in[24];
  const float* hln_b   = (const float*)d_in[25];
  const float* hw1     = (const float*)d_in[26];
  const float* hb1     = (const float*)d_in[27];
  const float* hw2     = (const float*)d_in[28];
  const float* hb2     = (const float*)d_in[29];

  // workspace layout
  char* w = (char*)d_ws;
  bf16*  wqkvT = (bf16*)(w);                      // 6*2304*768 bf16
  bf16*  woT   = (bf16*)(w + 21233664);           // 6*768*768
  bf16*  w1T   = (bf16*)(w + 28311552);           // 6*3072*768
  bf16*  w2T   = (bf16*)(w + 56623104);           // 6*768*3072
  bf16*  wc1T  = (bf16*)(w + 84934656);           // 768*256
  bf16*  wc2T  = (bf16*)(w + 85327872);           // 768*2304
  float* bqkv  = (float*)(w + 88866816);          // 6*2304 f32
  float* Xf    = (float*)(w + 88922112);          // 4096*768 f32
  bf16*  Xb    = (bf16*)(w + 101505024);          // 4096*768
  bf16*  qkv   = (bf16*)(w + 107796480);          // 3*4096*768 (q t-major, k t-major, v d-major)
  bf16*  CC    = (bf16*)(w + 126670848);          // 4096*768
  float* ATTN  = (float*)(w + 132962304);         // 4096*768 f32
  char*  BIG   = w + 145545216;                   // 50,331,648 shared region
  bf16*  A1  = (bf16*)(BIG);                      // 8192*256   (conv phase)
  bf16*  Y1G = (bf16*)(BIG + 4194304);            // 8192*768   (conv phase)
  bf16*  A2  = (bf16*)(BIG + 16777216);           // 4096*2304  (conv phase)
  bf16*  Hh  = (bf16*)(BIG);                      // 4096*3072  (ffn phase)
  float* FFN = (float*)(BIG + 25165824);          // 4096*768 f32 (ffn phase)
  // head phase (aliases, used only after last FFN)
  float* CLS  = (float*)(BIG);                    // 4*768
  float* HID  = (float*)(BIG + 16384);            // 4*3072
  float* LGT  = (float*)(BIG + 81920);            // 4*640
  float* PT1  = (float*)(BIG + 131072);           // 16*4*3072
  float* PT2  = (float*)(BIG + 1048576);          // 32*4*640
  float* HB2P = (float*)(BIG + 1572864);          // 640
  float* HW2P = (float*)(BIG + 1605632);          // 3072*640

  // ---- weight prep ----
  tconv<<<dim3(2, 24, 72), 256, 0, stream>>>(wq, wqkvT,            768, 64,   49152L, 1769472L, 49152L, 12);
  tconv<<<dim3(2, 24, 72), 256, 0, stream>>>(wk, wqkvT + 589824,   768, 64,   49152L, 1769472L, 49152L, 12);
  tconv<<<dim3(2, 24, 72), 256, 0, stream>>>(wv, wqkvT + 1179648,  768, 64,   49152L, 1769472L, 49152L, 12);
  tconv<<<dim3(24, 24, 6), 256, 0, stream>>>(wo, woT,              768, 768,  589824L, 589824L, 0L, 1);
  tconv<<<dim3(96, 24, 6), 256, 0, stream>>>(w1, w1T,              768, 3072, 2359296L, 2359296L, 0L, 1);
  tconv<<<dim3(24, 96, 6), 256, 0, stream>>>(w2, w2T,              3072, 768, 2359296L, 2359296L, 0L, 1);
  prep_cw<<<768,  256, 0, stream>>>(conv1_w, wc1T, 80, 256);
  prep_cw<<<6912, 256, 0, stream>>>(conv2_w, wc2T, 768, 2304);
  prep_bias<<<54, 256, 0, stream>>>(bq, bk, bv, bqkv);

  // ---- convs ----
  im2col1<<<8192, 256, 0, stream>>>(x_in, A1);
  { GP p{}; p.A = A1; p.B = wc1T; p.bias = conv1_b; p.Ob = Y1G;
    p.M = 8192; p.N = 768; p.K = 256;
    gemm_bt<128,64,2,2,EPI_GELU_BF16,1><<<dim3(64,12,1),256,0,stream>>>(p); }
  im2col2<<<36864, 256, 0, stream>>>(Y1G, A2);
  { GP p{}; p.A = A2; p.B = wc2T; p.bias = conv2_b; p.Of = Xf; p.Ob = Xb; p.aux = pos_emb;
    p.M = 4096; p.N = 768; p.K = 2304;
    gemm_bt<64,64,2,2,EPI_CONV2,0><<<dim3(64,12,1),256,0,stream>>>(p); }

  // ---- transformer layers ----
  for (int l = 0; l < 6; ++l) {
    { GP p{}; p.A = Xb; p.B = wqkvT + (long)l * 1769472; p.bias = bqkv + l * 2304;
      p.Ob = qkv; p.M = 4096; p.N = 2304; p.K = 768;
      gemm_bt<128,128,2,2,EPI_QKV,0><<<dim3(32,18,1),256,0,stream>>>(p); }
    attn_flash<<<768, 256, 0, stream>>>(qkv, CC);
    { GP p{}; p.A = CC; p.B = woT + (long)l * 589824; p.bias = bo + l * 768; p.Of = ATTN;
      p.M = 4096; p.N = 768; p.K = 768;
      gemm_bt<64,64,2,2,EPI_BIAS_F32,0><<<dim3(64,12,1),256,0,stream>>>(p); }
    ln_resid<<<4096, 256, 0, stream>>>(Xf, ATTN, ln1_g + l * 768, ln1_b + l * 768, Xf, Xb);
    { GP p{}; p.A = Xb; p.B = w1T + (long)l * 2359296; p.bias = b1 + l * 3072; p.Ob = Hh;
      p.M = 4096; p.N = 3072; p.K = 768;
      gemm_bt<128,128,2,2,EPI_RELU_BF16,0><<<dim3(32,24,1),256,0,stream>>>(p); }
    { GP p{}; p.A = Hh; p.B = w2T + (long)l * 2359296; p.bias = b2 + l * 768; p.Of = FFN;
      p.M = 4096; p.N = 768; p.K = 3072;
      gemm_bt<64,64,2,2,EPI_BIAS_F32,0><<<dim3(64,12,1),256,0,stream>>>(p); }
    ln_resid<<<4096, 256, 0, stream>>>(Xf, FFN, ln2_g + l * 768, ln2_b + l * 768, Xf, Xb);
  }

  // ---- head ----
  head_cls<<<4, 256, 0, stream>>>(Xf, lnp_g, lnp_b, hln_g, hln_b, CLS);
  prep_hw2<<<7680, 256, 0, stream>>>(hw2, hb2, HW2P, HB2P);
  mlp_part<<<dim3(24, 16), 256, 0, stream>>>(CLS, hw1, PT1, 768, 3072, 48);
  mlp_reduce<<<48, 256, 0, stream>>>(PT1, hb1, HID, 3072, 16, 1);
  mlp_part<<<dim3(5, 32), 256, 0, stream>>>(HID, HW2P, PT2, 3072, 640, 96);
  mlp_reduce<<<10, 256, 0, stream>>>(PT2, HB2P, LGT, 640, 32, 0);
  head_softmax<<<4, 256, 0, stream>>>(LGT, (float*)d_out);
}

// Round 16
// 1125.231 us; speedup vs baseline: 2.5382x; 1.0639x over previous
//
#include <hip/hip_runtime.h>
#include <hip/hip_bf16.h>

typedef __hip_bfloat16 bf16;
using v8s   = __attribute__((ext_vector_type(8))) short;
using f32x4 = __attribute__((ext_vector_type(4))) float;

#define DI __device__ __forceinline__

DI float gelu_f(float x) { return 0.5f * x * (1.f + erff(x * 0.70710678118654752f)); }

DI void g2lds16(const bf16* g, bf16* l) {
  __builtin_amdgcn_global_load_lds((const __attribute__((address_space(1))) void*)g,
                                   (__attribute__((address_space(3))) void*)l, 16, 0, 0);
}

// ---------------- block reduction helpers (256 threads, 4 waves) ----------------
DI float block_sum(float v, float* red, int tid) {
#pragma unroll
  for (int o = 32; o > 0; o >>= 1) v += __shfl_down(v, o);
  __syncthreads();
  if ((tid & 63) == 0) red[tid >> 6] = v;
  __syncthreads();
  return red[0] + red[1] + red[2] + red[3];
}
DI float block_max(float v, float* red, int tid) {
#pragma unroll
  for (int o = 32; o > 0; o >>= 1) v = fmaxf(v, __shfl_down(v, o));
  __syncthreads();
  if ((tid & 63) == 0) red[tid >> 6] = v;
  __syncthreads();
  return fmaxf(fmaxf(red[0], red[1]), fmaxf(red[2], red[3]));
}

// ---------------- weight prep ----------------
__global__ __launch_bounds__(256)
void tconv(const float* __restrict__ in, bf16* __restrict__ out,
           int R, int C, long inStrideZ, long outStrideL, long outStrideH, int zmod) {
  __shared__ float tile[32][33];
  int z = blockIdx.z;
  int lz = z / zmod, hz = z - lz * zmod;
  in  += (long)z * inStrideZ;
  out += (long)lz * outStrideL + (long)hz * outStrideH;
  int cb = blockIdx.x * 32, rb = blockIdx.y * 32;
  int tx = threadIdx.x & 31, ty = threadIdx.x >> 5;  // 32x8
#pragma unroll
  for (int i = 0; i < 32; i += 8)
    tile[ty + i][tx] = in[(long)(rb + ty + i) * C + cb + tx];
  __syncthreads();
#pragma unroll
  for (int i = 0; i < 32; i += 8)
    out[(long)(cb + ty + i) * R + rb + tx] = __float2bfloat16(tile[tx][ty + i]);
}

__global__ __launch_bounds__(256)
void prep_cw(const float* __restrict__ wsrc, bf16* __restrict__ o, int IC, int KT) {
  int idx = blockIdx.x * 256 + threadIdx.x;
  int oc = idx / KT, kp = idx - oc * KT;
  float v = 0.f;
  if (kp < IC * 3) {
    int kk = kp / IC, ic = kp - kk * IC;
    v = wsrc[(oc * IC + ic) * 3 + kk];
  }
  o[idx] = __float2bfloat16(v);
}

__global__ __launch_bounds__(256)
void prep_bias(const float* __restrict__ bq, const float* __restrict__ bk,
               const float* __restrict__ bv, float* __restrict__ o) {
  int idx = blockIdx.x * 256 + threadIdx.x;  // 6*2304
  int l = idx / 2304, n = idx - l * 2304;
  int which = n / 768, r = n - which * 768;
  const float* src = which == 0 ? bq : (which == 1 ? bk : bv);
  o[idx] = src[l * 768 + r];
}

// pad-repack head layer-2 weights: hw2 [3072][527] -> hw2p [3072][640] (zero pad)
__global__ __launch_bounds__(256)
void prep_hw2(const float* __restrict__ hw2, const float* __restrict__ hb2,
              float* __restrict__ hw2p, float* __restrict__ hb2p) {
  int idx = blockIdx.x * 256 + threadIdx.x;  // 3072*640
  int e = idx / 640, c = idx - e * 640;
  hw2p[idx] = c < 527 ? hw2[(long)e * 527 + c] : 0.f;
  if (idx < 640) hb2p[idx] = idx < 527 ? hb2[idx] : 0.f;
}

// ---------------- im2col ----------------
__global__ __launch_bounds__(256)
void im2col1(const float* __restrict__ x, bf16* __restrict__ out) {
  int idx = blockIdx.x * 256 + threadIdx.x;  // 8192*256
  int m = idx >> 8, kp = idx & 255;
  float v = 0.f;
  if (kp < 240) {
    int kk = kp / 80, ic = kp - kk * 80;
    int t = (m & 2047) + kk - 1;
    int b = m >> 11;
    if ((unsigned)t < 2048u) v = x[((long)(b * 80 + ic) << 11) + t];
  }
  out[idx] = __float2bfloat16(v);
}

__global__ __launch_bounds__(256)
void im2col2(const bf16* __restrict__ y, bf16* __restrict__ out) {
  int idx = blockIdx.x * 256 + threadIdx.x;  // 4096*2304
  int m = idx / 2304, kp = idx - m * 2304;
  int kk = kp / 768, ic = kp - kk * 768;
  int t = 2 * (m & 1023) + kk - 1;
  bf16 v = __float2bfloat16(0.f);
  if ((unsigned)t < 2048u) v = y[((long)(m >> 10) * 2048 + t) * 768 + ic];
  out[idx] = v;
}

// ---------------- GEMM: C[m][n] = sum_k A[m][k]*B[n][k]  (both bf16, K%64==0) ----------------
// Rule-21 XOR swizzle (conflicts = 0, verified r11). DBUF=1: 2-phase ping-pong.
// DBUF=0: single-buffer m97 structure -- cross-block wave overlap hides the
// barrier drain (m114); use with grids sized to exact multiples of 256 blocks.
enum { EPI_GELU_BF16, EPI_CONV2, EPI_QKV, EPI_BIAS_F32, EPI_RELU_BF16 };

struct GP {
  const bf16* A; const bf16* B; const float* bias;
  bf16* Ob; float* Of; const float* aux;
  int M, N, K; long sA, sB, sC; int zoff;
};

template<int BM, int BN, int WM, int WN, int EPI, int DBUF>
__global__ __launch_bounds__(WM * WN * 64, 2)
void gemm_bt(GP p) {
  constexpr int WAVES = WM * WN;
  constexpr int FM = BM / WM / 16, FN = BN / WN / 16;
  __shared__ __align__(16) bf16 As0[BM * 64], Bs0[BN * 64];
  __shared__ __align__(16) bf16 As1[DBUF ? BM * 64 : 8], Bs1[DBUF ? BN * 64 : 8];
  const int tid = threadIdx.x;
  const int lane = tid & 63, wid = tid >> 6;
  const int wr = wid / WN, wc = wid - wr * WN;
  const int row0 = wr * (BM / WM), col0 = wc * (BN / WN);
  const int lr = lane & 15, lk = (lane >> 4) * 8;
  const int lrow = lane >> 3;
  const int scol = (((lane & 7) ^ (lane >> 3)) & 7) * 8;  // pre-swizzled source col
  const int rswz = (lr & 7) * 8;                          // read-side XOR
  const int z = blockIdx.z;
  const bf16* Ab = p.A + (long)z * p.sA + (long)blockIdx.x * BM * p.K;
  const bf16* Bb = p.B + (long)z * p.sB + (long)blockIdx.y * BN * p.K;
  f32x4 acc[FM][FN] = {};

  auto stage = [&](bf16* As, bf16* Bs, int kt) {
#pragma unroll
    for (int i = 0; i < BM / 8 / WAVES; ++i) {
      const int c = wid + i * WAVES;  // chunk of 8 rows (1KB)
      g2lds16(&Ab[(long)(c * 8 + lrow) * p.K + kt + scol], &As[c << 9]);
    }
#pragma unroll
    for (int i = 0; i < BN / 8 / WAVES; ++i) {
      const int c = wid + i * WAVES;
      g2lds16(&Bb[(long)(c * 8 + lrow) * p.K + kt + scol], &Bs[c << 9]);
    }
  };

  auto compute = [&](const bf16* As, const bf16* Bs) {
#pragma unroll
    for (int ks = 0; ks < 2; ++ks) {
      v8s af[FM], bf_[FN];
#pragma unroll
      for (int mi = 0; mi < FM; ++mi)
        af[mi] = *(const v8s*)&As[(row0 + mi * 16 + lr) * 64 + ((ks * 32 + lk) ^ rswz)];
#pragma unroll
      for (int ni = 0; ni < FN; ++ni)
        bf_[ni] = *(const v8s*)&Bs[(col0 + ni * 16 + lr) * 64 + ((ks * 32 + lk) ^ rswz)];
      __builtin_amdgcn_s_setprio(1);
#pragma unroll
      for (int mi = 0; mi < FM; ++mi)
#pragma unroll
        for (int ni = 0; ni < FN; ++ni)
          acc[mi][ni] = __builtin_amdgcn_mfma_f32_16x16x32_bf16(af[mi], bf_[ni], acc[mi][ni], 0, 0, 0);
      __builtin_amdgcn_s_setprio(0);
    }
  };

  if constexpr (DBUF) {
    stage(As0, Bs0, 0);
    __syncthreads();
    int kt = 0;
    while (true) {
      if (kt + 64 < p.K) stage(As1, Bs1, kt + 64);
      compute(As0, Bs0);
      __syncthreads();
      kt += 64;
      if (kt >= p.K) break;
      if (kt + 64 < p.K) stage(As0, Bs0, kt + 64);
      compute(As1, Bs1);
      __syncthreads();
      kt += 64;
      if (kt >= p.K) break;
    }
  } else {
    for (int kt = 0; kt < p.K; kt += 64) {
      __syncthreads();
      stage(As0, Bs0, kt);
      __syncthreads();
      compute(As0, Bs0);
    }
  }

  // epilogue; D: row=(lane>>4)*4+r, col=lane&15
#pragma unroll
  for (int mi = 0; mi < FM; ++mi) {
#pragma unroll
    for (int ni = 0; ni < FN; ++ni) {
#pragma unroll
      for (int r = 0; r < 4; ++r) {
        float v = acc[mi][ni][r];
        const int m = blockIdx.x * BM + row0 + mi * 16 + (lane >> 4) * 4 + r;
        const int n = blockIdx.y * BN + col0 + ni * 16 + lr;
        if constexpr (EPI == EPI_GELU_BF16) {
          p.Ob[(long)m * p.N + n] = __float2bfloat16(gelu_f(v + p.bias[n]));
        } else if constexpr (EPI == EPI_CONV2) {
          float t = gelu_f(v + p.bias[n]) + p.aux[(long)(m & 1023) * 768 + n];
          p.Of[(long)m * 768 + n] = t;
          p.Ob[(long)m * 768 + n] = __float2bfloat16(t);
        } else if constexpr (EPI == EPI_QKV) {
          float t = v + p.bias[n];
          int which = n / 768, nn = n - which * 768;
          int h = nn >> 6, d = nn & 63;
          long bh = (long)(m >> 10) * 12 + h;
          if (which < 2)
            p.Ob[(long)which * 3145728 + (bh << 16) + ((long)(m & 1023) << 6) + d] = __float2bfloat16(t);
          else
            p.Ob[6291456L + (bh << 16) + ((long)d << 10) + (m & 1023)] = __float2bfloat16(t);
        } else if constexpr (EPI == EPI_BIAS_F32) {
          p.Of[(long)m * p.N + n] = v + p.bias[n];
        } else if constexpr (EPI == EPI_RELU_BF16) {
          p.Ob[(long)m * p.N + n] = __float2bfloat16(fmaxf(v + p.bias[n], 0.f));
        }
      }
    }
  }
}

// ---------------- fused flash attention ----------------
// QBLK=64: grid 768. qt = blk/48, bh = blk%48 (same-head blocks spaced 48 = 0
// mod 8 -> same XCD L2). 4 waves x 16 q-rows. K/V dbuf + XOR swizzle;
// denominator via ones-MFMA; defer-max THR=8 with LANE-LOCAL guard (full
// 16-shfl max tree only when some lane's local max exceeds mrow+8 -- P stays
// bounded by e^8 either way). P in stride-64 XOR-swizzled LDS:
// addr = row*64 + (col ^ ((row&7)*8)), same involution write & read ->
// LDS total exactly 40KB -> 4 blocks/CU (was 3 at 42.5KB).
__global__ __launch_bounds__(256)
void attn_flash(const bf16* __restrict__ qkv, bf16* __restrict__ cc) {
  __shared__ __align__(16) bf16 Ks[2][64 * 64], Vs[2][64 * 64];
  __shared__ __align__(16) bf16 Pl[4][16 * 64];
  const int tid = threadIdx.x, lane = tid & 63, wid = tid >> 6;
  const int lr = lane & 15, lg = lane >> 4;
  const int blk = blockIdx.x;
  const int qt = blk / 48, bh = blk - qt * 48;
  const int b = bh / 12, h = bh - b * 12;
  const long qb = (long)bh << 16;
  const bf16* Qg = qkv + qb;
  const bf16* Kg = qkv + 3145728 + qb;
  const bf16* Vg = qkv + 6291456 + qb;
  const int q0 = qt * 64 + wid * 16;
  const int lrow8 = lane >> 3;
  const int scol = (((lane & 7) ^ (lane >> 3)) & 7) * 8;  // pre-swizzled source col
  const int rswz = (lr & 7) * 8;                          // read-side XOR

  v8s aq[2];
#pragma unroll
  for (int ks = 0; ks < 2; ++ks)
    aq[ks] = *(const v8s*)&Qg[(long)(q0 + lr) * 64 + ks * 32 + lg * 8];

  const short oneb = (short)0x3F80;  // bf16 1.0
  const v8s ones = {oneb, oneb, oneb, oneb, oneb, oneb, oneb, oneb};

  float mrow[4] = {-1e30f, -1e30f, -1e30f, -1e30f};
  f32x4 acc[4] = {};
  f32x4 lacc = {};
  bf16* myP = &Pl[wid][0];

  auto stageKV = [&](int buf, int kt) {
#pragma unroll
    for (int i = 0; i < 2; ++i) {
      int c = wid + i * 4;
      g2lds16(&Kg[(long)(kt + c * 8 + lrow8) * 64 + scol], &Ks[buf][c << 9]);
      g2lds16(&Vg[((long)(c * 8 + lrow8) << 10) + kt + scol], &Vs[buf][c << 9]);
    }
  };

  stageKV(0, 0);
  __syncthreads();  // buf0 staged (vmcnt drained at barrier)

  for (int it = 0; it < 16; ++it) {
    const int cur = it & 1;
    if (it + 1 < 16) stageKV(cur ^ 1, (it + 1) * 64);
    const bf16* Kc = &Ks[cur][0];
    const bf16* Vc = &Vs[cur][0];

    // S = Q K^T
    f32x4 s[4] = {};
#pragma unroll
    for (int ks = 0; ks < 2; ++ks) {
      v8s bk[4];
#pragma unroll
      for (int ni = 0; ni < 4; ++ni)
        bk[ni] = *(const v8s*)&Kc[(ni * 16 + lr) * 64 + ((ks * 32 + lg * 8) ^ rswz)];
      __builtin_amdgcn_s_setprio(1);
#pragma unroll
      for (int ni = 0; ni < 4; ++ni)
        s[ni] = __builtin_amdgcn_mfma_f32_16x16x32_bf16(aq[ks], bk[ni], s[ni], 0, 0, 0);
      __builtin_amdgcn_s_setprio(0);
    }

    // online softmax, defer-max with lane-local guard
    float tloc[4];
    bool need = false;
#pragma unroll
    for (int r = 0; r < 4; ++r) {
      tloc[r] = fmaxf(fmaxf(s[0][r], s[1][r]), fmaxf(s[2][r], s[3][r]));
      need = need || (tloc[r] > mrow[r] + 8.f);
    }
    if (__any(need)) {
#pragma unroll
      for (int r = 0; r < 4; ++r) {
        float t = tloc[r];
#pragma unroll
        for (int o = 1; o < 16; o <<= 1) t = fmaxf(t, __shfl_xor(t, o));
        float mn = fmaxf(mrow[r], t);
        float al = __expf(mrow[r] - mn);
        mrow[r] = mn;
        lacc[r] *= al;
#pragma unroll
        for (int ni = 0; ni < 4; ++ni) acc[ni][r] *= al;
      }
    }
#pragma unroll
    for (int r = 0; r < 4; ++r) {
      const int row = lg * 4 + r;
      const int prow = row * 64, psw = (row & 7) * 8;
#pragma unroll
      for (int ni = 0; ni < 4; ++ni)
        myP[prow + ((ni * 16 + lr) ^ psw)] = __float2bfloat16(__expf(s[ni][r] - mrow[r]));
    }

    // O += P * V ; l += P * ones  (V d-major -> contiguous B-frags)
#pragma unroll
    for (int ks = 0; ks < 2; ++ks) {
      v8s pa, bv[4];
      pa = *(const v8s*)&myP[lr * 64 + ((ks * 32 + lg * 8) ^ ((lr & 7) * 8))];
#pragma unroll
      for (int ni = 0; ni < 4; ++ni)
        bv[ni] = *(const v8s*)&Vc[(ni * 16 + lr) * 64 + ((ks * 32 + lg * 8) ^ rswz)];
      __builtin_amdgcn_s_setprio(1);
#pragma unroll
      for (int ni = 0; ni < 4; ++ni)
        acc[ni] = __builtin_amdgcn_mfma_f32_16x16x32_bf16(pa, bv[ni], acc[ni], 0, 0, 0);
      lacc = __builtin_amdgcn_mfma_f32_16x16x32_bf16(pa, ones, lacc, 0, 0, 0);
      __builtin_amdgcn_s_setprio(0);
    }
    __syncthreads();  // all waves done with cur; next buffer fully staged
  }

  // epilogue: normalize and write concat layout [b*1024+t][h*64+d]
#pragma unroll
  for (int ni = 0; ni < 4; ++ni)
#pragma unroll
    for (int r = 0; r < 4; ++r) {
      int row = q0 + lg * 4 + r;
      cc[((long)(b << 10) + row) * 768 + h * 64 + ni * 16 + lr] =
          __float2bfloat16(acc[ni][r] / lacc[r]);
    }
}

// ---------------- residual + LayerNorm (row=768), float4-vectorized ----------------
__global__ __launch_bounds__(256)
void ln_resid(const float* __restrict__ xin, const float* __restrict__ add,
              const float* __restrict__ g, const float* __restrict__ bb,
              float* __restrict__ xo, bf16* __restrict__ xbo) {
  __shared__ float red[4];
  long row = blockIdx.x;
  int tid = threadIdx.x;
  const f32x4* xr = (const f32x4*)(xin + row * 768);
  const f32x4* ar = (const f32x4*)(add + row * 768);
  f32x4 v = {0.f, 0.f, 0.f, 0.f};
  if (tid < 192) {
    f32x4 a = xr[tid], c = ar[tid];
    v[0] = a[0] + c[0]; v[1] = a[1] + c[1]; v[2] = a[2] + c[2]; v[3] = a[3] + c[3];
  }
  float mean = block_sum(v[0] + v[1] + v[2] + v[3], red, tid) * (1.f / 768.f);
  if (tid < 192) { v[0] -= mean; v[1] -= mean; v[2] -= mean; v[3] -= mean; }
  float sq = tid < 192 ? v[0] * v[0] + v[1] * v[1] + v[2] * v[2] + v[3] * v[3] : 0.f;
  float var = block_sum(sq, red, tid) * (1.f / 768.f);
  float rs = rsqrtf(var + 1e-5f);
  if (tid < 192) {
    f32x4 gv = ((const f32x4*)g)[tid];
    f32x4 bv = ((const f32x4*)bb)[tid];
    f32x4 o;
    o[0] = v[0] * rs * gv[0] + bv[0];
    o[1] = v[1] * rs * gv[1] + bv[1];
    o[2] = v[2] * rs * gv[2] + bv[2];
    o[3] = v[3] * rs * gv[3] + bv[3];
    ((f32x4*)(xo + row * 768))[tid] = o;
    bf16 t0 = __float2bfloat16(o[0]), t1 = __float2bfloat16(o[1]);
    bf16 t2 = __float2bfloat16(o[2]), t3 = __float2bfloat16(o[3]);
    ushort4 pk;
    pk.x = *(unsigned short*)&t0; pk.y = *(unsigned short*)&t1;
    pk.z = *(unsigned short*)&t2; pk.w = *(unsigned short*)&t3;
    *(ushort4*)&xbo[row * 768 + tid * 4] = pk;
  }
}

// ---------------- classifier head ----------------
__global__ __launch_bounds__(256)
void head_cls(const float* __restrict__ x,
              const float* __restrict__ lnpg, const float* __restrict__ lnpb,
              const float* __restrict__ hlng, const float* __restrict__ hlnb,
              float* __restrict__ cls) {
  __shared__ float red[4];
  int b = blockIdx.x, tid = threadIdx.x;
  const float* xr = x + (long)b * 1024 * 768;  // row t=0
  float v0 = xr[tid], v1 = xr[tid + 256], v2 = xr[tid + 512];
  float s = block_sum(v0 + v1 + v2, red, tid) * (1.f / 768.f);
  v0 -= s; v1 -= s; v2 -= s;
  float q = block_sum(v0 * v0 + v1 * v1 + v2 * v2, red, tid) * (1.f / 768.f);
  float r = rsqrtf(q + 1e-5f);
  v0 = v0 * r * lnpg[tid]       + lnpb[tid];
  v1 = v1 * r * lnpg[tid + 256] + lnpb[tid + 256];
  v2 = v2 * r * lnpg[tid + 512] + lnpb[tid + 512];
  s = block_sum(v0 + v1 + v2, red, tid) * (1.f / 768.f);
  v0 -= s; v1 -= s; v2 -= s;
  q = block_sum(v0 * v0 + v1 * v1 + v2 * v2, red, tid) * (1.f / 768.f);
  r = rsqrtf(q + 1e-5f);
  cls[b * 768 + tid]       = v0 * r * hlng[tid]       + hlnb[tid];
  cls[b * 768 + tid + 256] = v1 * r * hlng[tid + 256] + hlnb[tid + 256];
  cls[b * 768 + tid + 512] = v2 * r * hlng[tid + 512] + hlnb[tid + 512];
}

// split-K GEMV stage A
__global__ __launch_bounds__(256)
void mlp_part(const float* __restrict__ in, const float* __restrict__ wmat,
              float* __restrict__ part, int IN, int OUTP, int ET) {
  __shared__ float cin[4][96];
  __shared__ float red[8][32][16];
  int tid = threadIdx.x;
  int tx = tid & 31, ty = tid >> 5;
  int e0 = blockIdx.y * ET;
  for (int i = tid; i < 4 * ET; i += 256) {
    int b = i / ET, el = i - b * ET;
    cin[b][el] = in[b * IN + e0 + el];
  }
  __syncthreads();
  f32x4 acc[4] = {};
  const float* wp = wmat + (long)e0 * OUTP + (blockIdx.x * 32 + tx) * 4;
  const int iters = ET >> 3;
  for (int i = 0; i < iters; ++i) {
    int el = ty + i * 8;
    f32x4 w = *(const f32x4*)(wp + (long)el * OUTP);
#pragma unroll
    for (int b = 0; b < 4; ++b) acc[b] += cin[b][el] * w;
  }
#pragma unroll
  for (int b = 0; b < 4; ++b) *(f32x4*)&red[ty][tx][b * 4] = acc[b];
  __syncthreads();
  if (tid < 128) {
    int rx = tid & 31, b = tid >> 5;
    f32x4 s = {};
#pragma unroll
    for (int t = 0; t < 8; ++t) s += *(const f32x4*)&red[t][rx][b * 4];
    *(f32x4*)&part[((long)blockIdx.y * 4 + b) * OUTP + (blockIdx.x * 32 + rx) * 4] = s;
  }
}

__global__ __launch_bounds__(256)
void mlp_reduce(const float* __restrict__ part, const float* __restrict__ bias,
                float* __restrict__ out, int OUTP, int S, int relu) {
  int idx = blockIdx.x * 256 + threadIdx.x;
  int b = idx / OUTP, j = idx - b * OUTP;
  float s = bias[j];
  for (int t = 0; t < S; ++t) s += part[((long)t * 4 + b) * OUTP + j];
  out[idx] = relu ? fmaxf(s, 0.f) : s;
}

// C=527 logits in [4][640] padded rows
__global__ __launch_bounds__(256)
void head_softmax(const float* __restrict__ lg, float* __restrict__ out) {
  __shared__ float red[4];
  int b = blockIdx.x, tid = threadIdx.x;
  const float* r = lg + (long)b * 640;
  float v0 = r[tid];
  float v1 = tid + 256 < 527 ? r[tid + 256] : -1e30f;
  float v2 = tid + 512 < 527 ? r[tid + 512] : -1e30f;
  float mx = block_max(fmaxf(v0, fmaxf(v1, v2)), red, tid);
  float e0 = __expf(v0 - mx);
  float e1 = tid + 256 < 527 ? __expf(v1 - mx) : 0.f;
  float e2 = tid + 512 < 527 ? __expf(v2 - mx) : 0.f;
  float sm = block_sum(e0 + e1 + e2, red, tid);
  float inv = 1.f / sm;
  out[(long)b * 527 + tid] = e0 * inv;
  if (tid + 256 < 527) out[(long)b * 527 + tid + 256] = e1 * inv;
  if (tid + 512 < 527) out[(long)b * 527 + tid + 512] = e2 * inv;
}

// ---------------- launcher ----------------
extern "C" void kernel_launch(void* const* d_in, const int* in_sizes, int n_in,
                              void* d_out, int out_size, void* d_ws, size_t ws_size,
                              hipStream_t stream) {
  const float* x_in    = (const float*)d_in[0];
  const float* conv1_w = (const float*)d_in[1];
  const float* conv1_b = (const float*)d_in[2];
  const float* conv2_w = (const float*)d_in[3];
  const float* conv2_b = (const float*)d_in[4];
  const float* pos_emb = (const float*)d_in[5];
  const float* ln1_g   = (const float*)d_in[6];
  const float* ln1_b   = (const float*)d_in[7];
  const float* wq      = (const float*)d_in[8];
  const float* bq      = (const float*)d_in[9];
  const float* wk      = (const float*)d_in[10];
  const float* bk      = (const float*)d_in[11];
  const float* wv      = (const float*)d_in[12];
  const float* bv      = (const float*)d_in[13];
  const float* wo      = (const float*)d_in[14];
  const float* bo      = (const float*)d_in[15];
  const float* w1      = (const float*)d_in[16];
  const float* b1      = (const float*)d_in[17];
  const float* w2      = (const float*)d_in[18];
  const float* b2      = (const float*)d_in[19];
  const float* ln2_g   = (const float*)d_in[20];
  const float* ln2_b   = (const float*)d_in[21];
  const float* lnp_g   = (const float*)d_in[22];
  const float* lnp_b   = (const float*)d_in[23];
  const float* hln_g   = (const float*)d_in[24];
  const float* hln_b   = (const float*)d_in[25];
  const float* hw1     = (const float*)d_in[26];
  const float* hb1     = (const float*)d_in[27];
  const float* hw2     = (const float*)d_in[28];
  const float* hb2     = (const float*)d_in[29];

  // workspace layout
  char* w = (char*)d_ws;
  bf16*  wqkvT = (bf16*)(w);                      // 6*2304*768 bf16
  bf16*  woT   = (bf16*)(w + 21233664);           // 6*768*768
  bf16*  w1T   = (bf16*)(w + 28311552);           // 6*3072*768
  bf16*  w2T   = (bf16*)(w + 56623104);           // 6*768*3072
  bf16*  wc1T  = (bf16*)(w + 84934656);           // 768*256
  bf16*  wc2T  = (bf16*)(w + 85327872);           // 768*2304
  float* bqkv  = (float*)(w + 88866816);          // 6*2304 f32
  float* Xf    = (float*)(w + 88922112);          // 4096*768 f32
  bf16*  Xb    = (bf16*)(w + 101505024);          // 4096*768
  bf16*  qkv   = (bf16*)(w + 107796480);          // 3*4096*768 (q t-major, k t-major, v d-major)
  bf16*  CC    = (bf16*)(w + 126670848);          // 4096*768
  float* ATTN  = (float*)(w + 132962304);         // 4096*768 f32
  char*  BIG   = w + 145545216;                   // 50,331,648 shared region
  bf16*  A1  = (bf16*)(BIG);                      // 8192*256   (conv phase)
  bf16*  Y1G = (bf16*)(BIG + 4194304);            // 8192*768   (conv phase)
  bf16*  A2  = (bf16*)(BIG + 16777216);           // 4096*2304  (conv phase)
  bf16*  Hh  = (bf16*)(BIG);                      // 4096*3072  (ffn phase)
  float* FFN = (float*)(BIG + 25165824);          // 4096*768 f32 (ffn phase)
  // head phase (aliases, used only after last FFN)
  float* CLS  = (float*)(BIG);                    // 4*768
  float* HID  = (float*)(BIG + 16384);            // 4*3072
  float* LGT  = (float*)(BIG + 81920);            // 4*640
  float* PT1  = (float*)(BIG + 131072);           // 16*4*3072
  float* PT2  = (float*)(BIG + 1048576);          // 32*4*640
  float* HB2P = (float*)(BIG + 1572864);          // 640
  float* HW2P = (float*)(BIG + 1605632);          // 3072*640

  // ---- weight prep ----
  tconv<<<dim3(2, 24, 72), 256, 0, stream>>>(wq, wqkvT,            768, 64,   49152L, 1769472L, 49152L, 12);
  tconv<<<dim3(2, 24, 72), 256, 0, stream>>>(wk, wqkvT + 589824,   768, 64,   49152L, 1769472L, 49152L, 12);
  tconv<<<dim3(2, 24, 72), 256, 0, stream>>>(wv, wqkvT + 1179648,  768, 64,   49152L, 1769472L, 49152L, 12);
  tconv<<<dim3(24, 24, 6), 256, 0, stream>>>(wo, woT,              768, 768,  589824L, 589824L, 0L, 1);
  tconv<<<dim3(96, 24, 6), 256, 0, stream>>>(w1, w1T,              768, 3072, 2359296L, 2359296L, 0L, 1);
  tconv<<<dim3(24, 96, 6), 256, 0, stream>>>(w2, w2T,              3072, 768, 2359296L, 2359296L, 0L, 1);
  prep_cw<<<768,  256, 0, stream>>>(conv1_w, wc1T, 80, 256);
  prep_cw<<<6912, 256, 0, stream>>>(conv2_w, wc2T, 768, 2304);
  prep_bias<<<54, 256, 0, stream>>>(bq, bk, bv, bqkv);

  // ---- convs ----
  im2col1<<<8192, 256, 0, stream>>>(x_in, A1);
  { GP p{}; p.A = A1; p.B = wc1T; p.bias = conv1_b; p.Ob = Y1G;
    p.M = 8192; p.N = 768; p.K = 256;
    gemm_bt<128,64,2,2,EPI_GELU_BF16,1><<<dim3(64,12,1),256,0,stream>>>(p); }
  im2col2<<<36864, 256, 0, stream>>>(Y1G, A2);
  { GP p{}; p.A = A2; p.B = wc2T; p.bias = conv2_b; p.Of = Xf; p.Ob = Xb; p.aux = pos_emb;
    p.M = 4096; p.N = 768; p.K = 2304;
    gemm_bt<64,64,2,2,EPI_CONV2,0><<<dim3(64,12,1),256,0,stream>>>(p); }

  // ---- transformer layers ----
  for (int l = 0; l < 6; ++l) {
    { GP p{}; p.A = Xb; p.B = wqkvT + (long)l * 1769472; p.bias = bqkv + l * 2304;
      p.Ob = qkv; p.M = 4096; p.N = 2304; p.K = 768;
      gemm_bt<128,128,2,2,EPI_QKV,0><<<dim3(32,18,1),256,0,stream>>>(p); }
    attn_flash<<<768, 256, 0, stream>>>(qkv, CC);
    { GP p{}; p.A = CC; p.B = woT + (long)l * 589824; p.bias = bo + l * 768; p.Of = ATTN;
      p.M = 4096; p.N = 768; p.K = 768;
      gemm_bt<64,64,2,2,EPI_BIAS_F32,0><<<dim3(64,12,1),256,0,stream>>>(p); }
    ln_resid<<<4096, 256, 0, stream>>>(Xf, ATTN, ln1_g + l * 768, ln1_b + l * 768, Xf, Xb);
    { GP p{}; p.A = Xb; p.B = w1T + (long)l * 2359296; p.bias = b1 + l * 3072; p.Ob = Hh;
      p.M = 4096; p.N = 3072; p.K = 768;
      gemm_bt<128,128,2,2,EPI_RELU_BF16,0><<<dim3(32,24,1),256,0,stream>>>(p); }
    { GP p{}; p.A = Hh; p.B = w2T + (long)l * 2359296; p.bias = b2 + l * 768; p.Of = FFN;
      p.M = 4096; p.N = 768; p.K = 3072;
      gemm_bt<64,64,2,2,EPI_BIAS_F32,0><<<dim3(64,12,1),256,0,stream>>>(p); }
    ln_resid<<<4096, 256, 0, stream>>>(Xf, FFN, ln2_g + l * 768, ln2_b + l * 768, Xf, Xb);
  }

  // ---- head ----
  head_cls<<<4, 256, 0, stream>>>(Xf, lnp_g, lnp_b, hln_g, hln_b, CLS);
  prep_hw2<<<7680, 256, 0, stream>>>(hw2, hb2, HW2P, HB2P);
  mlp_part<<<dim3(24, 16), 256, 0, stream>>>(CLS, hw1, PT1, 768, 3072, 48);
  mlp_reduce<<<48, 256, 0, stream>>>(PT1, hb1, HID, 3072, 16, 1);
  mlp_part<<<dim3(5, 32), 256, 0, stream>>>(HID, HW2P, PT2, 3072, 640, 96);
  mlp_reduce<<<10, 256, 0, stream>>>(PT2, HB2P, LGT, 640, 32, 0);
  head_softmax<<<4, 256, 0, stream>>>(LGT, (float*)d_out);
}

// Round 17
// 1077.829 us; speedup vs baseline: 2.6498x; 1.0440x over previous
//
#include <hip/hip_runtime.h>
#include <hip/hip_bf16.h>

typedef __hip_bfloat16 bf16;
using v8s   = __attribute__((ext_vector_type(8))) short;
using f32x4 = __attribute__((ext_vector_type(4))) float;

#define DI __device__ __forceinline__

DI float gelu_f(float x) { return 0.5f * x * (1.f + erff(x * 0.70710678118654752f)); }

DI void g2lds16(const bf16* g, bf16* l) {
  __builtin_amdgcn_global_load_lds((const __attribute__((address_space(1))) void*)g,
                                   (__attribute__((address_space(3))) void*)l, 16, 0, 0);
}

// ---------------- block reduction helpers (256 threads, 4 waves) ----------------
DI float block_sum(float v, float* red, int tid) {
#pragma unroll
  for (int o = 32; o > 0; o >>= 1) v += __shfl_down(v, o);
  __syncthreads();
  if ((tid & 63) == 0) red[tid >> 6] = v;
  __syncthreads();
  return red[0] + red[1] + red[2] + red[3];
}
DI float block_max(float v, float* red, int tid) {
#pragma unroll
  for (int o = 32; o > 0; o >>= 1) v = fmaxf(v, __shfl_down(v, o));
  __syncthreads();
  if ((tid & 63) == 0) red[tid >> 6] = v;
  __syncthreads();
  return fmaxf(fmaxf(red[0], red[1]), fmaxf(red[2], red[3]));
}

// ---------------- weight prep ----------------
__global__ __launch_bounds__(256)
void tconv(const float* __restrict__ in, bf16* __restrict__ out,
           int R, int C, long inStrideZ, long outStrideL, long outStrideH, int zmod) {
  __shared__ float tile[32][33];
  int z = blockIdx.z;
  int lz = z / zmod, hz = z - lz * zmod;
  in  += (long)z * inStrideZ;
  out += (long)lz * outStrideL + (long)hz * outStrideH;
  int cb = blockIdx.x * 32, rb = blockIdx.y * 32;
  int tx = threadIdx.x & 31, ty = threadIdx.x >> 5;  // 32x8
#pragma unroll
  for (int i = 0; i < 32; i += 8)
    tile[ty + i][tx] = in[(long)(rb + ty + i) * C + cb + tx];
  __syncthreads();
#pragma unroll
  for (int i = 0; i < 32; i += 8)
    out[(long)(cb + ty + i) * R + rb + tx] = __float2bfloat16(tile[tx][ty + i]);
}

__global__ __launch_bounds__(256)
void prep_cw(const float* __restrict__ wsrc, bf16* __restrict__ o, int IC, int KT) {
  int idx = blockIdx.x * 256 + threadIdx.x;
  int oc = idx / KT, kp = idx - oc * KT;
  float v = 0.f;
  if (kp < IC * 3) {
    int kk = kp / IC, ic = kp - kk * IC;
    v = wsrc[(oc * IC + ic) * 3 + kk];
  }
  o[idx] = __float2bfloat16(v);
}

__global__ __launch_bounds__(256)
void prep_bias(const float* __restrict__ bq, const float* __restrict__ bk,
               const float* __restrict__ bv, float* __restrict__ o) {
  int idx = blockIdx.x * 256 + threadIdx.x;  // 6*2304
  int l = idx / 2304, n = idx - l * 2304;
  int which = n / 768, r = n - which * 768;
  const float* src = which == 0 ? bq : (which == 1 ? bk : bv);
  o[idx] = src[l * 768 + r];
}

// pad-repack head layer-2 weights: hw2 [3072][527] -> hw2p [3072][640] (zero pad)
__global__ __launch_bounds__(256)
void prep_hw2(const float* __restrict__ hw2, const float* __restrict__ hb2,
              float* __restrict__ hw2p, float* __restrict__ hb2p) {
  int idx = blockIdx.x * 256 + threadIdx.x;  // 3072*640
  int e = idx / 640, c = idx - e * 640;
  hw2p[idx] = c < 527 ? hw2[(long)e * 527 + c] : 0.f;
  if (idx < 640) hb2p[idx] = idx < 527 ? hb2[idx] : 0.f;
}

// ---------------- im2col ----------------
__global__ __launch_bounds__(256)
void im2col1(const float* __restrict__ x, bf16* __restrict__ out) {
  int idx = blockIdx.x * 256 + threadIdx.x;  // 8192*256
  int m = idx >> 8, kp = idx & 255;
  float v = 0.f;
  if (kp < 240) {
    int kk = kp / 80, ic = kp - kk * 80;
    int t = (m & 2047) + kk - 1;
    int b = m >> 11;
    if ((unsigned)t < 2048u) v = x[((long)(b * 80 + ic) << 11) + t];
  }
  out[idx] = __float2bfloat16(v);
}

__global__ __launch_bounds__(256)
void im2col2(const bf16* __restrict__ y, bf16* __restrict__ out) {
  int idx = blockIdx.x * 256 + threadIdx.x;  // 4096*2304
  int m = idx / 2304, kp = idx - m * 2304;
  int kk = kp / 768, ic = kp - kk * 768;
  int t = 2 * (m & 1023) + kk - 1;
  bf16 v = __float2bfloat16(0.f);
  if ((unsigned)t < 2048u) v = y[((long)(m >> 10) * 2048 + t) * 768 + ic];
  out[idx] = v;
}

// ---------------- GEMM: C[m][n] = sum_k A[m][k]*B[n][k]  (both bf16, K%64==0) ----------------
// Rule-21 XOR swizzle (conflicts = 0, verified r11). DBUF=1: 2-phase ping-pong
// (1 barrier/K-step, load-compute overlap). DBUF=0: single-buffer m97 structure
// (2 barriers/K-step) -- cross-block wave overlap hides the drain (m114).
enum { EPI_GELU_BF16, EPI_CONV2, EPI_QKV, EPI_BIAS_F32, EPI_RELU_BF16 };

struct GP {
  const bf16* A; const bf16* B; const float* bias;
  bf16* Ob; float* Of; const float* aux;
  int M, N, K; long sA, sB, sC; int zoff;
};

template<int BM, int BN, int WM, int WN, int EPI, int DBUF>
__global__ __launch_bounds__(WM * WN * 64, 2)
void gemm_bt(GP p) {
  constexpr int WAVES = WM * WN;
  constexpr int FM = BM / WM / 16, FN = BN / WN / 16;
  __shared__ __align__(16) bf16 As0[BM * 64], Bs0[BN * 64];
  __shared__ __align__(16) bf16 As1[DBUF ? BM * 64 : 8], Bs1[DBUF ? BN * 64 : 8];
  const int tid = threadIdx.x;
  const int lane = tid & 63, wid = tid >> 6;
  const int wr = wid / WN, wc = wid - wr * WN;
  const int row0 = wr * (BM / WM), col0 = wc * (BN / WN);
  const int lr = lane & 15, lk = (lane >> 4) * 8;
  const int lrow = lane >> 3;
  const int scol = (((lane & 7) ^ (lane >> 3)) & 7) * 8;  // pre-swizzled source col
  const int rswz = (lr & 7) * 8;                          // read-side XOR
  const int z = blockIdx.z;
  const bf16* Ab = p.A + (long)z * p.sA + (long)blockIdx.x * BM * p.K;
  const bf16* Bb = p.B + (long)z * p.sB + (long)blockIdx.y * BN * p.K;
  f32x4 acc[FM][FN] = {};

  auto stage = [&](bf16* As, bf16* Bs, int kt) {
#pragma unroll
    for (int i = 0; i < BM / 8 / WAVES; ++i) {
      const int c = wid + i * WAVES;  // chunk of 8 rows (1KB)
      g2lds16(&Ab[(long)(c * 8 + lrow) * p.K + kt + scol], &As[c << 9]);
    }
#pragma unroll
    for (int i = 0; i < BN / 8 / WAVES; ++i) {
      const int c = wid + i * WAVES;
      g2lds16(&Bb[(long)(c * 8 + lrow) * p.K + kt + scol], &Bs[c << 9]);
    }
  };

  auto compute = [&](const bf16* As, const bf16* Bs) {
#pragma unroll
    for (int ks = 0; ks < 2; ++ks) {
      v8s af[FM], bf_[FN];
#pragma unroll
      for (int mi = 0; mi < FM; ++mi)
        af[mi] = *(const v8s*)&As[(row0 + mi * 16 + lr) * 64 + ((ks * 32 + lk) ^ rswz)];
#pragma unroll
      for (int ni = 0; ni < FN; ++ni)
        bf_[ni] = *(const v8s*)&Bs[(col0 + ni * 16 + lr) * 64 + ((ks * 32 + lk) ^ rswz)];
      __builtin_amdgcn_s_setprio(1);
#pragma unroll
      for (int mi = 0; mi < FM; ++mi)
#pragma unroll
        for (int ni = 0; ni < FN; ++ni)
          acc[mi][ni] = __builtin_amdgcn_mfma_f32_16x16x32_bf16(af[mi], bf_[ni], acc[mi][ni], 0, 0, 0);
      __builtin_amdgcn_s_setprio(0);
    }
  };

  if constexpr (DBUF) {
    stage(As0, Bs0, 0);
    __syncthreads();
    int kt = 0;
    while (true) {
      if (kt + 64 < p.K) stage(As1, Bs1, kt + 64);
      compute(As0, Bs0);
      __syncthreads();
      kt += 64;
      if (kt >= p.K) break;
      if (kt + 64 < p.K) stage(As0, Bs0, kt + 64);
      compute(As1, Bs1);
      __syncthreads();
      kt += 64;
      if (kt >= p.K) break;
    }
  } else {
    for (int kt = 0; kt < p.K; kt += 64) {
      __syncthreads();
      stage(As0, Bs0, kt);
      __syncthreads();
      compute(As0, Bs0);
    }
  }

  // epilogue; D: row=(lane>>4)*4+r, col=lane&15
#pragma unroll
  for (int mi = 0; mi < FM; ++mi) {
#pragma unroll
    for (int ni = 0; ni < FN; ++ni) {
#pragma unroll
      for (int r = 0; r < 4; ++r) {
        float v = acc[mi][ni][r];
        const int m = blockIdx.x * BM + row0 + mi * 16 + (lane >> 4) * 4 + r;
        const int n = blockIdx.y * BN + col0 + ni * 16 + lr;
        if constexpr (EPI == EPI_GELU_BF16) {
          p.Ob[(long)m * p.N + n] = __float2bfloat16(gelu_f(v + p.bias[n]));
        } else if constexpr (EPI == EPI_CONV2) {
          float t = gelu_f(v + p.bias[n]) + p.aux[(long)(m & 1023) * 768 + n];
          p.Of[(long)m * 768 + n] = t;
          p.Ob[(long)m * 768 + n] = __float2bfloat16(t);
        } else if constexpr (EPI == EPI_QKV) {
          float t = v + p.bias[n];
          int which = n / 768, nn = n - which * 768;
          int h = nn >> 6, d = nn & 63;
          long bh = (long)(m >> 10) * 12 + h;
          if (which < 2)
            p.Ob[(long)which * 3145728 + (bh << 16) + ((long)(m & 1023) << 6) + d] = __float2bfloat16(t);
          else
            p.Ob[6291456L + (bh << 16) + ((long)d << 10) + (m & 1023)] = __float2bfloat16(t);
        } else if constexpr (EPI == EPI_BIAS_F32) {
          p.Of[(long)m * p.N + n] = v + p.bias[n];
        } else if constexpr (EPI == EPI_RELU_BF16) {
          p.Ob[(long)m * p.N + n] = __float2bfloat16(fmaxf(v + p.bias[n], 0.f));
        }
      }
    }
  }
}

// ---------------- fused flash attention ----------------
// QBLK=64: grid 768. qt = blk/48, bh = blk%48 (same-head blocks spaced 48 = 0
// mod 8 -> same XCD L2). 4 waves x 16 q-rows. K/V dbuf + XOR swizzle;
// denominator via ones-MFMA; defer-max THR=8 with lane-local guard.
// P in stride-64 XOR-swizzled LDS -> 40KB total -> 4 blocks/CU.
__global__ __launch_bounds__(256)
void attn_flash(const bf16* __restrict__ qkv, bf16* __restrict__ cc) {
  __shared__ __align__(16) bf16 Ks[2][64 * 64], Vs[2][64 * 64];
  __shared__ __align__(16) bf16 Pl[4][16 * 64];
  const int tid = threadIdx.x, lane = tid & 63, wid = tid >> 6;
  const int lr = lane & 15, lg = lane >> 4;
  const int blk = blockIdx.x;
  const int qt = blk / 48, bh = blk - qt * 48;
  const int b = bh / 12, h = bh - b * 12;
  const long qb = (long)bh << 16;
  const bf16* Qg = qkv + qb;
  const bf16* Kg = qkv + 3145728 + qb;
  const bf16* Vg = qkv + 6291456 + qb;
  const int q0 = qt * 64 + wid * 16;
  const int lrow8 = lane >> 3;
  const int scol = (((lane & 7) ^ (lane >> 3)) & 7) * 8;  // pre-swizzled source col
  const int rswz = (lr & 7) * 8;                          // read-side XOR

  v8s aq[2];
#pragma unroll
  for (int ks = 0; ks < 2; ++ks)
    aq[ks] = *(const v8s*)&Qg[(long)(q0 + lr) * 64 + ks * 32 + lg * 8];

  const short oneb = (short)0x3F80;  // bf16 1.0
  const v8s ones = {oneb, oneb, oneb, oneb, oneb, oneb, oneb, oneb};

  float mrow[4] = {-1e30f, -1e30f, -1e30f, -1e30f};
  f32x4 acc[4] = {};
  f32x4 lacc = {};
  bf16* myP = &Pl[wid][0];

  auto stageKV = [&](int buf, int kt) {
#pragma unroll
    for (int i = 0; i < 2; ++i) {
      int c = wid + i * 4;
      g2lds16(&Kg[(long)(kt + c * 8 + lrow8) * 64 + scol], &Ks[buf][c << 9]);
      g2lds16(&Vg[((long)(c * 8 + lrow8) << 10) + kt + scol], &Vs[buf][c << 9]);
    }
  };

  stageKV(0, 0);
  __syncthreads();  // buf0 staged (vmcnt drained at barrier)

  for (int it = 0; it < 16; ++it) {
    const int cur = it & 1;
    if (it + 1 < 16) stageKV(cur ^ 1, (it + 1) * 64);
    const bf16* Kc = &Ks[cur][0];
    const bf16* Vc = &Vs[cur][0];

    // S = Q K^T
    f32x4 s[4] = {};
#pragma unroll
    for (int ks = 0; ks < 2; ++ks) {
      v8s bk[4];
#pragma unroll
      for (int ni = 0; ni < 4; ++ni)
        bk[ni] = *(const v8s*)&Kc[(ni * 16 + lr) * 64 + ((ks * 32 + lg * 8) ^ rswz)];
      __builtin_amdgcn_s_setprio(1);
#pragma unroll
      for (int ni = 0; ni < 4; ++ni)
        s[ni] = __builtin_amdgcn_mfma_f32_16x16x32_bf16(aq[ks], bk[ni], s[ni], 0, 0, 0);
      __builtin_amdgcn_s_setprio(0);
    }

    // online softmax, defer-max with lane-local guard
    float tloc[4];
    bool need = false;
#pragma unroll
    for (int r = 0; r < 4; ++r) {
      tloc[r] = fmaxf(fmaxf(s[0][r], s[1][r]), fmaxf(s[2][r], s[3][r]));
      need = need || (tloc[r] > mrow[r] + 8.f);
    }
    if (__any(need)) {
#pragma unroll
      for (int r = 0; r < 4; ++r) {
        float t = tloc[r];
#pragma unroll
        for (int o = 1; o < 16; o <<= 1) t = fmaxf(t, __shfl_xor(t, o));
        float mn = fmaxf(mrow[r], t);
        float al = __expf(mrow[r] - mn);
        mrow[r] = mn;
        lacc[r] *= al;
#pragma unroll
        for (int ni = 0; ni < 4; ++ni) acc[ni][r] *= al;
      }
    }
#pragma unroll
    for (int r = 0; r < 4; ++r) {
      const int row = lg * 4 + r;
      const int prow = row * 64, psw = (row & 7) * 8;
#pragma unroll
      for (int ni = 0; ni < 4; ++ni)
        myP[prow + ((ni * 16 + lr) ^ psw)] = __float2bfloat16(__expf(s[ni][r] - mrow[r]));
    }

    // O += P * V ; l += P * ones  (V d-major -> contiguous B-frags)
#pragma unroll
    for (int ks = 0; ks < 2; ++ks) {
      v8s pa, bv[4];
      pa = *(const v8s*)&myP[lr * 64 + ((ks * 32 + lg * 8) ^ ((lr & 7) * 8))];
#pragma unroll
      for (int ni = 0; ni < 4; ++ni)
        bv[ni] = *(const v8s*)&Vc[(ni * 16 + lr) * 64 + ((ks * 32 + lg * 8) ^ rswz)];
      __builtin_amdgcn_s_setprio(1);
#pragma unroll
      for (int ni = 0; ni < 4; ++ni)
        acc[ni] = __builtin_amdgcn_mfma_f32_16x16x32_bf16(pa, bv[ni], acc[ni], 0, 0, 0);
      lacc = __builtin_amdgcn_mfma_f32_16x16x32_bf16(pa, ones, lacc, 0, 0, 0);
      __builtin_amdgcn_s_setprio(0);
    }
    __syncthreads();  // all waves done with cur; next buffer fully staged
  }

  // epilogue: normalize and write concat layout [b*1024+t][h*64+d]
#pragma unroll
  for (int ni = 0; ni < 4; ++ni)
#pragma unroll
    for (int r = 0; r < 4; ++r) {
      int row = q0 + lg * 4 + r;
      cc[((long)(b << 10) + row) * 768 + h * 64 + ni * 16 + lr] =
          __float2bfloat16(acc[ni][r] / lacc[r]);
    }
}

// ---------------- residual + LayerNorm (row=768), float4-vectorized ----------------
__global__ __launch_bounds__(256)
void ln_resid(const float* __restrict__ xin, const float* __restrict__ add,
              const float* __restrict__ g, const float* __restrict__ bb,
              float* __restrict__ xo, bf16* __restrict__ xbo) {
  __shared__ float red[4];
  long row = blockIdx.x;
  int tid = threadIdx.x;
  const f32x4* xr = (const f32x4*)(xin + row * 768);
  const f32x4* ar = (const f32x4*)(add + row * 768);
  f32x4 v = {0.f, 0.f, 0.f, 0.f};
  if (tid < 192) {
    f32x4 a = xr[tid], c = ar[tid];
    v[0] = a[0] + c[0]; v[1] = a[1] + c[1]; v[2] = a[2] + c[2]; v[3] = a[3] + c[3];
  }
  float mean = block_sum(v[0] + v[1] + v[2] + v[3], red, tid) * (1.f / 768.f);
  if (tid < 192) { v[0] -= mean; v[1] -= mean; v[2] -= mean; v[3] -= mean; }
  float sq = tid < 192 ? v[0] * v[0] + v[1] * v[1] + v[2] * v[2] + v[3] * v[3] : 0.f;
  float var = block_sum(sq, red, tid) * (1.f / 768.f);
  float rs = rsqrtf(var + 1e-5f);
  if (tid < 192) {
    f32x4 gv = ((const f32x4*)g)[tid];
    f32x4 bv = ((const f32x4*)bb)[tid];
    f32x4 o;
    o[0] = v[0] * rs * gv[0] + bv[0];
    o[1] = v[1] * rs * gv[1] + bv[1];
    o[2] = v[2] * rs * gv[2] + bv[2];
    o[3] = v[3] * rs * gv[3] + bv[3];
    ((f32x4*)(xo + row * 768))[tid] = o;
    bf16 t0 = __float2bfloat16(o[0]), t1 = __float2bfloat16(o[1]);
    bf16 t2 = __float2bfloat16(o[2]), t3 = __float2bfloat16(o[3]);
    ushort4 pk;
    pk.x = *(unsigned short*)&t0; pk.y = *(unsigned short*)&t1;
    pk.z = *(unsigned short*)&t2; pk.w = *(unsigned short*)&t3;
    *(ushort4*)&xbo[row * 768 + tid * 4] = pk;
  }
}

// ---------------- classifier head ----------------
__global__ __launch_bounds__(256)
void head_cls(const float* __restrict__ x,
              const float* __restrict__ lnpg, const float* __restrict__ lnpb,
              const float* __restrict__ hlng, const float* __restrict__ hlnb,
              float* __restrict__ cls) {
  __shared__ float red[4];
  int b = blockIdx.x, tid = threadIdx.x;
  const float* xr = x + (long)b * 1024 * 768;  // row t=0
  float v0 = xr[tid], v1 = xr[tid + 256], v2 = xr[tid + 512];
  float s = block_sum(v0 + v1 + v2, red, tid) * (1.f / 768.f);
  v0 -= s; v1 -= s; v2 -= s;
  float q = block_sum(v0 * v0 + v1 * v1 + v2 * v2, red, tid) * (1.f / 768.f);
  float r = rsqrtf(q + 1e-5f);
  v0 = v0 * r * lnpg[tid]       + lnpb[tid];
  v1 = v1 * r * lnpg[tid + 256] + lnpb[tid + 256];
  v2 = v2 * r * lnpg[tid + 512] + lnpb[tid + 512];
  s = block_sum(v0 + v1 + v2, red, tid) * (1.f / 768.f);
  v0 -= s; v1 -= s; v2 -= s;
  q = block_sum(v0 * v0 + v1 * v1 + v2 * v2, red, tid) * (1.f / 768.f);
  r = rsqrtf(q + 1e-5f);
  cls[b * 768 + tid]       = v0 * r * hlng[tid]       + hlnb[tid];
  cls[b * 768 + tid + 256] = v1 * r * hlng[tid + 256] + hlnb[tid + 256];
  cls[b * 768 + tid + 512] = v2 * r * hlng[tid + 512] + hlnb[tid + 512];
}

// split-K GEMV stage A
__global__ __launch_bounds__(256)
void mlp_part(const float* __restrict__ in, const float* __restrict__ wmat,
              float* __restrict__ part, int IN, int OUTP, int ET) {
  __shared__ float cin[4][96];
  __shared__ float red[8][32][16];
  int tid = threadIdx.x;
  int tx = tid & 31, ty = tid >> 5;
  int e0 = blockIdx.y * ET;
  for (int i = tid; i < 4 * ET; i += 256) {
    int b = i / ET, el = i - b * ET;
    cin[b][el] = in[b * IN + e0 + el];
  }
  __syncthreads();
  f32x4 acc[4] = {};
  const float* wp = wmat + (long)e0 * OUTP + (blockIdx.x * 32 + tx) * 4;
  const int iters = ET >> 3;
  for (int i = 0; i < iters; ++i) {
    int el = ty + i * 8;
    f32x4 w = *(const f32x4*)(wp + (long)el * OUTP);
#pragma unroll
    for (int b = 0; b < 4; ++b) acc[b] += cin[b][el] * w;
  }
#pragma unroll
  for (int b = 0; b < 4; ++b) *(f32x4*)&red[ty][tx][b * 4] = acc[b];
  __syncthreads();
  if (tid < 128) {
    int rx = tid & 31, b = tid >> 5;
    f32x4 s = {};
#pragma unroll
    for (int t = 0; t < 8; ++t) s += *(const f32x4*)&red[t][rx][b * 4];
    *(f32x4*)&part[((long)blockIdx.y * 4 + b) * OUTP + (blockIdx.x * 32 + rx) * 4] = s;
  }
}

__global__ __launch_bounds__(256)
void mlp_reduce(const float* __restrict__ part, const float* __restrict__ bias,
                float* __restrict__ out, int OUTP, int S, int relu) {
  int idx = blockIdx.x * 256 + threadIdx.x;
  int b = idx / OUTP, j = idx - b * OUTP;
  float s = bias[j];
  for (int t = 0; t < S; ++t) s += part[((long)t * 4 + b) * OUTP + j];
  out[idx] = relu ? fmaxf(s, 0.f) : s;
}

// C=527 logits in [4][640] padded rows
__global__ __launch_bounds__(256)
void head_softmax(const float* __restrict__ lg, float* __restrict__ out) {
  __shared__ float red[4];
  int b = blockIdx.x, tid = threadIdx.x;
  const float* r = lg + (long)b * 640;
  float v0 = r[tid];
  float v1 = tid + 256 < 527 ? r[tid + 256] : -1e30f;
  float v2 = tid + 512 < 527 ? r[tid + 512] : -1e30f;
  float mx = block_max(fmaxf(v0, fmaxf(v1, v2)), red, tid);
  float e0 = __expf(v0 - mx);
  float e1 = tid + 256 < 527 ? __expf(v1 - mx) : 0.f;
  float e2 = tid + 512 < 527 ? __expf(v2 - mx) : 0.f;
  float sm = block_sum(e0 + e1 + e2, red, tid);
  float inv = 1.f / sm;
  out[(long)b * 527 + tid] = e0 * inv;
  if (tid + 256 < 527) out[(long)b * 527 + tid + 256] = e1 * inv;
  if (tid + 512 < 527) out[(long)b * 527 + tid + 512] = e2 * inv;
}

// ---------------- launcher ----------------
extern "C" void kernel_launch(void* const* d_in, const int* in_sizes, int n_in,
                              void* d_out, int out_size, void* d_ws, size_t ws_size,
                              hipStream_t stream) {
  const float* x_in    = (const float*)d_in[0];
  const float* conv1_w = (const float*)d_in[1];
  const float* conv1_b = (const float*)d_in[2];
  const float* conv2_w = (const float*)d_in[3];
  const float* conv2_b = (const float*)d_in[4];
  const float* pos_emb = (const float*)d_in[5];
  const float* ln1_g   = (const float*)d_in[6];
  const float* ln1_b   = (const float*)d_in[7];
  const float* wq      = (const float*)d_in[8];
  const float* bq      = (const float*)d_in[9];
  const float* wk      = (const float*)d_in[10];
  const float* bk      = (const float*)d_in[11];
  const float* wv      = (const float*)d_in[12];
  const float* bv      = (const float*)d_in[13];
  const float* wo      = (const float*)d_in[14];
  const float* bo      = (const float*)d_in[15];
  const float* w1      = (const float*)d_in[16];
  const float* b1      = (const float*)d_in[17];
  const float* w2      = (const float*)d_in[18];
  const float* b2      = (const float*)d_in[19];
  const float* ln2_g   = (const float*)d_in[20];
  const float* ln2_b   = (const float*)d_in[21];
  const float* lnp_g   = (const float*)d_in[22];
  const float* lnp_b   = (const float*)d_in[23];
  const float* hln_g   = (const float*)d_in[24];
  const float* hln_b   = (const float*)d_in[25];
  const float* hw1     = (const float*)d_in[26];
  const float* hb1     = (const float*)d_in[27];
  const float* hw2     = (const float*)d_in[28];
  const float* hb2     = (const float*)d_in[29];

  // workspace layout
  char* w = (char*)d_ws;
  bf16*  wqkvT = (bf16*)(w);                      // 6*2304*768 bf16
  bf16*  woT   = (bf16*)(w + 21233664);           // 6*768*768
  bf16*  w1T   = (bf16*)(w + 28311552);           // 6*3072*768
  bf16*  w2T   = (bf16*)(w + 56623104);           // 6*768*3072
  bf16*  wc1T  = (bf16*)(w + 84934656);           // 768*256
  bf16*  wc2T  = (bf16*)(w + 85327872);           // 768*2304
  float* bqkv  = (float*)(w + 88866816);          // 6*2304 f32
  float* Xf    = (float*)(w + 88922112);          // 4096*768 f32
  bf16*  Xb    = (bf16*)(w + 101505024);          // 4096*768
  bf16*  qkv   = (bf16*)(w + 107796480);          // 3*4096*768 (q t-major, k t-major, v d-major)
  bf16*  CC    = (bf16*)(w + 126670848);          // 4096*768
  float* ATTN  = (float*)(w + 132962304);         // 4096*768 f32
  char*  BIG   = w + 145545216;                   // 50,331,648 shared region
  bf16*  A1  = (bf16*)(BIG);                      // 8192*256   (conv phase)
  bf16*  Y1G = (bf16*)(BIG + 4194304);            // 8192*768   (conv phase)
  bf16*  A2  = (bf16*)(BIG + 16777216);           // 4096*2304  (conv phase)
  bf16*  Hh  = (bf16*)(BIG);                      // 4096*3072  (ffn phase)
  float* FFN = (float*)(BIG + 25165824);          // 4096*768 f32 (ffn phase)
  // head phase (aliases, used only after last FFN)
  float* CLS  = (float*)(BIG);                    // 4*768
  float* HID  = (float*)(BIG + 16384);            // 4*3072
  float* LGT  = (float*)(BIG + 81920);            // 4*640
  float* PT1  = (float*)(BIG + 131072);           // 16*4*3072
  float* PT2  = (float*)(BIG + 1048576);          // 32*4*640
  float* HB2P = (float*)(BIG + 1572864);          // 640
  float* HW2P = (float*)(BIG + 1605632);          // 3072*640

  // ---- weight prep ----
  tconv<<<dim3(2, 24, 72), 256, 0, stream>>>(wq, wqkvT,            768, 64,   49152L, 1769472L, 49152L, 12);
  tconv<<<dim3(2, 24, 72), 256, 0, stream>>>(wk, wqkvT + 589824,   768, 64,   49152L, 1769472L, 49152L, 12);
  tconv<<<dim3(2, 24, 72), 256, 0, stream>>>(wv, wqkvT + 1179648,  768, 64,   49152L, 1769472L, 49152L, 12);
  tconv<<<dim3(24, 24, 6), 256, 0, stream>>>(wo, woT,              768, 768,  589824L, 589824L, 0L, 1);
  tconv<<<dim3(96, 24, 6), 256, 0, stream>>>(w1, w1T,              768, 3072, 2359296L, 2359296L, 0L, 1);
  tconv<<<dim3(24, 96, 6), 256, 0, stream>>>(w2, w2T,              3072, 768, 2359296L, 2359296L, 0L, 1);
  prep_cw<<<768,  256, 0, stream>>>(conv1_w, wc1T, 80, 256);
  prep_cw<<<6912, 256, 0, stream>>>(conv2_w, wc2T, 768, 2304);
  prep_bias<<<54, 256, 0, stream>>>(bq, bk, bv, bqkv);

  // ---- convs ----
  im2col1<<<8192, 256, 0, stream>>>(x_in, A1);
  { GP p{}; p.A = A1; p.B = wc1T; p.bias = conv1_b; p.Ob = Y1G;
    p.M = 8192; p.N = 768; p.K = 256;
    gemm_bt<128,64,2,2,EPI_GELU_BF16,1><<<dim3(64,12,1),256,0,stream>>>(p); }
  im2col2<<<36864, 256, 0, stream>>>(Y1G, A2);
  { GP p{}; p.A = A2; p.B = wc2T; p.bias = conv2_b; p.Of = Xf; p.Ob = Xb; p.aux = pos_emb;
    p.M = 4096; p.N = 768; p.K = 2304;
    gemm_bt<64,64,2,2,EPI_CONV2,1><<<dim3(64,12,1),256,0,stream>>>(p); }

  // ---- transformer layers ----
  for (int l = 0; l < 6; ++l) {
    { GP p{}; p.A = Xb; p.B = wqkvT + (long)l * 1769472; p.bias = bqkv + l * 2304;
      p.Ob = qkv; p.M = 4096; p.N = 2304; p.K = 768;
      gemm_bt<128,128,2,2,EPI_QKV,0><<<dim3(32,18,1),256,0,stream>>>(p); }
    attn_flash<<<768, 256, 0, stream>>>(qkv, CC);
    { GP p{}; p.A = CC; p.B = woT + (long)l * 589824; p.bias = bo + l * 768; p.Of = ATTN;
      p.M = 4096; p.N = 768; p.K = 768;
      gemm_bt<64,64,2,2,EPI_BIAS_F32,1><<<dim3(64,12,1),256,0,stream>>>(p); }
    ln_resid<<<4096, 256, 0, stream>>>(Xf, ATTN, ln1_g + l * 768, ln1_b + l * 768, Xf, Xb);
    { GP p{}; p.A = Xb; p.B = w1T + (long)l * 2359296; p.bias = b1 + l * 3072; p.Ob = Hh;
      p.M = 4096; p.N = 3072; p.K = 768;
      gemm_bt<128,128,2,2,EPI_RELU_BF16,0><<<dim3(32,24,1),256,0,stream>>>(p); }
    { GP p{}; p.A = Hh; p.B = w2T + (long)l * 2359296; p.bias = b2 + l * 768; p.Of = FFN;
      p.M = 4096; p.N = 768; p.K = 3072;
      gemm_bt<64,64,2,2,EPI_BIAS_F32,1><<<dim3(64,12,1),256,0,stream>>>(p); }
    ln_resid<<<4096, 256, 0, stream>>>(Xf, FFN, ln2_g + l * 768, ln2_b + l * 768, Xf, Xb);
  }

  // ---- head ----
  head_cls<<<4, 256, 0, stream>>>(Xf, lnp_g, lnp_b, hln_g, hln_b, CLS);
  prep_hw2<<<7680, 256, 0, stream>>>(hw2, hb2, HW2P, HB2P);
  mlp_part<<<dim3(24, 16), 256, 0, stream>>>(CLS, hw1, PT1, 768, 3072, 48);
  mlp_reduce<<<48, 256, 0, stream>>>(PT1, hb1, HID, 3072, 16, 1);
  mlp_part<<<dim3(5, 32), 256, 0, stream>>>(HID, HW2P, PT2, 3072, 640, 96);
  mlp_reduce<<<10, 256, 0, stream>>>(PT2, HB2P, LGT, 640, 32, 0);
  head_softmax<<<4, 256, 0, stream>>>(LGT, (float*)d_out);
}

// Round 18
// 1072.309 us; speedup vs baseline: 2.6635x; 1.0051x over previous
//
#include <hip/hip_runtime.h>
#include <hip/hip_bf16.h>

typedef __hip_bfloat16 bf16;
using v8s   = __attribute__((ext_vector_type(8))) short;
using f32x4 = __attribute__((ext_vector_type(4))) float;

#define DI __device__ __forceinline__

DI float gelu_f(float x) { return 0.5f * x * (1.f + erff(x * 0.70710678118654752f)); }

DI void g2lds16(const bf16* g, bf16* l) {
  __builtin_amdgcn_global_load_lds((const __attribute__((address_space(1))) void*)g,
                                   (__attribute__((address_space(3))) void*)l, 16, 0, 0);
}

// counted-vmcnt barrier (T4): wait until only N vector-mem ops outstanding,
// then barrier. N>0 keeps the just-issued prefetch in flight across the
// barrier (the __syncthreads drain was the structural stall -- it compiles to
// s_waitcnt vmcnt(0) before s_barrier, draining the prefetch we just issued).
template<int N> DI void vm_barrier() {
  if constexpr (N == 0)      asm volatile("s_waitcnt vmcnt(0)\ns_barrier" ::: "memory");
  else if constexpr (N == 2) asm volatile("s_waitcnt vmcnt(2)\ns_barrier" ::: "memory");
  else if constexpr (N == 4) asm volatile("s_waitcnt vmcnt(4)\ns_barrier" ::: "memory");
  else if constexpr (N == 6) asm volatile("s_waitcnt vmcnt(6)\ns_barrier" ::: "memory");
  else if constexpr (N == 8) asm volatile("s_waitcnt vmcnt(8)\ns_barrier" ::: "memory");
}
DI void lds_barrier() { asm volatile("s_barrier" ::: "memory"); }

// ---------------- block reduction helpers (256 threads, 4 waves) ----------------
DI float block_sum(float v, float* red, int tid) {
#pragma unroll
  for (int o = 32; o > 0; o >>= 1) v += __shfl_down(v, o);
  __syncthreads();
  if ((tid & 63) == 0) red[tid >> 6] = v;
  __syncthreads();
  return red[0] + red[1] + red[2] + red[3];
}
DI float block_max(float v, float* red, int tid) {
#pragma unroll
  for (int o = 32; o > 0; o >>= 1) v = fmaxf(v, __shfl_down(v, o));
  __syncthreads();
  if ((tid & 63) == 0) red[tid >> 6] = v;
  __syncthreads();
  return fmaxf(fmaxf(red[0], red[1]), fmaxf(red[2], red[3]));
}

// ---------------- weight prep ----------------
__global__ __launch_bounds__(256)
void tconv(const float* __restrict__ in, bf16* __restrict__ out,
           int R, int C, long inStrideZ, long outStrideL, long outStrideH, int zmod) {
  __shared__ float tile[32][33];
  int z = blockIdx.z;
  int lz = z / zmod, hz = z - lz * zmod;
  in  += (long)z * inStrideZ;
  out += (long)lz * outStrideL + (long)hz * outStrideH;
  int cb = blockIdx.x * 32, rb = blockIdx.y * 32;
  int tx = threadIdx.x & 31, ty = threadIdx.x >> 5;  // 32x8
#pragma unroll
  for (int i = 0; i < 32; i += 8)
    tile[ty + i][tx] = in[(long)(rb + ty + i) * C + cb + tx];
  __syncthreads();
#pragma unroll
  for (int i = 0; i < 32; i += 8)
    out[(long)(cb + ty + i) * R + rb + tx] = __float2bfloat16(tile[tx][ty + i]);
}

__global__ __launch_bounds__(256)
void prep_cw(const float* __restrict__ wsrc, bf16* __restrict__ o, int IC, int KT) {
  int idx = blockIdx.x * 256 + threadIdx.x;
  int oc = idx / KT, kp = idx - oc * KT;
  float v = 0.f;
  if (kp < IC * 3) {
    int kk = kp / IC, ic = kp - kk * IC;
    v = wsrc[(oc * IC + ic) * 3 + kk];
  }
  o[idx] = __float2bfloat16(v);
}

__global__ __launch_bounds__(256)
void prep_bias(const float* __restrict__ bq, const float* __restrict__ bk,
               const float* __restrict__ bv, float* __restrict__ o) {
  int idx = blockIdx.x * 256 + threadIdx.x;  // 6*2304
  int l = idx / 2304, n = idx - l * 2304;
  int which = n / 768, r = n - which * 768;
  const float* src = which == 0 ? bq : (which == 1 ? bk : bv);
  o[idx] = src[l * 768 + r];
}

// pad-repack head layer-2 weights: hw2 [3072][527] -> hw2p [3072][640] (zero pad)
__global__ __launch_bounds__(256)
void prep_hw2(const float* __restrict__ hw2, const float* __restrict__ hb2,
              float* __restrict__ hw2p, float* __restrict__ hb2p) {
  int idx = blockIdx.x * 256 + threadIdx.x;  // 3072*640
  int e = idx / 640, c = idx - e * 640;
  hw2p[idx] = c < 527 ? hw2[(long)e * 527 + c] : 0.f;
  if (idx < 640) hb2p[idx] = idx < 527 ? hb2[idx] : 0.f;
}

// ---------------- im2col ----------------
__global__ __launch_bounds__(256)
void im2col1(const float* __restrict__ x, bf16* __restrict__ out) {
  int idx = blockIdx.x * 256 + threadIdx.x;  // 8192*256
  int m = idx >> 8, kp = idx & 255;
  float v = 0.f;
  if (kp < 240) {
    int kk = kp / 80, ic = kp - kk * 80;
    int t = (m & 2047) + kk - 1;
    int b = m >> 11;
    if ((unsigned)t < 2048u) v = x[((long)(b * 80 + ic) << 11) + t];
  }
  out[idx] = __float2bfloat16(v);
}

__global__ __launch_bounds__(256)
void im2col2(const bf16* __restrict__ y, bf16* __restrict__ out) {
  int idx = blockIdx.x * 256 + threadIdx.x;  // 4096*2304
  int m = idx / 2304, kp = idx - m * 2304;
  int kk = kp / 768, ic = kp - kk * 768;
  int t = 2 * (m & 1023) + kk - 1;
  bf16 v = __float2bfloat16(0.f);
  if ((unsigned)t < 2048u) v = y[((long)(m >> 10) * 2048 + t) * 768 + ic];
  out[idx] = v;
}

// ---------------- GEMM: C[m][n] = sum_k A[m][k]*B[n][k]  (both bf16, K%64==0) ----------------
// Rule-21 XOR swizzle (conflicts 0, r11). DBUF=1: counted-vmcnt double-buffer
// (T4): stage(next) -> vmcnt(L)+barrier (current tile's loads done, next
// tile's stay IN FLIGHT under compute) -> compute(cur) -> plain barrier
// (publish done-reading before overwrite). DBUF=0: single-buffer m97 (m114).
enum { EPI_GELU_BF16, EPI_CONV2, EPI_QKV, EPI_BIAS_F32, EPI_RELU_BF16 };

struct GP {
  const bf16* A; const bf16* B; const float* bias;
  bf16* Ob; float* Of; const float* aux;
  int M, N, K; long sA, sB, sC; int zoff;
};

template<int BM, int BN, int WM, int WN, int EPI, int DBUF>
__global__ __launch_bounds__(WM * WN * 64, 2)
void gemm_bt(GP p) {
  constexpr int WAVES = WM * WN;
  constexpr int FM = BM / WM / 16, FN = BN / WN / 16;
  constexpr int LDN = BM / 8 / WAVES + BN / 8 / WAVES;  // gload_lds per wave per tile
  __shared__ __align__(16) bf16 As0[BM * 64], Bs0[BN * 64];
  __shared__ __align__(16) bf16 As1[DBUF ? BM * 64 : 8], Bs1[DBUF ? BN * 64 : 8];
  const int tid = threadIdx.x;
  const int lane = tid & 63, wid = tid >> 6;
  const int wr = wid / WN, wc = wid - wr * WN;
  const int row0 = wr * (BM / WM), col0 = wc * (BN / WN);
  const int lr = lane & 15, lk = (lane >> 4) * 8;
  const int lrow = lane >> 3;
  const int scol = (((lane & 7) ^ (lane >> 3)) & 7) * 8;  // pre-swizzled source col
  const int rswz = (lr & 7) * 8;                          // read-side XOR
  const int z = blockIdx.z;
  const bf16* Ab = p.A + (long)z * p.sA + (long)blockIdx.x * BM * p.K;
  const bf16* Bb = p.B + (long)z * p.sB + (long)blockIdx.y * BN * p.K;
  f32x4 acc[FM][FN] = {};

  auto stage = [&](bf16* As, bf16* Bs, int kt) {
#pragma unroll
    for (int i = 0; i < BM / 8 / WAVES; ++i) {
      const int c = wid + i * WAVES;  // chunk of 8 rows (1KB)
      g2lds16(&Ab[(long)(c * 8 + lrow) * p.K + kt + scol], &As[c << 9]);
    }
#pragma unroll
    for (int i = 0; i < BN / 8 / WAVES; ++i) {
      const int c = wid + i * WAVES;
      g2lds16(&Bb[(long)(c * 8 + lrow) * p.K + kt + scol], &Bs[c << 9]);
    }
  };

  auto compute = [&](const bf16* As, const bf16* Bs) {
#pragma unroll
    for (int ks = 0; ks < 2; ++ks) {
      v8s af[FM], bf_[FN];
#pragma unroll
      for (int mi = 0; mi < FM; ++mi)
        af[mi] = *(const v8s*)&As[(row0 + mi * 16 + lr) * 64 + ((ks * 32 + lk) ^ rswz)];
#pragma unroll
      for (int ni = 0; ni < FN; ++ni)
        bf_[ni] = *(const v8s*)&Bs[(col0 + ni * 16 + lr) * 64 + ((ks * 32 + lk) ^ rswz)];
      __builtin_amdgcn_s_setprio(1);
#pragma unroll
      for (int mi = 0; mi < FM; ++mi)
#pragma unroll
        for (int ni = 0; ni < FN; ++ni)
          acc[mi][ni] = __builtin_amdgcn_mfma_f32_16x16x32_bf16(af[mi], bf_[ni], acc[mi][ni], 0, 0, 0);
      __builtin_amdgcn_s_setprio(0);
    }
  };

  if constexpr (DBUF) {
    stage(As0, Bs0, 0);
    int kt = 0;
    while (true) {
      bool more = kt + 64 < p.K;
      if (more) { stage(As1, Bs1, kt + 64); vm_barrier<LDN>(); } else vm_barrier<0>();
      compute(As0, Bs0);
      kt += 64;
      if (kt >= p.K) break;
      lds_barrier();
      more = kt + 64 < p.K;
      if (more) { stage(As0, Bs0, kt + 64); vm_barrier<LDN>(); } else vm_barrier<0>();
      compute(As1, Bs1);
      kt += 64;
      if (kt >= p.K) break;
      lds_barrier();
    }
  } else {
    for (int kt = 0; kt < p.K; kt += 64) {
      __syncthreads();
      stage(As0, Bs0, kt);
      __syncthreads();
      compute(As0, Bs0);
    }
  }

  // epilogue; D: row=(lane>>4)*4+r, col=lane&15
#pragma unroll
  for (int mi = 0; mi < FM; ++mi) {
#pragma unroll
    for (int ni = 0; ni < FN; ++ni) {
#pragma unroll
      for (int r = 0; r < 4; ++r) {
        float v = acc[mi][ni][r];
        const int m = blockIdx.x * BM + row0 + mi * 16 + (lane >> 4) * 4 + r;
        const int n = blockIdx.y * BN + col0 + ni * 16 + lr;
        if constexpr (EPI == EPI_GELU_BF16) {
          p.Ob[(long)m * p.N + n] = __float2bfloat16(gelu_f(v + p.bias[n]));
        } else if constexpr (EPI == EPI_CONV2) {
          float t = gelu_f(v + p.bias[n]) + p.aux[(long)(m & 1023) * 768 + n];
          p.Of[(long)m * 768 + n] = t;
          p.Ob[(long)m * 768 + n] = __float2bfloat16(t);
        } else if constexpr (EPI == EPI_QKV) {
          float t = v + p.bias[n];
          int which = n / 768, nn = n - which * 768;
          int h = nn >> 6, d = nn & 63;
          long bh = (long)(m >> 10) * 12 + h;
          if (which < 2)
            p.Ob[(long)which * 3145728 + (bh << 16) + ((long)(m & 1023) << 6) + d] = __float2bfloat16(t);
          else
            p.Ob[6291456L + (bh << 16) + ((long)d << 10) + (m & 1023)] = __float2bfloat16(t);
        } else if constexpr (EPI == EPI_BIAS_F32) {
          p.Of[(long)m * p.N + n] = v + p.bias[n];
        } else if constexpr (EPI == EPI_RELU_BF16) {
          p.Ob[(long)m * p.N + n] = __float2bfloat16(fmaxf(v + p.bias[n], 0.f));
        }
      }
    }
  }
}

// ---------------- fused flash attention ----------------
// QBLK=64: grid 768. qt = blk/48, bh = blk%48 (XCD-aligned). 4 waves x 16
// q-rows. K/V dbuf with counted-vmcnt barriers (T4, L=4 loads/wave/tile);
// XOR swizzle; ones-MFMA denominator; defer-max THR=8 with lane-local guard;
// P stride-64 XOR-swizzled -> 40KB LDS.
__global__ __launch_bounds__(256)
void attn_flash(const bf16* __restrict__ qkv, bf16* __restrict__ cc) {
  __shared__ __align__(16) bf16 Ks[2][64 * 64], Vs[2][64 * 64];
  __shared__ __align__(16) bf16 Pl[4][16 * 64];
  const int tid = threadIdx.x, lane = tid & 63, wid = tid >> 6;
  const int lr = lane & 15, lg = lane >> 4;
  const int blk = blockIdx.x;
  const int qt = blk / 48, bh = blk - qt * 48;
  const int b = bh / 12, h = bh - b * 12;
  const long qb = (long)bh << 16;
  const bf16* Qg = qkv + qb;
  const bf16* Kg = qkv + 3145728 + qb;
  const bf16* Vg = qkv + 6291456 + qb;
  const int q0 = qt * 64 + wid * 16;
  const int lrow8 = lane >> 3;
  const int scol = (((lane & 7) ^ (lane >> 3)) & 7) * 8;  // pre-swizzled source col
  const int rswz = (lr & 7) * 8;                          // read-side XOR

  v8s aq[2];
#pragma unroll
  for (int ks = 0; ks < 2; ++ks)
    aq[ks] = *(const v8s*)&Qg[(long)(q0 + lr) * 64 + ks * 32 + lg * 8];

  const short oneb = (short)0x3F80;  // bf16 1.0
  const v8s ones = {oneb, oneb, oneb, oneb, oneb, oneb, oneb, oneb};

  float mrow[4] = {-1e30f, -1e30f, -1e30f, -1e30f};
  f32x4 acc[4] = {};
  f32x4 lacc = {};
  bf16* myP = &Pl[wid][0];

  auto stageKV = [&](int buf, int kt) {
#pragma unroll
    for (int i = 0; i < 2; ++i) {
      int c = wid + i * 4;
      g2lds16(&Kg[(long)(kt + c * 8 + lrow8) * 64 + scol], &Ks[buf][c << 9]);
      g2lds16(&Vg[((long)(c * 8 + lrow8) << 10) + kt + scol], &Vs[buf][c << 9]);
    }
  };

  stageKV(0, 0);

  for (int it = 0; it < 16; ++it) {
    const int cur = it & 1;
    if (it + 1 < 16) { stageKV(cur ^ 1, (it + 1) * 64); vm_barrier<4>(); }
    else vm_barrier<0>();
    const bf16* Kc = &Ks[cur][0];
    const bf16* Vc = &Vs[cur][0];

    // S = Q K^T
    f32x4 s[4] = {};
#pragma unroll
    for (int ks = 0; ks < 2; ++ks) {
      v8s bk[4];
#pragma unroll
      for (int ni = 0; ni < 4; ++ni)
        bk[ni] = *(const v8s*)&Kc[(ni * 16 + lr) * 64 + ((ks * 32 + lg * 8) ^ rswz)];
      __builtin_amdgcn_s_setprio(1);
#pragma unroll
      for (int ni = 0; ni < 4; ++ni)
        s[ni] = __builtin_amdgcn_mfma_f32_16x16x32_bf16(aq[ks], bk[ni], s[ni], 0, 0, 0);
      __builtin_amdgcn_s_setprio(0);
    }

    // online softmax, defer-max with lane-local guard
    float tloc[4];
    bool need = false;
#pragma unroll
    for (int r = 0; r < 4; ++r) {
      tloc[r] = fmaxf(fmaxf(s[0][r], s[1][r]), fmaxf(s[2][r], s[3][r]));
      need = need || (tloc[r] > mrow[r] + 8.f);
    }
    if (__any(need)) {
#pragma unroll
      for (int r = 0; r < 4; ++r) {
        float t = tloc[r];
#pragma unroll
        for (int o = 1; o < 16; o <<= 1) t = fmaxf(t, __shfl_xor(t, o));
        float mn = fmaxf(mrow[r], t);
        float al = __expf(mrow[r] - mn);
        mrow[r] = mn;
        lacc[r] *= al;
#pragma unroll
        for (int ni = 0; ni < 4; ++ni) acc[ni][r] *= al;
      }
    }
#pragma unroll
    for (int r = 0; r < 4; ++r) {
      const int row = lg * 4 + r;
      const int prow = row * 64, psw = (row & 7) * 8;
#pragma unroll
      for (int ni = 0; ni < 4; ++ni)
        myP[prow + ((ni * 16 + lr) ^ psw)] = __float2bfloat16(__expf(s[ni][r] - mrow[r]));
    }

    // O += P * V ; l += P * ones  (V d-major -> contiguous B-frags)
#pragma unroll
    for (int ks = 0; ks < 2; ++ks) {
      v8s pa, bv[4];
      pa = *(const v8s*)&myP[lr * 64 + ((ks * 32 + lg * 8) ^ ((lr & 7) * 8))];
#pragma unroll
      for (int ni = 0; ni < 4; ++ni)
        bv[ni] = *(const v8s*)&Vc[(ni * 16 + lr) * 64 + ((ks * 32 + lg * 8) ^ rswz)];
      __builtin_amdgcn_s_setprio(1);
#pragma unroll
      for (int ni = 0; ni < 4; ++ni)
        acc[ni] = __builtin_amdgcn_mfma_f32_16x16x32_bf16(pa, bv[ni], acc[ni], 0, 0, 0);
      lacc = __builtin_amdgcn_mfma_f32_16x16x32_bf16(pa, ones, lacc, 0, 0, 0);
      __builtin_amdgcn_s_setprio(0);
    }
    if (it < 15) lds_barrier();  // all waves done reading cur; safe to overwrite
  }

  // epilogue: normalize and write concat layout [b*1024+t][h*64+d]
#pragma unroll
  for (int ni = 0; ni < 4; ++ni)
#pragma unroll
    for (int r = 0; r < 4; ++r) {
      int row = q0 + lg * 4 + r;
      cc[((long)(b << 10) + row) * 768 + h * 64 + ni * 16 + lr] =
          __float2bfloat16(acc[ni][r] / lacc[r]);
    }
}

// ---------------- residual + LayerNorm (row=768), float4-vectorized ----------------
__global__ __launch_bounds__(256)
void ln_resid(const float* __restrict__ xin, const float* __restrict__ add,
              const float* __restrict__ g, const float* __restrict__ bb,
              float* __restrict__ xo, bf16* __restrict__ xbo) {
  __shared__ float red[4];
  long row = blockIdx.x;
  int tid = threadIdx.x;
  const f32x4* xr = (const f32x4*)(xin + row * 768);
  const f32x4* ar = (const f32x4*)(add + row * 768);
  f32x4 v = {0.f, 0.f, 0.f, 0.f};
  if (tid < 192) {
    f32x4 a = xr[tid], c = ar[tid];
    v[0] = a[0] + c[0]; v[1] = a[1] + c[1]; v[2] = a[2] + c[2]; v[3] = a[3] + c[3];
  }
  float mean = block_sum(v[0] + v[1] + v[2] + v[3], red, tid) * (1.f / 768.f);
  if (tid < 192) { v[0] -= mean; v[1] -= mean; v[2] -= mean; v[3] -= mean; }
  float sq = tid < 192 ? v[0] * v[0] + v[1] * v[1] + v[2] * v[2] + v[3] * v[3] : 0.f;
  float var = block_sum(sq, red, tid) * (1.f / 768.f);
  float rs = rsqrtf(var + 1e-5f);
  if (tid < 192) {
    f32x4 gv = ((const f32x4*)g)[tid];
    f32x4 bv = ((const f32x4*)bb)[tid];
    f32x4 o;
    o[0] = v[0] * rs * gv[0] + bv[0];
    o[1] = v[1] * rs * gv[1] + bv[1];
    o[2] = v[2] * rs * gv[2] + bv[2];
    o[3] = v[3] * rs * gv[3] + bv[3];
    ((f32x4*)(xo + row * 768))[tid] = o;
    bf16 t0 = __float2bfloat16(o[0]), t1 = __float2bfloat16(o[1]);
    bf16 t2 = __float2bfloat16(o[2]), t3 = __float2bfloat16(o[3]);
    ushort4 pk;
    pk.x = *(unsigned short*)&t0; pk.y = *(unsigned short*)&t1;
    pk.z = *(unsigned short*)&t2; pk.w = *(unsigned short*)&t3;
    *(ushort4*)&xbo[row * 768 + tid * 4] = pk;
  }
}

// ---------------- classifier head ----------------
__global__ __launch_bounds__(256)
void head_cls(const float* __restrict__ x,
              const float* __restrict__ lnpg, const float* __restrict__ lnpb,
              const float* __restrict__ hlng, const float* __restrict__ hlnb,
              float* __restrict__ cls) {
  __shared__ float red[4];
  int b = blockIdx.x, tid = threadIdx.x;
  const float* xr = x + (long)b * 1024 * 768;  // row t=0
  float v0 = xr[tid], v1 = xr[tid + 256], v2 = xr[tid + 512];
  float s = block_sum(v0 + v1 + v2, red, tid) * (1.f / 768.f);
  v0 -= s; v1 -= s; v2 -= s;
  float q = block_sum(v0 * v0 + v1 * v1 + v2 * v2, red, tid) * (1.f / 768.f);
  float r = rsqrtf(q + 1e-5f);
  v0 = v0 * r * lnpg[tid]       + lnpb[tid];
  v1 = v1 * r * lnpg[tid + 256] + lnpb[tid + 256];
  v2 = v2 * r * lnpg[tid + 512] + lnpb[tid + 512];
  s = block_sum(v0 + v1 + v2, red, tid) * (1.f / 768.f);
  v0 -= s; v1 -= s; v2 -= s;
  q = block_sum(v0 * v0 + v1 * v1 + v2 * v2, red, tid) * (1.f / 768.f);
  r = rsqrtf(q + 1e-5f);
  cls[b * 768 + tid]       = v0 * r * hlng[tid]       + hlnb[tid];
  cls[b * 768 + tid + 256] = v1 * r * hlng[tid + 256] + hlnb[tid + 256];
  cls[b * 768 + tid + 512] = v2 * r * hlng[tid + 512] + hlnb[tid + 512];
}

// split-K GEMV stage A
__global__ __launch_bounds__(256)
void mlp_part(const float* __restrict__ in, const float* __restrict__ wmat,
              float* __restrict__ part, int IN, int OUTP, int ET) {
  __shared__ float cin[4][96];
  __shared__ float red[8][32][16];
  int tid = threadIdx.x;
  int tx = tid & 31, ty = tid >> 5;
  int e0 = blockIdx.y * ET;
  for (int i = tid; i < 4 * ET; i += 256) {
    int b = i / ET, el = i - b * ET;
    cin[b][el] = in[b * IN + e0 + el];
  }
  __syncthreads();
  f32x4 acc[4] = {};
  const float* wp = wmat + (long)e0 * OUTP + (blockIdx.x * 32 + tx) * 4;
  const int iters = ET >> 3;
  for (int i = 0; i < iters; ++i) {
    int el = ty + i * 8;
    f32x4 w = *(const f32x4*)(wp + (long)el * OUTP);
#pragma unroll
    for (int b = 0; b < 4; ++b) acc[b] += cin[b][el] * w;
  }
#pragma unroll
  for (int b = 0; b < 4; ++b) *(f32x4*)&red[ty][tx][b * 4] = acc[b];
  __syncthreads();
  if (tid < 128) {
    int rx = tid & 31, b = tid >> 5;
    f32x4 s = {};
#pragma unroll
    for (int t = 0; t < 8; ++t) s += *(const f32x4*)&red[t][rx][b * 4];
    *(f32x4*)&part[((long)blockIdx.y * 4 + b) * OUTP + (blockIdx.x * 32 + rx) * 4] = s;
  }
}

__global__ __launch_bounds__(256)
void mlp_reduce(const float* __restrict__ part, const float* __restrict__ bias,
                float* __restrict__ out, int OUTP, int S, int relu) {
  int idx = blockIdx.x * 256 + threadIdx.x;
  int b = idx / OUTP, j = idx - b * OUTP;
  float s = bias[j];
  for (int t = 0; t < S; ++t) s += part[((long)t * 4 + b) * OUTP + j];
  out[idx] = relu ? fmaxf(s, 0.f) : s;
}

// C=527 logits in [4][640] padded rows
__global__ __launch_bounds__(256)
void head_softmax(const float* __restrict__ lg, float* __restrict__ out) {
  __shared__ float red[4];
  int b = blockIdx.x, tid = threadIdx.x;
  const float* r = lg + (long)b * 640;
  float v0 = r[tid];
  float v1 = tid + 256 < 527 ? r[tid + 256] : -1e30f;
  float v2 = tid + 512 < 527 ? r[tid + 512] : -1e30f;
  float mx = block_max(fmaxf(v0, fmaxf(v1, v2)), red, tid);
  float e0 = __expf(v0 - mx);
  float e1 = tid + 256 < 527 ? __expf(v1 - mx) : 0.f;
  float e2 = tid + 512 < 527 ? __expf(v2 - mx) : 0.f;
  float sm = block_sum(e0 + e1 + e2, red, tid);
  float inv = 1.f / sm;
  out[(long)b * 527 + tid] = e0 * inv;
  if (tid + 256 < 527) out[(long)b * 527 + tid + 256] = e1 * inv;
  if (tid + 512 < 527) out[(long)b * 527 + tid + 512] = e2 * inv;
}

// ---------------- launcher ----------------
extern "C" void kernel_launch(void* const* d_in, const int* in_sizes, int n_in,
                              void* d_out, int out_size, void* d_ws, size_t ws_size,
                              hipStream_t stream) {
  const float* x_in    = (const float*)d_in[0];
  const float* conv1_w = (const float*)d_in[1];
  const float* conv1_b = (const float*)d_in[2];
  const float* conv2_w = (const float*)d_in[3];
  const float* conv2_b = (const float*)d_in[4];
  const float* pos_emb = (const float*)d_in[5];
  const float* ln1_g   = (const float*)d_in[6];
  const float* ln1_b   = (const float*)d_in[7];
  const float* wq      = (const float*)d_in[8];
  const float* bq      = (const float*)d_in[9];
  const float* wk      = (const float*)d_in[10];
  const float* bk      = (const float*)d_in[11];
  const float* wv      = (const float*)d_in[12];
  const float* bv      = (const float*)d_in[13];
  const float* wo      = (const float*)d_in[14];
  const float* bo      = (const float*)d_in[15];
  const float* w1      = (const float*)d_in[16];
  const float* b1      = (const float*)d_in[17];
  const float* w2      = (const float*)d_in[18];
  const float* b2      = (const float*)d_in[19];
  const float* ln2_g   = (const float*)d_in[20];
  const float* ln2_b   = (const float*)d_in[21];
  const float* lnp_g   = (const float*)d_in[22];
  const float* lnp_b   = (const float*)d_in[23];
  const float* hln_g   = (const float*)d_in[24];
  const float* hln_b   = (const float*)d_in[25];
  const float* hw1     = (const float*)d_in[26];
  const float* hb1     = (const float*)d_in[27];
  const float* hw2     = (const float*)d_in[28];
  const float* hb2     = (const float*)d_in[29];

  // workspace layout
  char* w = (char*)d_ws;
  bf16*  wqkvT = (bf16*)(w);                      // 6*2304*768 bf16
  bf16*  woT   = (bf16*)(w + 21233664);           // 6*768*768
  bf16*  w1T   = (bf16*)(w + 28311552);           // 6*3072*768
  bf16*  w2T   = (bf16*)(w + 56623104);           // 6*768*3072
  bf16*  wc1T  = (bf16*)(w + 84934656);           // 768*256
  bf16*  wc2T  = (bf16*)(w + 85327872);           // 768*2304
  float* bqkv  = (float*)(w + 88866816);          // 6*2304 f32
  float* Xf    = (float*)(w + 88922112);          // 4096*768 f32
  bf16*  Xb    = (bf16*)(w + 101505024);          // 4096*768
  bf16*  qkv   = (bf16*)(w + 107796480);          // 3*4096*768 (q t-major, k t-major, v d-major)
  bf16*  CC    = (bf16*)(w + 126670848);          // 4096*768
  float* ATTN  = (float*)(w + 132962304);         // 4096*768 f32
  char*  BIG   = w + 145545216;                   // 50,331,648 shared region
  bf16*  A1  = (bf16*)(BIG);                      // 8192*256   (conv phase)
  bf16*  Y1G = (bf16*)(BIG + 4194304);            // 8192*768   (conv phase)
  bf16*  A2  = (bf16*)(BIG + 16777216);           // 4096*2304  (conv phase)
  bf16*  Hh  = (bf16*)(BIG);                      // 4096*3072  (ffn phase)
  float* FFN = (float*)(BIG + 25165824);          // 4096*768 f32 (ffn phase)
  // head phase (aliases, used only after last FFN)
  float* CLS  = (float*)(BIG);                    // 4*768
  float* HID  = (float*)(BIG + 16384);            // 4*3072
  float* LGT  = (float*)(BIG + 81920);            // 4*640
  float* PT1  = (float*)(BIG + 131072);           // 16*4*3072
  float* PT2  = (float*)(BIG + 1048576);          // 32*4*640
  float* HB2P = (float*)(BIG + 1572864);          // 640
  float* HW2P = (float*)(BIG + 1605632);          // 3072*640

  // ---- weight prep ----
  tconv<<<dim3(2, 24, 72), 256, 0, stream>>>(wq, wqkvT,            768, 64,   49152L, 1769472L, 49152L, 12);
  tconv<<<dim3(2, 24, 72), 256, 0, stream>>>(wk, wqkvT + 589824,   768, 64,   49152L, 1769472L, 49152L, 12);
  tconv<<<dim3(2, 24, 72), 256, 0, stream>>>(wv, wqkvT + 1179648,  768, 64,   49152L, 1769472L, 49152L, 12);
  tconv<<<dim3(24, 24, 6), 256, 0, stream>>>(wo, woT,              768, 768,  589824L, 589824L, 0L, 1);
  tconv<<<dim3(96, 24, 6), 256, 0, stream>>>(w1, w1T,              768, 3072, 2359296L, 2359296L, 0L, 1);
  tconv<<<dim3(24, 96, 6), 256, 0, stream>>>(w2, w2T,              3072, 768, 2359296L, 2359296L, 0L, 1);
  prep_cw<<<768,  256, 0, stream>>>(conv1_w, wc1T, 80, 256);
  prep_cw<<<6912, 256, 0, stream>>>(conv2_w, wc2T, 768, 2304);
  prep_bias<<<54, 256, 0, stream>>>(bq, bk, bv, bqkv);

  // ---- convs ----
  im2col1<<<8192, 256, 0, stream>>>(x_in, A1);
  { GP p{}; p.A = A1; p.B = wc1T; p.bias = conv1_b; p.Ob = Y1G;
    p.M = 8192; p.N = 768; p.K = 256;
    gemm_bt<128,64,2,2,EPI_GELU_BF16,1><<<dim3(64,12,1),256,0,stream>>>(p); }
  im2col2<<<36864, 256, 0, stream>>>(Y1G, A2);
  { GP p{}; p.A = A2; p.B = wc2T; p.bias = conv2_b; p.Of = Xf; p.Ob = Xb; p.aux = pos_emb;
    p.M = 4096; p.N = 768; p.K = 2304;
    gemm_bt<64,64,2,2,EPI_CONV2,1><<<dim3(64,12,1),256,0,stream>>>(p); }

  // ---- transformer layers ----
  for (int l = 0; l < 6; ++l) {
    { GP p{}; p.A = Xb; p.B = wqkvT + (long)l * 1769472; p.bias = bqkv + l * 2304;
      p.Ob = qkv; p.M = 4096; p.N = 2304; p.K = 768;
      gemm_bt<128,128,2,2,EPI_QKV,0><<<dim3(32,18,1),256,0,stream>>>(p); }
    attn_flash<<<768, 256, 0, stream>>>(qkv, CC);
    { GP p{}; p.A = CC; p.B = woT + (long)l * 589824; p.bias = bo + l * 768; p.Of = ATTN;
      p.M = 4096; p.N = 768; p.K = 768;
      gemm_bt<64,64,2,2,EPI_BIAS_F32,1><<<dim3(64,12,1),256,0,stream>>>(p); }
    ln_resid<<<4096, 256, 0, stream>>>(Xf, ATTN, ln1_g + l * 768, ln1_b + l * 768, Xf, Xb);
    { GP p{}; p.A = Xb; p.B = w1T + (long)l * 2359296; p.bias = b1 + l * 3072; p.Ob = Hh;
      p.M = 4096; p.N = 3072; p.K = 768;
      gemm_bt<128,128,2,2,EPI_RELU_BF16,0><<<dim3(32,24,1),256,0,stream>>>(p); }
    { GP p{}; p.A = Hh; p.B = w2T + (long)l * 2359296; p.bias = b2 + l * 768; p.Of = FFN;
      p.M = 4096; p.N = 768; p.K = 3072;
      gemm_bt<64,64,2,2,EPI_BIAS_F32,1><<<dim3(64,12,1),256,0,stream>>>(p); }
    ln_resid<<<4096, 256, 0, stream>>>(Xf, FFN, ln2_g + l * 768, ln2_b + l * 768, Xf, Xb);
  }

  // ---- head ----
  head_cls<<<4, 256, 0, stream>>>(Xf, lnp_g, lnp_b, hln_g, hln_b, CLS);
  prep_hw2<<<7680, 256, 0, stream>>>(hw2, hb2, HW2P, HB2P);
  mlp_part<<<dim3(24, 16), 256, 0, stream>>>(CLS, hw1, PT1, 768, 3072, 48);
  mlp_reduce<<<48, 256, 0, stream>>>(PT1, hb1, HID, 3072, 16, 1);
  mlp_part<<<dim3(5, 32), 256, 0, stream>>>(HID, HW2P, PT2, 3072, 640, 96);
  mlp_reduce<<<10, 256, 0, stream>>>(PT2, HB2P, LGT, 640, 32, 0);
  head_softmax<<<4, 256, 0, stream>>>(LGT, (float*)d_out);
}